// Round 10
// baseline (16931.087 us; speedup 1.0000x reference)
//
#include <hip/hip_runtime.h>
#include <hip/hip_bf16.h>

// ============================================================================
// FrameAggregator — ROUND 10: naive reference transcription, FLOAT32 OUTPUT.
// Root cause of rounds 1-9: d_out is f32 (reference dtype), not bf16.
// Pipeline identical to round-9's quadruple-audited naive version.
// f32 compute; xw/x1/s1/U stored bf16 in ws (~39 MB).
// Sentinels (f32, now visible): 2^20 ws too small; 2^36 n_in; 2^(37+i) sizes.
// ============================================================================

typedef __hip_bfloat16 bf16;
#define DEV static __device__ __forceinline__
DEV float b2f(bf16 x){ return __bfloat162float(x); }
DEV bf16  f2b(float x){ return __float2bfloat16(x); }

constexpr int B_  = 128;
constexpr int N_  = 512;
constexpr int EG_ = 8192;
constexpr int E_  = B_*EG_;     // 1048576
constexpr int NT_ = B_*N_;      // 65536

constexpr size_t OFF_MC  = (size_t)B_*32*128;                 // 524288
constexpr size_t OFF_O   = OFF_MC + 1;
constexpr size_t OFF_AGG = OFF_O + 1;                         // 524290
constexpr size_t OFF_ADJ = OFF_AGG + (size_t)B_*N_*32;        // 2621442

// ---------------------------------------------------------------------------
__global__ void q_init(float* den, float* losses){
  int i = threadIdx.x;
  if (i < B_) den[i] = 0.f;
  if (i < 2)  losses[i] = 0.f;
}
__global__ void q_sent(float* out, float v){
  if (threadIdx.x == 0) out[0] = v;
}

// ---------------------------------------------------------------------------
// deg/drow: block per graph; thread t owns nodes (base+t) and (base+t+256).
__global__ __launch_bounds__(256) void q_deg(const int* __restrict__ ei,
    const float* __restrict__ ea, float* __restrict__ dis, float* __restrict__ drow){
  int b = blockIdx.x, t = threadIdx.x;
  int base = b*N_, e0 = b*EG_;
  int n0 = base + t, n1 = base + t + 256;
  float dg0 = 1.f, dg1 = 1.f, dr0 = 0.f, dr1 = 0.f;  // 1.0 = self-loop weight
  for (int e = e0; e < e0 + EG_; ++e){
    int r = ei[e], c = ei[E_ + e];
    float w = ea[e];
    if (c == n0) dg0 += w;
    if (c == n1) dg1 += w;
    if (r == n0) dr0 += 1.f;
    if (r == n1) dr1 += 1.f;
  }
  dis[n0] = rsqrtf(dg0);  dis[n1] = rsqrtf(dg1);
  drow[n0] = dr0;         drow[n1] = dr1;
}

// ---------------------------------------------------------------------------
// xw[n,f] = sum_c pos[n,c] * W1[c,f]
__global__ __launch_bounds__(256) void q_xw(const float* __restrict__ pos,
    const float* __restrict__ W1, bf16* __restrict__ xw){
  int id = blockIdx.x*256 + threadIdx.x;        // NT*64
  int n = id >> 6, f = id & 63;
  float a = 0.f;
  for (int c = 0; c < 128; ++c) a += pos[(size_t)n*128 + c] * W1[c*64 + f];
  xw[id] = f2b(a);
}

// ---------------------------------------------------------------------------
// GCN conv by GATHER: wave per node n (lane = feature f).
__global__ __launch_bounds__(256) void q_gcn(const int* __restrict__ ei,
    const float* __restrict__ ea, const float* __restrict__ dis,
    const bf16* __restrict__ xw, const float* __restrict__ b1,
    bf16* __restrict__ x1){
  int n = (blockIdx.x*256 + threadIdx.x) >> 6;  // node 0..NT-1
  int f = threadIdx.x & 63;
  int e0 = (n >> 9) * EG_;
  float dn = dis[n];
  float h = dn*dn*b2f(xw[(size_t)n*64 + f]);
  for (int e = e0; e < e0 + EG_; ++e){
    if (ei[E_ + e] == n){
      int r = ei[e];
      h += dis[r]*ea[e]*dn*b2f(xw[(size_t)r*64 + f]);
    }
  }
  h += b1[f];
  x1[(size_t)n*64 + f] = f2b(h > 0.f ? h : 0.f);
}

// ---------------------------------------------------------------------------
// s1 softmax: wave per node, lane = cluster k; den[b] += ||s_n||^2*drow[n].
__global__ __launch_bounds__(256) void q_s1(const bf16* __restrict__ x1,
    const float* __restrict__ Wp1, const float* __restrict__ bp1,
    const float* __restrict__ drow, bf16* __restrict__ s1, float* __restrict__ den){
  int n = (blockIdx.x*256 + threadIdx.x) >> 6;
  int k = threadIdx.x & 63;
  float lg = bp1[k];
  for (int f = 0; f < 64; ++f) lg += b2f(x1[(size_t)n*64 + f]) * Wp1[f*64 + k];
  float m = lg;
  #pragma unroll
  for (int o = 32; o >= 1; o >>= 1) m = fmaxf(m, __shfl_xor(m, o));
  float p = expf(lg - m);
  float s = p;
  #pragma unroll
  for (int o = 32; o >= 1; o >>= 1) s += __shfl_xor(s, o);
  float sv = p / s;
  s1[(size_t)n*64 + k] = f2b(sv);
  float q = sv*sv;
  #pragma unroll
  for (int o = 32; o >= 1; o >>= 1) q += __shfl_xor(q, o);
  if (k == 0) atomicAdd(&den[n >> 9], q * drow[n]);
}

// ---------------------------------------------------------------------------
// U = A @ s1 by GATHER: wave per node n (row), lane = cluster l.
__global__ __launch_bounds__(256) void q_u(const int* __restrict__ ei,
    const bf16* __restrict__ s1, bf16* __restrict__ U){
  int n = (blockIdx.x*256 + threadIdx.x) >> 6;
  int l = threadIdx.x & 63;
  int e0 = (n >> 9) * EG_;
  float u = 0.f;
  for (int e = e0; e < e0 + EG_; ++e){
    if (ei[e] == n) u += b2f(s1[(size_t)ei[E_ + e]*64 + l]);
  }
  U[(size_t)n*64 + l] = f2b(u);
}

// ---------------------------------------------------------------------------
// adjP[b,k,l] = sum_n s1[bN+n,k]*U[bN+n,l]
__global__ __launch_bounds__(256) void q_adjp(const bf16* __restrict__ s1,
    const bf16* __restrict__ U, float* __restrict__ adjP){
  int id = blockIdx.x*256 + threadIdx.x;        // B*4096
  int b = id >> 12, k = (id >> 6) & 63, l = id & 63;
  int base = b*N_;
  float a = 0.f;
  for (int n = 0; n < N_; ++n)
    a += b2f(s1[(size_t)(base+n)*64 + k]) * b2f(U[(size_t)(base+n)*64 + l]);
  adjP[id] = a;
}
// ssP[b,k,l] = sum_n s1[..,k]*s1[..,l]
__global__ __launch_bounds__(256) void q_ssp(const bf16* __restrict__ s1,
    float* __restrict__ ssP){
  int id = blockIdx.x*256 + threadIdx.x;
  int b = id >> 12, k = (id >> 6) & 63, l = id & 63;
  int base = b*N_;
  float a = 0.f;
  for (int n = 0; n < N_; ++n)
    a += b2f(s1[(size_t)(base+n)*64 + k]) * b2f(s1[(size_t)(base+n)*64 + l]);
  ssP[id] = a;
}
// X1p[b,k,f] = sum_n s1[..,k]*x1[..,f]
__global__ __launch_bounds__(256) void q_x1p(const bf16* __restrict__ s1,
    const bf16* __restrict__ x1, float* __restrict__ X1p){
  int id = blockIdx.x*256 + threadIdx.x;
  int b = id >> 12, k = (id >> 6) & 63, f = id & 63;
  int base = b*N_;
  float a = 0.f;
  for (int n = 0; n < N_; ++n)
    a += b2f(s1[(size_t)(base+n)*64 + k]) * b2f(x1[(size_t)(base+n)*64 + f]);
  X1p[id] = a;
}

// ---------------------------------------------------------------------------
// norm1: losses (mincut1, ortho1); A2 = degnorm(diagzero(adjP)).
__global__ __launch_bounds__(256) void q_norm1(const float* __restrict__ adjP,
    const float* __restrict__ ssP, const float* __restrict__ den,
    float* __restrict__ A2, float* __restrict__ losses){
  __shared__ float aL[4096];
  __shared__ float rL[64];
  __shared__ float red[4];
  int b = blockIdx.x, t = threadIdx.x;
  for (int j = t; j < 4096; j += 256) aL[j] = adjP[(size_t)b*4096 + j];
  __syncthreads();
  if (t == 0){
    float tr = 0.f;
    for (int k = 0; k < 64; ++k) tr += aL[k*64 + k];
    atomicAdd(&losses[0], -(tr/den[b]) * (1.0f/B_));
  }
  if (t < 64){
    float rs = 0.f;
    for (int l = 0; l < 64; ++l) rs += aL[t*64 + l];
    rs -= aL[t*64 + t];                     // diag zeroed before rowsum
    rL[t] = 1.f/(sqrtf(rs) + 1e-15f);
  }
  float pp = 0.f;
  for (int j = t; j < 4096; j += 256){ float v = ssP[(size_t)b*4096 + j]; pp += v*v; }
  #pragma unroll
  for (int o = 32; o >= 1; o >>= 1) pp += __shfl_xor(pp, o);
  if ((t & 63) == 0) red[t >> 6] = pp;
  __syncthreads();                          // publishes red AND rL
  float fro = sqrtf(red[0]+red[1]+red[2]+red[3]);
  __syncthreads();
  float op = 0.f;
  for (int j = t; j < 4096; j += 256){
    int kk = j >> 6, ll = j & 63;
    float v = ssP[(size_t)b*4096 + j]/fro - ((kk==ll) ? 0.125f : 0.f);  // I/sqrt(64)
    op += v*v;
  }
  #pragma unroll
  for (int o = 32; o >= 1; o >>= 1) op += __shfl_xor(op, o);
  if ((t & 63) == 0) red[t >> 6] = op;
  __syncthreads();
  if (t == 0) atomicAdd(&losses[1], sqrtf(red[0]+red[1]+red[2]+red[3]) * (1.0f/B_));
  for (int j = t; j < 4096; j += 256){
    int kk = j >> 6, ll = j & 63;
    A2[(size_t)b*4096 + j] = (kk==ll) ? 0.f : aL[j]*rL[kk]*rL[ll];
  }
}

// ---------------------------------------------------------------------------
// AX[b,n,f] = sum_m A2[b,n,m]*X1p[b,m,f]
__global__ __launch_bounds__(256) void q_ax(const float* __restrict__ A2,
    const float* __restrict__ X1p, float* __restrict__ AX){
  int id = blockIdx.x*256 + threadIdx.x;        // B*4096
  int b = id >> 12, n = (id >> 6) & 63, f = id & 63;
  float a = 0.f;
  for (int m = 0; m < 64; ++m) a += A2[(size_t)b*4096 + n*64 + m]*X1p[(size_t)b*4096 + m*64 + f];
  AX[id] = a;
}
// x2 = relu(AX@W2r + X1p@W2s + b2)
__global__ __launch_bounds__(256) void q_x2(const float* __restrict__ AX,
    const float* __restrict__ X1p, const float* __restrict__ W2r,
    const float* __restrict__ W2s, const float* __restrict__ b2,
    float* __restrict__ x2){
  int id = blockIdx.x*256 + threadIdx.x;        // B*4096
  int b = id >> 12, n = (id >> 6) & 63, f = id & 63;
  float a = b2[f];
  for (int m = 0; m < 64; ++m) a += AX[(size_t)b*4096 + n*64 + m]*W2r[m*64 + f];
  for (int m = 0; m < 64; ++m) a += X1p[(size_t)b*4096 + n*64 + m]*W2s[m*64 + f];
  x2[id] = a > 0.f ? a : 0.f;
}

// ---------------------------------------------------------------------------
// s2 softmax over 32: one THREAD per (b,n).
__global__ __launch_bounds__(256) void q_s2(const float* __restrict__ x2,
    const float* __restrict__ Wp2, const float* __restrict__ bp2,
    float* __restrict__ s2){
  int id = blockIdx.x*256 + threadIdx.x;        // B*64
  if (id >= B_*64) return;
  float lg[32];
  float mx = -1e30f;
  #pragma unroll
  for (int k = 0; k < 32; ++k){
    float a = bp2[k];
    for (int f = 0; f < 64; ++f) a += x2[(size_t)id*64 + f]*Wp2[f*32 + k];
    lg[k] = a; mx = fmaxf(mx, a);
  }
  float ss = 0.f;
  #pragma unroll
  for (int k = 0; k < 32; ++k){ lg[k] = expf(lg[k]-mx); ss += lg[k]; }
  float inv = 1.f/ss;
  #pragma unroll
  for (int k = 0; k < 32; ++k) s2[(size_t)id*32 + k] = lg[k]*inv;
}

// ---------------------------------------------------------------------------
// V[b,n,l] = sum_m A2[b,n,m]*s2[b,m,l]
__global__ __launch_bounds__(256) void q_v(const float* __restrict__ A2,
    const float* __restrict__ s2, float* __restrict__ V){
  int id = blockIdx.x*256 + threadIdx.x;        // B*2048
  int b = id >> 11, n = (id >> 5) & 63, l = id & 31;
  float a = 0.f;
  for (int m = 0; m < 64; ++m) a += A2[(size_t)b*4096 + n*64 + m]*s2[(size_t)b*2048 + m*32 + l];
  V[id] = a;
}
// adj2[b,k,l] = sum_n s2[n,k]*V[n,l] ; ss2 = s2^T s2
__global__ __launch_bounds__(256) void q_adj2(const float* __restrict__ s2,
    const float* __restrict__ V, float* __restrict__ adj2, float* __restrict__ ss2){
  int id = blockIdx.x*256 + threadIdx.x;        // B*1024
  int b = id >> 10, k = (id >> 5) & 31, l = id & 31;
  float a = 0.f, c = 0.f;
  for (int n = 0; n < 64; ++n){
    float sk = s2[(size_t)b*2048 + n*32 + k];
    a += sk*V[(size_t)b*2048 + n*32 + l];
    c += sk*s2[(size_t)b*2048 + n*32 + l];
  }
  adj2[id] = a; ss2[id] = c;
}

// ---------------------------------------------------------------------------
// norm2: losses (mincut2, ortho2); A3 -> ws and out (f32).
__global__ __launch_bounds__(256) void q_norm2(const float* __restrict__ adj2,
    const float* __restrict__ ss2, const float* __restrict__ A2,
    const float* __restrict__ s2, float* __restrict__ A3,
    float* __restrict__ out, float* __restrict__ losses){
  __shared__ float aL[1024];
  __shared__ float sL[1024];
  __shared__ float r2[32];
  __shared__ float red[4];
  __shared__ float den2s;
  int b = blockIdx.x, t = threadIdx.x;
  for (int j = t; j < 1024; j += 256){
    aL[j] = adj2[(size_t)b*1024 + j];
    sL[j] = ss2[(size_t)b*1024 + j];
  }
  __syncthreads();
  if (t < 64){
    float rsA = 0.f;
    for (int m = 0; m < 64; ++m) rsA += A2[(size_t)b*4096 + t*64 + m];
    float q = 0.f;
    for (int k = 0; k < 32; ++k){ float s = s2[(size_t)b*2048 + t*32 + k]; q += s*s; }
    float part = rsA*q;
    #pragma unroll
    for (int o = 32; o >= 1; o >>= 1) part += __shfl_xor(part, o);
    if (t == 0) den2s = part;
  }
  if (t < 32){
    float rs = 0.f;
    for (int l = 0; l < 32; ++l) rs += aL[t*32 + l];
    rs -= aL[t*32 + t];
    r2[t] = 1.f/(sqrtf(rs) + 1e-15f);
  }
  __syncthreads();
  if (t == 0){
    float tr = 0.f;
    for (int k = 0; k < 32; ++k) tr += aL[k*32 + k];
    atomicAdd(&losses[0], -(tr/den2s) * (1.0f/B_));
  }
  float pp = 0.f;
  for (int j = t; j < 1024; j += 256){ float v = sL[j]; pp += v*v; }
  #pragma unroll
  for (int o = 32; o >= 1; o >>= 1) pp += __shfl_xor(pp, o);
  if ((t & 63) == 0) red[t >> 6] = pp;
  __syncthreads();
  float fro = sqrtf(red[0]+red[1]+red[2]+red[3]);
  __syncthreads();
  float op = 0.f;
  for (int j = t; j < 1024; j += 256){
    int kk = j >> 5, ll = j & 31;
    float v = sL[j]/fro - ((kk==ll) ? 0.1767766952966369f : 0.f);  // I/sqrt(32)
    op += v*v;
  }
  #pragma unroll
  for (int o = 32; o >= 1; o >>= 1) op += __shfl_xor(op, o);
  if ((t & 63) == 0) red[t >> 6] = op;
  __syncthreads();
  if (t == 0) atomicAdd(&losses[1], sqrtf(red[0]+red[1]+red[2]+red[3]) * (1.0f/B_));
  for (int j = t; j < 1024; j += 256){
    int kk = j >> 5, ll = j & 31;
    float v = (kk==ll) ? 0.f : aL[j]*r2[kk]*r2[ll];
    A3[(size_t)b*1024 + j] = v;
    out[OFF_ADJ + (size_t)b*1024 + j] = v;
  }
}

// ---------------------------------------------------------------------------
// o2[b,k,f] = sum_n s2[n,k]*x2[n,f]
__global__ __launch_bounds__(256) void q_o2(const float* __restrict__ s2,
    const float* __restrict__ x2, float* __restrict__ o2){
  int id = blockIdx.x*256 + threadIdx.x;        // B*2048
  int b = id >> 11, k = (id >> 6) & 31, f = id & 63;
  float a = 0.f;
  for (int n = 0; n < 64; ++n)
    a += s2[(size_t)b*2048 + n*32 + k]*x2[(size_t)b*4096 + n*64 + f];
  o2[id] = a;
}
// G[b,n,f] = sum_m A3[b,n,m]*o2[b,m,f]
__global__ __launch_bounds__(256) void q_g(const float* __restrict__ A3,
    const float* __restrict__ o2, float* __restrict__ G){
  int id = blockIdx.x*256 + threadIdx.x;        // B*2048
  int b = id >> 11, n = (id >> 6) & 31, f = id & 63;
  float a = 0.f;
  for (int m = 0; m < 32; ++m)
    a += A3[(size_t)b*1024 + n*32 + m]*o2[(size_t)b*2048 + m*64 + f];
  G[id] = a;
}
// x3[b,n,o] -> out (f32)
__global__ __launch_bounds__(256) void q_xout(const float* __restrict__ G,
    const float* __restrict__ o2, const float* __restrict__ W3r,
    const float* __restrict__ W3s, const float* __restrict__ b3,
    float* __restrict__ out){
  int id = blockIdx.x*256 + threadIdx.x;        // B*4096
  int b = id >> 12, n = (id >> 7) & 31, o = id & 127;
  float a = b3[o];
  for (int f = 0; f < 64; ++f) a += G[(size_t)b*2048 + n*64 + f]*W3r[f*128 + o];
  for (int f = 0; f < 64; ++f) a += o2[(size_t)b*2048 + n*64 + f]*W3s[f*128 + o];
  out[(size_t)b*4096 + n*128 + o] = a;
}

// ---------------------------------------------------------------------------
// agg[b,n,l] = sum_k s1[bN+n,k]*s2[b,k,l] -> out (f32)
__global__ __launch_bounds__(256) void q_agg(const bf16* __restrict__ s1,
    const float* __restrict__ s2, float* __restrict__ out){
  int id = blockIdx.x*256 + threadIdx.x;        // B*16384
  int b = id >> 14, n = (id >> 5) & 511, l = id & 31;
  float a = 0.f;
  for (int k = 0; k < 64; ++k)
    a += b2f(s1[((size_t)b*N_ + n)*64 + k]) * s2[(size_t)b*2048 + k*32 + l];
  out[OFF_AGG + ((size_t)b*N_ + n)*32 + l] = a;
}

// ---------------------------------------------------------------------------
__global__ void q_loss(const float* losses, float* out){
  if (threadIdx.x == 0){
    out[OFF_MC] = losses[0];
    out[OFF_O]  = losses[1];
  }
}

// ===========================================================================
extern "C" void kernel_launch(void* const* d_in, const int* in_sizes, int n_in,
                              void* d_out, int out_size, void* d_ws, size_t ws_size,
                              hipStream_t stream){
  (void)out_size;
  float* out = (float*)d_out;

  static const long long EXP_SIZES[16] = {
    8388608LL, 2097152LL, 1048576LL, 65536LL,
    8192LL, 64LL, 4096LL, 64LL,
    4096LL, 64LL, 4096LL, 2048LL, 32LL,
    8192LL, 128LL, 8192LL };
  if (n_in != 16){ q_sent<<<1,64,0,stream>>>(out, exp2f(36.f)); return; }
  for (int i = 0; i < 16; ++i){
    if ((long long)in_sizes[i] != EXP_SIZES[i]){
      q_sent<<<1,64,0,stream>>>(out, exp2f((float)(37+i))); return;
    }
  }

  const float* pos = (const float*)d_in[0];
  const int*   ei  = (const int*)  d_in[1];
  const float* ea  = (const float*)d_in[2];
  const float* W1  = (const float*)d_in[4];
  const float* b1  = (const float*)d_in[5];
  const float* Wp1 = (const float*)d_in[6];
  const float* bp1 = (const float*)d_in[7];
  const float* W2r = (const float*)d_in[8];
  const float* b2  = (const float*)d_in[9];
  const float* W2s = (const float*)d_in[10];
  const float* Wp2 = (const float*)d_in[11];
  const float* bp2 = (const float*)d_in[12];
  const float* W3r = (const float*)d_in[13];
  const float* b3  = (const float*)d_in[14];
  const float* W3s = (const float*)d_in[15];

  // ---- workspace (~39 MB); only aliasing: xw -> U (xw dead after q_gcn)
  char* w = (char*)d_ws;
  float* dis    = (float*)w; w += (size_t)NT_*4;        // 256 KB
  float* drow   = (float*)w; w += (size_t)NT_*4;        // 256 KB
  float* den    = (float*)w; w += (size_t)B_*4;
  float* losses = (float*)w; w += 64;
  float* adjP   = (float*)w; w += (size_t)B_*4096*4;    // 2 MB
  float* ssP    = (float*)w; w += (size_t)B_*4096*4;    // 2 MB
  float* X1p    = (float*)w; w += (size_t)B_*4096*4;    // 2 MB
  float* A2     = (float*)w; w += (size_t)B_*4096*4;    // 2 MB
  float* AX     = (float*)w; w += (size_t)B_*4096*4;    // 2 MB
  float* x2     = (float*)w; w += (size_t)B_*4096*4;    // 2 MB
  float* s2     = (float*)w; w += (size_t)B_*2048*4;    // 1 MB
  float* V      = (float*)w; w += (size_t)B_*2048*4;    // 1 MB
  float* adj2   = (float*)w; w += (size_t)B_*1024*4;    // 0.5 MB
  float* ss2    = (float*)w; w += (size_t)B_*1024*4;    // 0.5 MB
  float* A3     = (float*)w; w += (size_t)B_*1024*4;    // 0.5 MB
  float* o2     = (float*)w; w += (size_t)B_*2048*4;    // 1 MB
  float* G      = (float*)w; w += (size_t)B_*2048*4;    // 1 MB
  bf16*  xwU    = (bf16*)w;  w += (size_t)NT_*64*2;     // 8 MB (xw, then U)
  bf16*  x1     = (bf16*)w;  w += (size_t)NT_*64*2;     // 8 MB
  bf16*  s1     = (bf16*)w;  w += (size_t)NT_*64*2;     // 8 MB
  size_t need = (size_t)(w - (char*)d_ws);
  if (ws_size < need){ q_sent<<<1,64,0,stream>>>(out, exp2f(20.f)); return; }

  q_init <<<1,    256, 0, stream>>>(den, losses);
  q_deg  <<<B_,   256, 0, stream>>>(ei, ea, dis, drow);
  q_xw   <<<16384,256, 0, stream>>>(pos, W1, xwU);
  q_gcn  <<<NT_/4,256, 0, stream>>>(ei, ea, dis, xwU, b1, x1);
  q_s1   <<<NT_/4,256, 0, stream>>>(x1, Wp1, bp1, drow, s1, den);
  q_u    <<<NT_/4,256, 0, stream>>>(ei, s1, xwU);            // xwU := U
  q_adjp <<<2048, 256, 0, stream>>>(s1, xwU, adjP);
  q_ssp  <<<2048, 256, 0, stream>>>(s1, ssP);
  q_x1p  <<<2048, 256, 0, stream>>>(s1, x1, X1p);
  q_norm1<<<B_,   256, 0, stream>>>(adjP, ssP, den, A2, losses);
  q_ax   <<<2048, 256, 0, stream>>>(A2, X1p, AX);
  q_x2   <<<2048, 256, 0, stream>>>(AX, X1p, W2r, W2s, b2, x2);
  q_s2   <<<32,   256, 0, stream>>>(x2, Wp2, bp2, s2);
  q_v    <<<1024, 256, 0, stream>>>(A2, s2, V);
  q_adj2 <<<512,  256, 0, stream>>>(s2, V, adj2, ss2);
  q_norm2<<<B_,   256, 0, stream>>>(adj2, ss2, A2, s2, A3, out, losses);
  q_o2   <<<1024, 256, 0, stream>>>(s2, x2, o2);
  q_g    <<<1024, 256, 0, stream>>>(A3, o2, G);
  q_xout <<<2048, 256, 0, stream>>>(G, o2, W3r, W3s, b3, out);
  q_agg  <<<8192, 256, 0, stream>>>(s1, s2, out);
  q_loss <<<1,     64, 0, stream>>>(losses, out);
}

// Round 11
// 2240.683 us; speedup vs baseline: 7.5562x; 7.5562x over previous
//
#include <hip/hip_runtime.h>
#include <hip/hip_bf16.h>

// ============================================================================
// FrameAggregator — ROUND 11: scatter edge kernels (LDS accumulators).
// Round-10 passing pipeline with q_deg/q_gcn/q_u replaced by block-per-graph
// LDS scatter versions (each edge visited once, not 512x).
// f32 output; xw/x1/s1/U stored bf16 in ws (~39 MB).
// ============================================================================

typedef __hip_bfloat16 bf16;
#define DEV static __device__ __forceinline__
DEV float b2f(bf16 x){ return __bfloat162float(x); }
DEV bf16  f2b(float x){ return __float2bfloat16(x); }

constexpr int B_  = 128;
constexpr int N_  = 512;
constexpr int EG_ = 8192;
constexpr int E_  = B_*EG_;     // 1048576
constexpr int NT_ = B_*N_;      // 65536

constexpr size_t OFF_MC  = (size_t)B_*32*128;                 // 524288
constexpr size_t OFF_O   = OFF_MC + 1;
constexpr size_t OFF_AGG = OFF_O + 1;                         // 524290
constexpr size_t OFF_ADJ = OFF_AGG + (size_t)B_*N_*32;        // 2621442

// ---------------------------------------------------------------------------
__global__ void q_init(float* den, float* losses){
  int i = threadIdx.x;
  if (i < B_) den[i] = 0.f;
  if (i < 2)  losses[i] = 0.f;
}
__global__ void q_sent(float* out, float v){
  if (threadIdx.x == 0) out[0] = v;
}

// ---------------------------------------------------------------------------
// deg/drow via LDS scatter: block per graph, each edge visited once.
__global__ __launch_bounds__(256) void q_deg(const int* __restrict__ ei,
    const float* __restrict__ ea, float* __restrict__ dis, float* __restrict__ drow){
  __shared__ float degL[N_];
  __shared__ float drL[N_];
  int t = threadIdx.x, b = blockIdx.x, base = b*N_;
  for (int j=t; j<N_; j+=256){ degL[j] = 1.0f; drL[j] = 0.f; }  // 1.0 = self loop
  __syncthreads();
  int e0 = b*EG_;
  for (int j=t; j<EG_; j+=256){
    int e = e0 + j;
    int r = ei[e], c = ei[E_+e];
    atomicAdd(&degL[c-base], ea[e]);
    atomicAdd(&drL [r-base], 1.0f);
  }
  __syncthreads();
  for (int j=t; j<N_; j+=256){
    dis [base+j] = rsqrtf(degL[j]);
    drow[base+j] = drL[j];
  }
}

// ---------------------------------------------------------------------------
// xw[n,f] = sum_c pos[n,c] * W1[c,f]
__global__ __launch_bounds__(256) void q_xw(const float* __restrict__ pos,
    const float* __restrict__ W1, bf16* __restrict__ xw){
  int id = blockIdx.x*256 + threadIdx.x;        // NT*64
  int n = id >> 6, f = id & 63;
  float a = 0.f;
  for (int c = 0; c < 128; ++c) a += pos[(size_t)n*128 + c] * W1[c*64 + f];
  xw[id] = f2b(a);
}

// ---------------------------------------------------------------------------
// GCN conv via LDS scatter: block per graph, h[512][64] f32 in LDS (128 KB).
// Init h[n] = dis[n]^2*xw[n]; per edge (r,c): h[c] += dis[r]*ea*dis[c]*xw[r];
// epilogue relu(h + b1) -> x1 (bf16).
__global__ __launch_bounds__(1024) void q_gcn(const int* __restrict__ ei,
    const float* __restrict__ ea, const float* __restrict__ dis,
    const bf16* __restrict__ xw, const float* __restrict__ b1,
    bf16* __restrict__ x1){
  __shared__ float hacc[N_][64];   // 128 KB
  int t = threadIdx.x, b = blockIdx.x, base = b*N_;
  for (int j=t; j<N_*64; j+=1024){
    int n = j>>6, f = j&63; int g = base + n;
    float d = dis[g];
    hacc[n][f] = d*d*b2f(xw[(size_t)g*64 + f]);
  }
  __syncthreads();
  int wv = t>>6, lane = t&63;
  int ebase = b*EG_ + wv*(EG_/16);
  for (int j=0; j<EG_/16; j+=4){
    int e = ebase + j;
    int r0=ei[e+0], c0=ei[E_+e+0];
    int r1=ei[e+1], c1=ei[E_+e+1];
    int r2=ei[e+2], c2=ei[E_+e+2];
    int r3=ei[e+3], c3=ei[E_+e+3];
    float w0 = dis[r0]*ea[e+0]*dis[c0];
    float w1 = dis[r1]*ea[e+1]*dis[c1];
    float w2 = dis[r2]*ea[e+2]*dis[c2];
    float w3 = dis[r3]*ea[e+3]*dis[c3];
    float v0 = b2f(xw[(size_t)r0*64 + lane]);
    float v1 = b2f(xw[(size_t)r1*64 + lane]);
    float v2 = b2f(xw[(size_t)r2*64 + lane]);
    float v3 = b2f(xw[(size_t)r3*64 + lane]);
    atomicAdd(&hacc[c0-base][lane], w0*v0);
    atomicAdd(&hacc[c1-base][lane], w1*v1);
    atomicAdd(&hacc[c2-base][lane], w2*v2);
    atomicAdd(&hacc[c3-base][lane], w3*v3);
  }
  __syncthreads();
  float b1v = b1[t&63];     // stride 1024 keeps f = t&63 fixed
  for (int j=t; j<N_*64; j+=1024){
    float v = ((float*)hacc)[j] + b1v;
    x1[(size_t)base*64 + j] = f2b(v > 0.f ? v : 0.f);
  }
}

// ---------------------------------------------------------------------------
// s1 softmax: wave per node, lane = cluster k; den[b] += ||s_n||^2*drow[n].
__global__ __launch_bounds__(256) void q_s1(const bf16* __restrict__ x1,
    const float* __restrict__ Wp1, const float* __restrict__ bp1,
    const float* __restrict__ drow, bf16* __restrict__ s1, float* __restrict__ den){
  int n = (blockIdx.x*256 + threadIdx.x) >> 6;
  int k = threadIdx.x & 63;
  float lg = bp1[k];
  for (int f = 0; f < 64; ++f) lg += b2f(x1[(size_t)n*64 + f]) * Wp1[f*64 + k];
  float m = lg;
  #pragma unroll
  for (int o = 32; o >= 1; o >>= 1) m = fmaxf(m, __shfl_xor(m, o));
  float p = expf(lg - m);
  float s = p;
  #pragma unroll
  for (int o = 32; o >= 1; o >>= 1) s += __shfl_xor(s, o);
  float sv = p / s;
  s1[(size_t)n*64 + k] = f2b(sv);
  float q = sv*sv;
  #pragma unroll
  for (int o = 32; o >= 1; o >>= 1) q += __shfl_xor(q, o);
  if (k == 0) atomicAdd(&den[n >> 9], q * drow[n]);
}

// ---------------------------------------------------------------------------
// U = A @ s1 via LDS scatter: block per graph; per edge (r,c): U[r] += s1[c].
__global__ __launch_bounds__(1024) void q_u(const int* __restrict__ ei,
    const bf16* __restrict__ s1, bf16* __restrict__ U){
  __shared__ float uacc[N_][64];   // 128 KB
  int t = threadIdx.x, b = blockIdx.x, base = b*N_;
  for (int j=t; j<N_*64; j+=1024) ((float*)uacc)[j] = 0.f;
  __syncthreads();
  int wv = t>>6, lane = t&63;
  int ebase = b*EG_ + wv*(EG_/16);
  for (int j=0; j<EG_/16; j+=4){
    int e = ebase + j;
    int r0=ei[e+0], c0=ei[E_+e+0];
    int r1=ei[e+1], c1=ei[E_+e+1];
    int r2=ei[e+2], c2=ei[E_+e+2];
    int r3=ei[e+3], c3=ei[E_+e+3];
    float v0 = b2f(s1[(size_t)c0*64 + lane]);
    float v1 = b2f(s1[(size_t)c1*64 + lane]);
    float v2 = b2f(s1[(size_t)c2*64 + lane]);
    float v3 = b2f(s1[(size_t)c3*64 + lane]);
    atomicAdd(&uacc[r0-base][lane], v0);
    atomicAdd(&uacc[r1-base][lane], v1);
    atomicAdd(&uacc[r2-base][lane], v2);
    atomicAdd(&uacc[r3-base][lane], v3);
  }
  __syncthreads();
  for (int j=t; j<N_*64; j+=1024) U[(size_t)base*64 + j] = f2b(((float*)uacc)[j]);
}

// ---------------------------------------------------------------------------
// adjP[b,k,l] = sum_n s1[bN+n,k]*U[bN+n,l]
__global__ __launch_bounds__(256) void q_adjp(const bf16* __restrict__ s1,
    const bf16* __restrict__ U, float* __restrict__ adjP){
  int id = blockIdx.x*256 + threadIdx.x;        // B*4096
  int b = id >> 12, k = (id >> 6) & 63, l = id & 63;
  int base = b*N_;
  float a = 0.f;
  for (int n = 0; n < N_; ++n)
    a += b2f(s1[(size_t)(base+n)*64 + k]) * b2f(U[(size_t)(base+n)*64 + l]);
  adjP[id] = a;
}
// ssP[b,k,l] = sum_n s1[..,k]*s1[..,l]
__global__ __launch_bounds__(256) void q_ssp(const bf16* __restrict__ s1,
    float* __restrict__ ssP){
  int id = blockIdx.x*256 + threadIdx.x;
  int b = id >> 12, k = (id >> 6) & 63, l = id & 63;
  int base = b*N_;
  float a = 0.f;
  for (int n = 0; n < N_; ++n)
    a += b2f(s1[(size_t)(base+n)*64 + k]) * b2f(s1[(size_t)(base+n)*64 + l]);
  ssP[id] = a;
}
// X1p[b,k,f] = sum_n s1[..,k]*x1[..,f]
__global__ __launch_bounds__(256) void q_x1p(const bf16* __restrict__ s1,
    const bf16* __restrict__ x1, float* __restrict__ X1p){
  int id = blockIdx.x*256 + threadIdx.x;
  int b = id >> 12, k = (id >> 6) & 63, f = id & 63;
  int base = b*N_;
  float a = 0.f;
  for (int n = 0; n < N_; ++n)
    a += b2f(s1[(size_t)(base+n)*64 + k]) * b2f(x1[(size_t)(base+n)*64 + f]);
  X1p[id] = a;
}

// ---------------------------------------------------------------------------
// norm1: losses (mincut1, ortho1); A2 = degnorm(diagzero(adjP)).
__global__ __launch_bounds__(256) void q_norm1(const float* __restrict__ adjP,
    const float* __restrict__ ssP, const float* __restrict__ den,
    float* __restrict__ A2, float* __restrict__ losses){
  __shared__ float aL[4096];
  __shared__ float rL[64];
  __shared__ float red[4];
  int b = blockIdx.x, t = threadIdx.x;
  for (int j = t; j < 4096; j += 256) aL[j] = adjP[(size_t)b*4096 + j];
  __syncthreads();
  if (t == 0){
    float tr = 0.f;
    for (int k = 0; k < 64; ++k) tr += aL[k*64 + k];
    atomicAdd(&losses[0], -(tr/den[b]) * (1.0f/B_));
  }
  if (t < 64){
    float rs = 0.f;
    for (int l = 0; l < 64; ++l) rs += aL[t*64 + l];
    rs -= aL[t*64 + t];                     // diag zeroed before rowsum
    rL[t] = 1.f/(sqrtf(rs) + 1e-15f);
  }
  float pp = 0.f;
  for (int j = t; j < 4096; j += 256){ float v = ssP[(size_t)b*4096 + j]; pp += v*v; }
  #pragma unroll
  for (int o = 32; o >= 1; o >>= 1) pp += __shfl_xor(pp, o);
  if ((t & 63) == 0) red[t >> 6] = pp;
  __syncthreads();                          // publishes red AND rL
  float fro = sqrtf(red[0]+red[1]+red[2]+red[3]);
  __syncthreads();
  float op = 0.f;
  for (int j = t; j < 4096; j += 256){
    int kk = j >> 6, ll = j & 63;
    float v = ssP[(size_t)b*4096 + j]/fro - ((kk==ll) ? 0.125f : 0.f);  // I/sqrt(64)
    op += v*v;
  }
  #pragma unroll
  for (int o = 32; o >= 1; o >>= 1) op += __shfl_xor(op, o);
  if ((t & 63) == 0) red[t >> 6] = op;
  __syncthreads();
  if (t == 0) atomicAdd(&losses[1], sqrtf(red[0]+red[1]+red[2]+red[3]) * (1.0f/B_));
  for (int j = t; j < 4096; j += 256){
    int kk = j >> 6, ll = j & 63;
    A2[(size_t)b*4096 + j] = (kk==ll) ? 0.f : aL[j]*rL[kk]*rL[ll];
  }
}

// ---------------------------------------------------------------------------
// AX[b,n,f] = sum_m A2[b,n,m]*X1p[b,m,f]
__global__ __launch_bounds__(256) void q_ax(const float* __restrict__ A2,
    const float* __restrict__ X1p, float* __restrict__ AX){
  int id = blockIdx.x*256 + threadIdx.x;        // B*4096
  int b = id >> 12, n = (id >> 6) & 63, f = id & 63;
  float a = 0.f;
  for (int m = 0; m < 64; ++m) a += A2[(size_t)b*4096 + n*64 + m]*X1p[(size_t)b*4096 + m*64 + f];
  AX[id] = a;
}
// x2 = relu(AX@W2r + X1p@W2s + b2)
__global__ __launch_bounds__(256) void q_x2(const float* __restrict__ AX,
    const float* __restrict__ X1p, const float* __restrict__ W2r,
    const float* __restrict__ W2s, const float* __restrict__ b2,
    float* __restrict__ x2){
  int id = blockIdx.x*256 + threadIdx.x;        // B*4096
  int b = id >> 12, n = (id >> 6) & 63, f = id & 63;
  float a = b2[f];
  for (int m = 0; m < 64; ++m) a += AX[(size_t)b*4096 + n*64 + m]*W2r[m*64 + f];
  for (int m = 0; m < 64; ++m) a += X1p[(size_t)b*4096 + n*64 + m]*W2s[m*64 + f];
  x2[id] = a > 0.f ? a : 0.f;
}

// ---------------------------------------------------------------------------
// s2 softmax over 32: one THREAD per (b,n).
__global__ __launch_bounds__(256) void q_s2(const float* __restrict__ x2,
    const float* __restrict__ Wp2, const float* __restrict__ bp2,
    float* __restrict__ s2){
  int id = blockIdx.x*256 + threadIdx.x;        // B*64
  if (id >= B_*64) return;
  float lg[32];
  float mx = -1e30f;
  #pragma unroll
  for (int k = 0; k < 32; ++k){
    float a = bp2[k];
    for (int f = 0; f < 64; ++f) a += x2[(size_t)id*64 + f]*Wp2[f*32 + k];
    lg[k] = a; mx = fmaxf(mx, a);
  }
  float ss = 0.f;
  #pragma unroll
  for (int k = 0; k < 32; ++k){ lg[k] = expf(lg[k]-mx); ss += lg[k]; }
  float inv = 1.f/ss;
  #pragma unroll
  for (int k = 0; k < 32; ++k) s2[(size_t)id*32 + k] = lg[k]*inv;
}

// ---------------------------------------------------------------------------
// V[b,n,l] = sum_m A2[b,n,m]*s2[b,m,l]
__global__ __launch_bounds__(256) void q_v(const float* __restrict__ A2,
    const float* __restrict__ s2, float* __restrict__ V){
  int id = blockIdx.x*256 + threadIdx.x;        // B*2048
  int b = id >> 11, n = (id >> 5) & 63, l = id & 31;
  float a = 0.f;
  for (int m = 0; m < 64; ++m) a += A2[(size_t)b*4096 + n*64 + m]*s2[(size_t)b*2048 + m*32 + l];
  V[id] = a;
}
// adj2[b,k,l] = sum_n s2[n,k]*V[n,l] ; ss2 = s2^T s2
__global__ __launch_bounds__(256) void q_adj2(const float* __restrict__ s2,
    const float* __restrict__ V, float* __restrict__ adj2, float* __restrict__ ss2){
  int id = blockIdx.x*256 + threadIdx.x;        // B*1024
  int b = id >> 10, k = (id >> 5) & 31, l = id & 31;
  float a = 0.f, c = 0.f;
  for (int n = 0; n < 64; ++n){
    float sk = s2[(size_t)b*2048 + n*32 + k];
    a += sk*V[(size_t)b*2048 + n*32 + l];
    c += sk*s2[(size_t)b*2048 + n*32 + l];
  }
  adj2[id] = a; ss2[id] = c;
}

// ---------------------------------------------------------------------------
// norm2: losses (mincut2, ortho2); A3 -> ws and out (f32).
__global__ __launch_bounds__(256) void q_norm2(const float* __restrict__ adj2,
    const float* __restrict__ ss2, const float* __restrict__ A2,
    const float* __restrict__ s2, float* __restrict__ A3,
    float* __restrict__ out, float* __restrict__ losses){
  __shared__ float aL[1024];
  __shared__ float sL[1024];
  __shared__ float r2[32];
  __shared__ float red[4];
  __shared__ float den2s;
  int b = blockIdx.x, t = threadIdx.x;
  for (int j = t; j < 1024; j += 256){
    aL[j] = adj2[(size_t)b*1024 + j];
    sL[j] = ss2[(size_t)b*1024 + j];
  }
  __syncthreads();
  if (t < 64){
    float rsA = 0.f;
    for (int m = 0; m < 64; ++m) rsA += A2[(size_t)b*4096 + t*64 + m];
    float q = 0.f;
    for (int k = 0; k < 32; ++k){ float s = s2[(size_t)b*2048 + t*32 + k]; q += s*s; }
    float part = rsA*q;
    #pragma unroll
    for (int o = 32; o >= 1; o >>= 1) part += __shfl_xor(part, o);
    if (t == 0) den2s = part;
  }
  if (t < 32){
    float rs = 0.f;
    for (int l = 0; l < 32; ++l) rs += aL[t*32 + l];
    rs -= aL[t*32 + t];
    r2[t] = 1.f/(sqrtf(rs) + 1e-15f);
  }
  __syncthreads();
  if (t == 0){
    float tr = 0.f;
    for (int k = 0; k < 32; ++k) tr += aL[k*32 + k];
    atomicAdd(&losses[0], -(tr/den2s) * (1.0f/B_));
  }
  float pp = 0.f;
  for (int j = t; j < 1024; j += 256){ float v = sL[j]; pp += v*v; }
  #pragma unroll
  for (int o = 32; o >= 1; o >>= 1) pp += __shfl_xor(pp, o);
  if ((t & 63) == 0) red[t >> 6] = pp;
  __syncthreads();
  float fro = sqrtf(red[0]+red[1]+red[2]+red[3]);
  __syncthreads();
  float op = 0.f;
  for (int j = t; j < 1024; j += 256){
    int kk = j >> 5, ll = j & 31;
    float v = sL[j]/fro - ((kk==ll) ? 0.1767766952966369f : 0.f);  // I/sqrt(32)
    op += v*v;
  }
  #pragma unroll
  for (int o = 32; o >= 1; o >>= 1) op += __shfl_xor(op, o);
  if ((t & 63) == 0) red[t >> 6] = op;
  __syncthreads();
  if (t == 0) atomicAdd(&losses[1], sqrtf(red[0]+red[1]+red[2]+red[3]) * (1.0f/B_));
  for (int j = t; j < 1024; j += 256){
    int kk = j >> 5, ll = j & 31;
    float v = (kk==ll) ? 0.f : aL[j]*r2[kk]*r2[ll];
    A3[(size_t)b*1024 + j] = v;
    out[OFF_ADJ + (size_t)b*1024 + j] = v;
  }
}

// ---------------------------------------------------------------------------
// o2[b,k,f] = sum_n s2[n,k]*x2[n,f]
__global__ __launch_bounds__(256) void q_o2(const float* __restrict__ s2,
    const float* __restrict__ x2, float* __restrict__ o2){
  int id = blockIdx.x*256 + threadIdx.x;        // B*2048
  int b = id >> 11, k = (id >> 6) & 31, f = id & 63;
  float a = 0.f;
  for (int n = 0; n < 64; ++n)
    a += s2[(size_t)b*2048 + n*32 + k]*x2[(size_t)b*4096 + n*64 + f];
  o2[id] = a;
}
// G[b,n,f] = sum_m A3[b,n,m]*o2[b,m,f]
__global__ __launch_bounds__(256) void q_g(const float* __restrict__ A3,
    const float* __restrict__ o2, float* __restrict__ G){
  int id = blockIdx.x*256 + threadIdx.x;        // B*2048
  int b = id >> 11, n = (id >> 6) & 31, f = id & 63;
  float a = 0.f;
  for (int m = 0; m < 32; ++m)
    a += A3[(size_t)b*1024 + n*32 + m]*o2[(size_t)b*2048 + m*64 + f];
  G[id] = a;
}
// x3[b,n,o] -> out (f32)
__global__ __launch_bounds__(256) void q_xout(const float* __restrict__ G,
    const float* __restrict__ o2, const float* __restrict__ W3r,
    const float* __restrict__ W3s, const float* __restrict__ b3,
    float* __restrict__ out){
  int id = blockIdx.x*256 + threadIdx.x;        // B*4096
  int b = id >> 12, n = (id >> 7) & 31, o = id & 127;
  float a = b3[o];
  for (int f = 0; f < 64; ++f) a += G[(size_t)b*2048 + n*64 + f]*W3r[f*128 + o];
  for (int f = 0; f < 64; ++f) a += o2[(size_t)b*2048 + n*64 + f]*W3s[f*128 + o];
  out[(size_t)b*4096 + n*128 + o] = a;
}

// ---------------------------------------------------------------------------
// agg[b,n,l] = sum_k s1[bN+n,k]*s2[b,k,l] -> out (f32)
__global__ __launch_bounds__(256) void q_agg(const bf16* __restrict__ s1,
    const float* __restrict__ s2, float* __restrict__ out){
  int id = blockIdx.x*256 + threadIdx.x;        // B*16384
  int b = id >> 14, n = (id >> 5) & 511, l = id & 31;
  float a = 0.f;
  for (int k = 0; k < 64; ++k)
    a += b2f(s1[((size_t)b*N_ + n)*64 + k]) * s2[(size_t)b*2048 + k*32 + l];
  out[OFF_AGG + ((size_t)b*N_ + n)*32 + l] = a;
}

// ---------------------------------------------------------------------------
__global__ void q_loss(const float* losses, float* out){
  if (threadIdx.x == 0){
    out[OFF_MC] = losses[0];
    out[OFF_O]  = losses[1];
  }
}

// ===========================================================================
extern "C" void kernel_launch(void* const* d_in, const int* in_sizes, int n_in,
                              void* d_out, int out_size, void* d_ws, size_t ws_size,
                              hipStream_t stream){
  (void)out_size;
  float* out = (float*)d_out;

  static const long long EXP_SIZES[16] = {
    8388608LL, 2097152LL, 1048576LL, 65536LL,
    8192LL, 64LL, 4096LL, 64LL,
    4096LL, 64LL, 4096LL, 2048LL, 32LL,
    8192LL, 128LL, 8192LL };
  if (n_in != 16){ q_sent<<<1,64,0,stream>>>(out, exp2f(36.f)); return; }
  for (int i = 0; i < 16; ++i){
    if ((long long)in_sizes[i] != EXP_SIZES[i]){
      q_sent<<<1,64,0,stream>>>(out, exp2f((float)(37+i))); return;
    }
  }

  const float* pos = (const float*)d_in[0];
  const int*   ei  = (const int*)  d_in[1];
  const float* ea  = (const float*)d_in[2];
  const float* W1  = (const float*)d_in[4];
  const float* b1  = (const float*)d_in[5];
  const float* Wp1 = (const float*)d_in[6];
  const float* bp1 = (const float*)d_in[7];
  const float* W2r = (const float*)d_in[8];
  const float* b2  = (const float*)d_in[9];
  const float* W2s = (const float*)d_in[10];
  const float* Wp2 = (const float*)d_in[11];
  const float* bp2 = (const float*)d_in[12];
  const float* W3r = (const float*)d_in[13];
  const float* b3  = (const float*)d_in[14];
  const float* W3s = (const float*)d_in[15];

  // ---- workspace (~39 MB); only aliasing: xw -> U (xw dead after q_gcn)
  char* w = (char*)d_ws;
  float* dis    = (float*)w; w += (size_t)NT_*4;        // 256 KB
  float* drow   = (float*)w; w += (size_t)NT_*4;        // 256 KB
  float* den    = (float*)w; w += (size_t)B_*4;
  float* losses = (float*)w; w += 64;
  float* adjP   = (float*)w; w += (size_t)B_*4096*4;    // 2 MB
  float* ssP    = (float*)w; w += (size_t)B_*4096*4;    // 2 MB
  float* X1p    = (float*)w; w += (size_t)B_*4096*4;    // 2 MB
  float* A2     = (float*)w; w += (size_t)B_*4096*4;    // 2 MB
  float* AX     = (float*)w; w += (size_t)B_*4096*4;    // 2 MB
  float* x2     = (float*)w; w += (size_t)B_*4096*4;    // 2 MB
  float* s2     = (float*)w; w += (size_t)B_*2048*4;    // 1 MB
  float* V      = (float*)w; w += (size_t)B_*2048*4;    // 1 MB
  float* adj2   = (float*)w; w += (size_t)B_*1024*4;    // 0.5 MB
  float* ss2    = (float*)w; w += (size_t)B_*1024*4;    // 0.5 MB
  float* A3     = (float*)w; w += (size_t)B_*1024*4;    // 0.5 MB
  float* o2     = (float*)w; w += (size_t)B_*2048*4;    // 1 MB
  float* G      = (float*)w; w += (size_t)B_*2048*4;    // 1 MB
  bf16*  xwU    = (bf16*)w;  w += (size_t)NT_*64*2;     // 8 MB (xw, then U)
  bf16*  x1     = (bf16*)w;  w += (size_t)NT_*64*2;     // 8 MB
  bf16*  s1     = (bf16*)w;  w += (size_t)NT_*64*2;     // 8 MB
  size_t need = (size_t)(w - (char*)d_ws);
  if (ws_size < need){ q_sent<<<1,64,0,stream>>>(out, exp2f(20.f)); return; }

  q_init <<<1,    256, 0, stream>>>(den, losses);
  q_deg  <<<B_,   256, 0, stream>>>(ei, ea, dis, drow);
  q_xw   <<<16384,256, 0, stream>>>(pos, W1, xwU);
  q_gcn  <<<B_,  1024, 0, stream>>>(ei, ea, dis, xwU, b1, x1);
  q_s1   <<<NT_/4,256, 0, stream>>>(x1, Wp1, bp1, drow, s1, den);
  q_u    <<<B_,  1024, 0, stream>>>(ei, s1, xwU);            // xwU := U
  q_adjp <<<2048, 256, 0, stream>>>(s1, xwU, adjP);
  q_ssp  <<<2048, 256, 0, stream>>>(s1, ssP);
  q_x1p  <<<2048, 256, 0, stream>>>(s1, x1, X1p);
  q_norm1<<<B_,   256, 0, stream>>>(adjP, ssP, den, A2, losses);
  q_ax   <<<2048, 256, 0, stream>>>(A2, X1p, AX);
  q_x2   <<<2048, 256, 0, stream>>>(AX, X1p, W2r, W2s, b2, x2);
  q_s2   <<<32,   256, 0, stream>>>(x2, Wp2, bp2, s2);
  q_v    <<<1024, 256, 0, stream>>>(A2, s2, V);
  q_adj2 <<<512,  256, 0, stream>>>(s2, V, adj2, ss2);
  q_norm2<<<B_,   256, 0, stream>>>(adj2, ss2, A2, s2, A3, out, losses);
  q_o2   <<<1024, 256, 0, stream>>>(s2, x2, o2);
  q_g    <<<1024, 256, 0, stream>>>(A3, o2, G);
  q_xout <<<2048, 256, 0, stream>>>(G, o2, W3r, W3s, b3, out);
  q_agg  <<<8192, 256, 0, stream>>>(s1, s2, out);
  q_loss <<<1,     64, 0, stream>>>(losses, out);
}

// Round 12
// 1578.081 us; speedup vs baseline: 10.7289x; 1.4199x over previous
//
#include <hip/hip_runtime.h>
#include <hip/hip_bf16.h>

// ============================================================================
// FrameAggregator — ROUND 12: edge kernels reworked for latency hiding.
//  * q_prep: ew[e] = dis[r]*ea*dis[c] (coalesced, once)
//  * q_gcn/q_u: 4 blocks/graph (16-feature slices), 34 KB LDS (rows padded
//    to 17), 512 thr, 16 independent gather chains per wave.
// Everything else identical to the round-11 passing pipeline.
// f32 output; xw/x1/s1/U bf16 in ws (~43 MB).
// ============================================================================

typedef __hip_bfloat16 bf16;
#define DEV static __device__ __forceinline__
DEV float b2f(bf16 x){ return __bfloat162float(x); }
DEV bf16  f2b(float x){ return __float2bfloat16(x); }

constexpr int B_  = 128;
constexpr int N_  = 512;
constexpr int EG_ = 8192;
constexpr int E_  = B_*EG_;     // 1048576
constexpr int NT_ = B_*N_;      // 65536

constexpr size_t OFF_MC  = (size_t)B_*32*128;                 // 524288
constexpr size_t OFF_O   = OFF_MC + 1;
constexpr size_t OFF_AGG = OFF_O + 1;                         // 524290
constexpr size_t OFF_ADJ = OFF_AGG + (size_t)B_*N_*32;        // 2621442

// ---------------------------------------------------------------------------
__global__ void q_init(float* den, float* losses){
  int i = threadIdx.x;
  if (i < B_) den[i] = 0.f;
  if (i < 2)  losses[i] = 0.f;
}
__global__ void q_sent(float* out, float v){
  if (threadIdx.x == 0) out[0] = v;
}

// ---------------------------------------------------------------------------
// deg/drow via LDS scatter: block per graph.
__global__ __launch_bounds__(256) void q_deg(const int* __restrict__ ei,
    const float* __restrict__ ea, float* __restrict__ dis, float* __restrict__ drow){
  __shared__ float degL[N_];
  __shared__ float drL[N_];
  int t = threadIdx.x, b = blockIdx.x, base = b*N_;
  for (int j=t; j<N_; j+=256){ degL[j] = 1.0f; drL[j] = 0.f; }  // 1.0 = self loop
  __syncthreads();
  int e0 = b*EG_;
  for (int j=t; j<EG_; j+=256){
    int e = e0 + j;
    int r = ei[e], c = ei[E_+e];
    atomicAdd(&degL[c-base], ea[e]);
    atomicAdd(&drL [r-base], 1.0f);
  }
  __syncthreads();
  for (int j=t; j<N_; j+=256){
    dis [base+j] = rsqrtf(degL[j]);
    drow[base+j] = drL[j];
  }
}

// ---------------------------------------------------------------------------
// ew[e] = dis[r]*ea[e]*dis[c]  (coalesced; dis gathers L2-hot)
__global__ __launch_bounds__(256) void q_prep(const int* __restrict__ ei,
    const float* __restrict__ ea, const float* __restrict__ dis,
    float* __restrict__ ew){
  int e = blockIdx.x*256 + threadIdx.x;
  ew[e] = dis[ei[e]] * ea[e] * dis[ei[E_+e]];
}

// ---------------------------------------------------------------------------
// xw[n,f] = sum_c pos[n,c] * W1[c,f]
__global__ __launch_bounds__(256) void q_xw(const float* __restrict__ pos,
    const float* __restrict__ W1, bf16* __restrict__ xw){
  int id = blockIdx.x*256 + threadIdx.x;        // NT*64
  int n = id >> 6, f = id & 63;
  float a = 0.f;
  for (int c = 0; c < 128; ++c) a += pos[(size_t)n*128 + c] * W1[c*64 + f];
  xw[id] = f2b(a);
}

// ---------------------------------------------------------------------------
// GCN conv, 4 blocks/graph (16-feature slice each). LDS h[512][17] f32.
// Wave = 4 edge-groups x 16 lanes; 4-deep unroll per group.
__global__ __launch_bounds__(512) void q_gcn(const int* __restrict__ ei,
    const float* __restrict__ ew, const float* __restrict__ dis,
    const bf16* __restrict__ xw, const float* __restrict__ b1,
    bf16* __restrict__ x1){
  __shared__ float hacc[N_*17];    // 34816 B
  int t = threadIdx.x, blk = blockIdx.x;
  int b = blk >> 2, f0 = (blk & 3)*16;
  int base = b*N_;
  for (int j=t; j<N_*16; j+=512){
    int n = j>>4, f = j&15;
    float d = dis[base+n];
    hacc[n*17 + f] = d*d*b2f(xw[(size_t)(base+n)*64 + f0 + f]);
  }
  __syncthreads();
  int wv = t>>6, grp = (t>>4)&3, f = t&15;
  int ebase = b*EG_ + wv*1024 + grp;
  for (int j=0; j<1024; j+=16){
    int e = ebase + j;
    int r0 = ei[e],    c0 = ei[E_+e];
    int r1 = ei[e+4],  c1 = ei[E_+e+4];
    int r2 = ei[e+8],  c2 = ei[E_+e+8];
    int r3 = ei[e+12], c3 = ei[E_+e+12];
    float w0 = ew[e],  w1 = ew[e+4], w2 = ew[e+8], w3 = ew[e+12];
    float v0 = b2f(xw[(size_t)r0*64 + f0 + f]);
    float v1 = b2f(xw[(size_t)r1*64 + f0 + f]);
    float v2 = b2f(xw[(size_t)r2*64 + f0 + f]);
    float v3 = b2f(xw[(size_t)r3*64 + f0 + f]);
    atomicAdd(&hacc[(c0-base)*17 + f], w0*v0);
    atomicAdd(&hacc[(c1-base)*17 + f], w1*v1);
    atomicAdd(&hacc[(c2-base)*17 + f], w2*v2);
    atomicAdd(&hacc[(c3-base)*17 + f], w3*v3);
  }
  __syncthreads();
  for (int j=t; j<N_*16; j+=512){
    int n = j>>4, f = j&15;
    float v = hacc[n*17 + f] + b1[f0 + f];
    x1[(size_t)(base+n)*64 + f0 + f] = f2b(v > 0.f ? v : 0.f);
  }
}

// ---------------------------------------------------------------------------
// s1 softmax: wave per node, lane = cluster k; den[b] += ||s_n||^2*drow[n].
__global__ __launch_bounds__(256) void q_s1(const bf16* __restrict__ x1,
    const float* __restrict__ Wp1, const float* __restrict__ bp1,
    const float* __restrict__ drow, bf16* __restrict__ s1, float* __restrict__ den){
  int n = (blockIdx.x*256 + threadIdx.x) >> 6;
  int k = threadIdx.x & 63;
  float lg = bp1[k];
  for (int f = 0; f < 64; ++f) lg += b2f(x1[(size_t)n*64 + f]) * Wp1[f*64 + k];
  float m = lg;
  #pragma unroll
  for (int o = 32; o >= 1; o >>= 1) m = fmaxf(m, __shfl_xor(m, o));
  float p = expf(lg - m);
  float s = p;
  #pragma unroll
  for (int o = 32; o >= 1; o >>= 1) s += __shfl_xor(s, o);
  float sv = p / s;
  s1[(size_t)n*64 + k] = f2b(sv);
  float q = sv*sv;
  #pragma unroll
  for (int o = 32; o >= 1; o >>= 1) q += __shfl_xor(q, o);
  if (k == 0) atomicAdd(&den[n >> 9], q * drow[n]);
}

// ---------------------------------------------------------------------------
// U = A @ s1, 4 blocks/graph (16-cluster slice). Per edge (r,c): U[r]+=s1[c].
__global__ __launch_bounds__(512) void q_u(const int* __restrict__ ei,
    const bf16* __restrict__ s1, bf16* __restrict__ U){
  __shared__ float uacc[N_*17];    // 34816 B
  int t = threadIdx.x, blk = blockIdx.x;
  int b = blk >> 2, f0 = (blk & 3)*16;
  int base = b*N_;
  for (int j=t; j<N_*17; j+=512) uacc[j] = 0.f;
  __syncthreads();
  int wv = t>>6, grp = (t>>4)&3, f = t&15;
  int ebase = b*EG_ + wv*1024 + grp;
  for (int j=0; j<1024; j+=16){
    int e = ebase + j;
    int r0 = ei[e],    c0 = ei[E_+e];
    int r1 = ei[e+4],  c1 = ei[E_+e+4];
    int r2 = ei[e+8],  c2 = ei[E_+e+8];
    int r3 = ei[e+12], c3 = ei[E_+e+12];
    float v0 = b2f(s1[(size_t)c0*64 + f0 + f]);
    float v1 = b2f(s1[(size_t)c1*64 + f0 + f]);
    float v2 = b2f(s1[(size_t)c2*64 + f0 + f]);
    float v3 = b2f(s1[(size_t)c3*64 + f0 + f]);
    atomicAdd(&uacc[(r0-base)*17 + f], v0);
    atomicAdd(&uacc[(r1-base)*17 + f], v1);
    atomicAdd(&uacc[(r2-base)*17 + f], v2);
    atomicAdd(&uacc[(r3-base)*17 + f], v3);
  }
  __syncthreads();
  for (int j=t; j<N_*16; j+=512){
    int n = j>>4, f = j&15;
    U[(size_t)(base+n)*64 + f0 + f] = f2b(uacc[n*17 + f]);
  }
}

// ---------------------------------------------------------------------------
// adjP[b,k,l] = sum_n s1[bN+n,k]*U[bN+n,l]
__global__ __launch_bounds__(256) void q_adjp(const bf16* __restrict__ s1,
    const bf16* __restrict__ U, float* __restrict__ adjP){
  int id = blockIdx.x*256 + threadIdx.x;        // B*4096
  int b = id >> 12, k = (id >> 6) & 63, l = id & 63;
  int base = b*N_;
  float a = 0.f;
  for (int n = 0; n < N_; ++n)
    a += b2f(s1[(size_t)(base+n)*64 + k]) * b2f(U[(size_t)(base+n)*64 + l]);
  adjP[id] = a;
}
// ssP[b,k,l] = sum_n s1[..,k]*s1[..,l]
__global__ __launch_bounds__(256) void q_ssp(const bf16* __restrict__ s1,
    float* __restrict__ ssP){
  int id = blockIdx.x*256 + threadIdx.x;
  int b = id >> 12, k = (id >> 6) & 63, l = id & 63;
  int base = b*N_;
  float a = 0.f;
  for (int n = 0; n < N_; ++n)
    a += b2f(s1[(size_t)(base+n)*64 + k]) * b2f(s1[(size_t)(base+n)*64 + l]);
  ssP[id] = a;
}
// X1p[b,k,f] = sum_n s1[..,k]*x1[..,f]
__global__ __launch_bounds__(256) void q_x1p(const bf16* __restrict__ s1,
    const bf16* __restrict__ x1, float* __restrict__ X1p){
  int id = blockIdx.x*256 + threadIdx.x;
  int b = id >> 12, k = (id >> 6) & 63, f = id & 63;
  int base = b*N_;
  float a = 0.f;
  for (int n = 0; n < N_; ++n)
    a += b2f(s1[(size_t)(base+n)*64 + k]) * b2f(x1[(size_t)(base+n)*64 + f]);
  X1p[id] = a;
}

// ---------------------------------------------------------------------------
// norm1: losses (mincut1, ortho1); A2 = degnorm(diagzero(adjP)).
__global__ __launch_bounds__(256) void q_norm1(const float* __restrict__ adjP,
    const float* __restrict__ ssP, const float* __restrict__ den,
    float* __restrict__ A2, float* __restrict__ losses){
  __shared__ float aL[4096];
  __shared__ float rL[64];
  __shared__ float red[4];
  int b = blockIdx.x, t = threadIdx.x;
  for (int j = t; j < 4096; j += 256) aL[j] = adjP[(size_t)b*4096 + j];
  __syncthreads();
  if (t == 0){
    float tr = 0.f;
    for (int k = 0; k < 64; ++k) tr += aL[k*64 + k];
    atomicAdd(&losses[0], -(tr/den[b]) * (1.0f/B_));
  }
  if (t < 64){
    float rs = 0.f;
    for (int l = 0; l < 64; ++l) rs += aL[t*64 + l];
    rs -= aL[t*64 + t];                     // diag zeroed before rowsum
    rL[t] = 1.f/(sqrtf(rs) + 1e-15f);
  }
  float pp = 0.f;
  for (int j = t; j < 4096; j += 256){ float v = ssP[(size_t)b*4096 + j]; pp += v*v; }
  #pragma unroll
  for (int o = 32; o >= 1; o >>= 1) pp += __shfl_xor(pp, o);
  if ((t & 63) == 0) red[t >> 6] = pp;
  __syncthreads();                          // publishes red AND rL
  float fro = sqrtf(red[0]+red[1]+red[2]+red[3]);
  __syncthreads();
  float op = 0.f;
  for (int j = t; j < 4096; j += 256){
    int kk = j >> 6, ll = j & 63;
    float v = ssP[(size_t)b*4096 + j]/fro - ((kk==ll) ? 0.125f : 0.f);  // I/sqrt(64)
    op += v*v;
  }
  #pragma unroll
  for (int o = 32; o >= 1; o >>= 1) op += __shfl_xor(op, o);
  if ((t & 63) == 0) red[t >> 6] = op;
  __syncthreads();
  if (t == 0) atomicAdd(&losses[1], sqrtf(red[0]+red[1]+red[2]+red[3]) * (1.0f/B_));
  for (int j = t; j < 4096; j += 256){
    int kk = j >> 6, ll = j & 63;
    A2[(size_t)b*4096 + j] = (kk==ll) ? 0.f : aL[j]*rL[kk]*rL[ll];
  }
}

// ---------------------------------------------------------------------------
// AX[b,n,f] = sum_m A2[b,n,m]*X1p[b,m,f]
__global__ __launch_bounds__(256) void q_ax(const float* __restrict__ A2,
    const float* __restrict__ X1p, float* __restrict__ AX){
  int id = blockIdx.x*256 + threadIdx.x;        // B*4096
  int b = id >> 12, n = (id >> 6) & 63, f = id & 63;
  float a = 0.f;
  for (int m = 0; m < 64; ++m) a += A2[(size_t)b*4096 + n*64 + m]*X1p[(size_t)b*4096 + m*64 + f];
  AX[id] = a;
}
// x2 = relu(AX@W2r + X1p@W2s + b2)
__global__ __launch_bounds__(256) void q_x2(const float* __restrict__ AX,
    const float* __restrict__ X1p, const float* __restrict__ W2r,
    const float* __restrict__ W2s, const float* __restrict__ b2,
    float* __restrict__ x2){
  int id = blockIdx.x*256 + threadIdx.x;        // B*4096
  int b = id >> 12, n = (id >> 6) & 63, f = id & 63;
  float a = b2[f];
  for (int m = 0; m < 64; ++m) a += AX[(size_t)b*4096 + n*64 + m]*W2r[m*64 + f];
  for (int m = 0; m < 64; ++m) a += X1p[(size_t)b*4096 + n*64 + m]*W2s[m*64 + f];
  x2[id] = a > 0.f ? a : 0.f;
}

// ---------------------------------------------------------------------------
// s2 softmax over 32: one THREAD per (b,n).
__global__ __launch_bounds__(256) void q_s2(const float* __restrict__ x2,
    const float* __restrict__ Wp2, const float* __restrict__ bp2,
    float* __restrict__ s2){
  int id = blockIdx.x*256 + threadIdx.x;        // B*64
  if (id >= B_*64) return;
  float lg[32];
  float mx = -1e30f;
  #pragma unroll
  for (int k = 0; k < 32; ++k){
    float a = bp2[k];
    for (int f = 0; f < 64; ++f) a += x2[(size_t)id*64 + f]*Wp2[f*32 + k];
    lg[k] = a; mx = fmaxf(mx, a);
  }
  float ss = 0.f;
  #pragma unroll
  for (int k = 0; k < 32; ++k){ lg[k] = expf(lg[k]-mx); ss += lg[k]; }
  float inv = 1.f/ss;
  #pragma unroll
  for (int k = 0; k < 32; ++k) s2[(size_t)id*32 + k] = lg[k]*inv;
}

// ---------------------------------------------------------------------------
// V[b,n,l] = sum_m A2[b,n,m]*s2[b,m,l]
__global__ __launch_bounds__(256) void q_v(const float* __restrict__ A2,
    const float* __restrict__ s2, float* __restrict__ V){
  int id = blockIdx.x*256 + threadIdx.x;        // B*2048
  int b = id >> 11, n = (id >> 5) & 63, l = id & 31;
  float a = 0.f;
  for (int m = 0; m < 64; ++m) a += A2[(size_t)b*4096 + n*64 + m]*s2[(size_t)b*2048 + m*32 + l];
  V[id] = a;
}
// adj2[b,k,l] = sum_n s2[n,k]*V[n,l] ; ss2 = s2^T s2
__global__ __launch_bounds__(256) void q_adj2(const float* __restrict__ s2,
    const float* __restrict__ V, float* __restrict__ adj2, float* __restrict__ ss2){
  int id = blockIdx.x*256 + threadIdx.x;        // B*1024
  int b = id >> 10, k = (id >> 5) & 31, l = id & 31;
  float a = 0.f, c = 0.f;
  for (int n = 0; n < 64; ++n){
    float sk = s2[(size_t)b*2048 + n*32 + k];
    a += sk*V[(size_t)b*2048 + n*32 + l];
    c += sk*s2[(size_t)b*2048 + n*32 + l];
  }
  adj2[id] = a; ss2[id] = c;
}

// ---------------------------------------------------------------------------
// norm2: losses (mincut2, ortho2); A3 -> ws and out (f32).
__global__ __launch_bounds__(256) void q_norm2(const float* __restrict__ adj2,
    const float* __restrict__ ss2, const float* __restrict__ A2,
    const float* __restrict__ s2, float* __restrict__ A3,
    float* __restrict__ out, float* __restrict__ losses){
  __shared__ float aL[1024];
  __shared__ float sL[1024];
  __shared__ float r2[32];
  __shared__ float red[4];
  __shared__ float den2s;
  int b = blockIdx.x, t = threadIdx.x;
  for (int j = t; j < 1024; j += 256){
    aL[j] = adj2[(size_t)b*1024 + j];
    sL[j] = ss2[(size_t)b*1024 + j];
  }
  __syncthreads();
  if (t < 64){
    float rsA = 0.f;
    for (int m = 0; m < 64; ++m) rsA += A2[(size_t)b*4096 + t*64 + m];
    float q = 0.f;
    for (int k = 0; k < 32; ++k){ float s = s2[(size_t)b*2048 + t*32 + k]; q += s*s; }
    float part = rsA*q;
    #pragma unroll
    for (int o = 32; o >= 1; o >>= 1) part += __shfl_xor(part, o);
    if (t == 0) den2s = part;
  }
  if (t < 32){
    float rs = 0.f;
    for (int l = 0; l < 32; ++l) rs += aL[t*32 + l];
    rs -= aL[t*32 + t];
    r2[t] = 1.f/(sqrtf(rs) + 1e-15f);
  }
  __syncthreads();
  if (t == 0){
    float tr = 0.f;
    for (int k = 0; k < 32; ++k) tr += aL[k*32 + k];
    atomicAdd(&losses[0], -(tr/den2s) * (1.0f/B_));
  }
  float pp = 0.f;
  for (int j = t; j < 1024; j += 256){ float v = sL[j]; pp += v*v; }
  #pragma unroll
  for (int o = 32; o >= 1; o >>= 1) pp += __shfl_xor(pp, o);
  if ((t & 63) == 0) red[t >> 6] = pp;
  __syncthreads();
  float fro = sqrtf(red[0]+red[1]+red[2]+red[3]);
  __syncthreads();
  float op = 0.f;
  for (int j = t; j < 1024; j += 256){
    int kk = j >> 5, ll = j & 31;
    float v = sL[j]/fro - ((kk==ll) ? 0.1767766952966369f : 0.f);  // I/sqrt(32)
    op += v*v;
  }
  #pragma unroll
  for (int o = 32; o >= 1; o >>= 1) op += __shfl_xor(op, o);
  if ((t & 63) == 0) red[t >> 6] = op;
  __syncthreads();
  if (t == 0) atomicAdd(&losses[1], sqrtf(red[0]+red[1]+red[2]+red[3]) * (1.0f/B_));
  for (int j = t; j < 1024; j += 256){
    int kk = j >> 5, ll = j & 31;
    float v = (kk==ll) ? 0.f : aL[j]*r2[kk]*r2[ll];
    A3[(size_t)b*1024 + j] = v;
    out[OFF_ADJ + (size_t)b*1024 + j] = v;
  }
}

// ---------------------------------------------------------------------------
// o2[b,k,f] = sum_n s2[n,k]*x2[n,f]
__global__ __launch_bounds__(256) void q_o2(const float* __restrict__ s2,
    const float* __restrict__ x2, float* __restrict__ o2){
  int id = blockIdx.x*256 + threadIdx.x;        // B*2048
  int b = id >> 11, k = (id >> 6) & 31, f = id & 63;
  float a = 0.f;
  for (int n = 0; n < 64; ++n)
    a += s2[(size_t)b*2048 + n*32 + k]*x2[(size_t)b*4096 + n*64 + f];
  o2[id] = a;
}
// G[b,n,f] = sum_m A3[b,n,m]*o2[b,m,f]
__global__ __launch_bounds__(256) void q_g(const float* __restrict__ A3,
    const float* __restrict__ o2, float* __restrict__ G){
  int id = blockIdx.x*256 + threadIdx.x;        // B*2048
  int b = id >> 11, n = (id >> 6) & 31, f = id & 63;
  float a = 0.f;
  for (int m = 0; m < 32; ++m)
    a += A3[(size_t)b*1024 + n*32 + m]*o2[(size_t)b*2048 + m*64 + f];
  G[id] = a;
}
// x3[b,n,o] -> out (f32)
__global__ __launch_bounds__(256) void q_xout(const float* __restrict__ G,
    const float* __restrict__ o2, const float* __restrict__ W3r,
    const float* __restrict__ W3s, const float* __restrict__ b3,
    float* __restrict__ out){
  int id = blockIdx.x*256 + threadIdx.x;        // B*4096
  int b = id >> 12, n = (id >> 7) & 31, o = id & 127;
  float a = b3[o];
  for (int f = 0; f < 64; ++f) a += G[(size_t)b*2048 + n*64 + f]*W3r[f*128 + o];
  for (int f = 0; f < 64; ++f) a += o2[(size_t)b*2048 + n*64 + f]*W3s[f*128 + o];
  out[(size_t)b*4096 + n*128 + o] = a;
}

// ---------------------------------------------------------------------------
// agg[b,n,l] = sum_k s1[bN+n,k]*s2[b,k,l] -> out (f32)
__global__ __launch_bounds__(256) void q_agg(const bf16* __restrict__ s1,
    const float* __restrict__ s2, float* __restrict__ out){
  int id = blockIdx.x*256 + threadIdx.x;        // B*16384
  int b = id >> 14, n = (id >> 5) & 511, l = id & 31;
  float a = 0.f;
  for (int k = 0; k < 64; ++k)
    a += b2f(s1[((size_t)b*N_ + n)*64 + k]) * s2[(size_t)b*2048 + k*32 + l];
  out[OFF_AGG + ((size_t)b*N_ + n)*32 + l] = a;
}

// ---------------------------------------------------------------------------
__global__ void q_loss(const float* losses, float* out){
  if (threadIdx.x == 0){
    out[OFF_MC] = losses[0];
    out[OFF_O]  = losses[1];
  }
}

// ===========================================================================
extern "C" void kernel_launch(void* const* d_in, const int* in_sizes, int n_in,
                              void* d_out, int out_size, void* d_ws, size_t ws_size,
                              hipStream_t stream){
  (void)out_size;
  float* out = (float*)d_out;

  static const long long EXP_SIZES[16] = {
    8388608LL, 2097152LL, 1048576LL, 65536LL,
    8192LL, 64LL, 4096LL, 64LL,
    4096LL, 64LL, 4096LL, 2048LL, 32LL,
    8192LL, 128LL, 8192LL };
  if (n_in != 16){ q_sent<<<1,64,0,stream>>>(out, exp2f(36.f)); return; }
  for (int i = 0; i < 16; ++i){
    if ((long long)in_sizes[i] != EXP_SIZES[i]){
      q_sent<<<1,64,0,stream>>>(out, exp2f((float)(37+i))); return;
    }
  }

  const float* pos = (const float*)d_in[0];
  const int*   ei  = (const int*)  d_in[1];
  const float* ea  = (const float*)d_in[2];
  const float* W1  = (const float*)d_in[4];
  const float* b1  = (const float*)d_in[5];
  const float* Wp1 = (const float*)d_in[6];
  const float* bp1 = (const float*)d_in[7];
  const float* W2r = (const float*)d_in[8];
  const float* b2  = (const float*)d_in[9];
  const float* W2s = (const float*)d_in[10];
  const float* Wp2 = (const float*)d_in[11];
  const float* bp2 = (const float*)d_in[12];
  const float* W3r = (const float*)d_in[13];
  const float* b3  = (const float*)d_in[14];
  const float* W3s = (const float*)d_in[15];

  // ---- workspace (~43 MB); only aliasing: xw -> U (xw dead after q_gcn)
  char* w = (char*)d_ws;
  float* dis    = (float*)w; w += (size_t)NT_*4;        // 256 KB
  float* drow   = (float*)w; w += (size_t)NT_*4;        // 256 KB
  float* den    = (float*)w; w += (size_t)B_*4;
  float* losses = (float*)w; w += 64;
  float* ew     = (float*)w; w += (size_t)E_*4;         // 4 MB
  float* adjP   = (float*)w; w += (size_t)B_*4096*4;    // 2 MB
  float* ssP    = (float*)w; w += (size_t)B_*4096*4;    // 2 MB
  float* X1p    = (float*)w; w += (size_t)B_*4096*4;    // 2 MB
  float* A2     = (float*)w; w += (size_t)B_*4096*4;    // 2 MB
  float* AX     = (float*)w; w += (size_t)B_*4096*4;    // 2 MB
  float* x2     = (float*)w; w += (size_t)B_*4096*4;    // 2 MB
  float* s2     = (float*)w; w += (size_t)B_*2048*4;    // 1 MB
  float* V      = (float*)w; w += (size_t)B_*2048*4;    // 1 MB
  float* adj2   = (float*)w; w += (size_t)B_*1024*4;    // 0.5 MB
  float* ss2    = (float*)w; w += (size_t)B_*1024*4;    // 0.5 MB
  float* A3     = (float*)w; w += (size_t)B_*1024*4;    // 0.5 MB
  float* o2     = (float*)w; w += (size_t)B_*2048*4;    // 1 MB
  float* G      = (float*)w; w += (size_t)B_*2048*4;    // 1 MB
  bf16*  xwU    = (bf16*)w;  w += (size_t)NT_*64*2;     // 8 MB (xw, then U)
  bf16*  x1     = (bf16*)w;  w += (size_t)NT_*64*2;     // 8 MB
  bf16*  s1     = (bf16*)w;  w += (size_t)NT_*64*2;     // 8 MB
  size_t need = (size_t)(w - (char*)d_ws);
  if (ws_size < need){ q_sent<<<1,64,0,stream>>>(out, exp2f(20.f)); return; }

  q_init <<<1,    256, 0, stream>>>(den, losses);
  q_deg  <<<B_,   256, 0, stream>>>(ei, ea, dis, drow);
  q_prep <<<E_/256,256,0, stream>>>(ei, ea, dis, ew);
  q_xw   <<<16384,256, 0, stream>>>(pos, W1, xwU);
  q_gcn  <<<B_*4, 512, 0, stream>>>(ei, ew, dis, xwU, b1, x1);
  q_s1   <<<NT_/4,256, 0, stream>>>(x1, Wp1, bp1, drow, s1, den);
  q_u    <<<B_*4, 512, 0, stream>>>(ei, s1, xwU);            // xwU := U
  q_adjp <<<2048, 256, 0, stream>>>(s1, xwU, adjP);
  q_ssp  <<<2048, 256, 0, stream>>>(s1, ssP);
  q_x1p  <<<2048, 256, 0, stream>>>(s1, x1, X1p);
  q_norm1<<<B_,   256, 0, stream>>>(adjP, ssP, den, A2, losses);
  q_ax   <<<2048, 256, 0, stream>>>(A2, X1p, AX);
  q_x2   <<<2048, 256, 0, stream>>>(AX, X1p, W2r, W2s, b2, x2);
  q_s2   <<<32,   256, 0, stream>>>(x2, Wp2, bp2, s2);
  q_v    <<<1024, 256, 0, stream>>>(A2, s2, V);
  q_adj2 <<<512,  256, 0, stream>>>(s2, V, adj2, ss2);
  q_norm2<<<B_,   256, 0, stream>>>(adj2, ss2, A2, s2, A3, out, losses);
  q_o2   <<<1024, 256, 0, stream>>>(s2, x2, o2);
  q_g    <<<1024, 256, 0, stream>>>(A3, o2, G);
  q_xout <<<2048, 256, 0, stream>>>(G, o2, W3r, W3s, b3, out);
  q_agg  <<<8192, 256, 0, stream>>>(s1, s2, out);
  q_loss <<<1,     64, 0, stream>>>(losses, out);
}

// Round 13
// 1371.881 us; speedup vs baseline: 12.3415x; 1.1503x over previous
//
#include <hip/hip_runtime.h>
#include <hip/hip_bf16.h>

// ============================================================================
// FrameAggregator — ROUND 13:
//  * q_s1: LDS-staged Wp1 + shuffle-broadcast x1 row (no loads in inner loop)
//  * q_p3: fused adjP/ssP/X1p as one LDS-tiled triple-GEMM per graph
// Everything else identical to the round-12 passing pipeline.
// ============================================================================

typedef __hip_bfloat16 bf16;
#define DEV static __device__ __forceinline__
DEV float b2f(bf16 x){ return __bfloat162float(x); }
DEV bf16  f2b(float x){ return __float2bfloat16(x); }

constexpr int B_  = 128;
constexpr int N_  = 512;
constexpr int EG_ = 8192;
constexpr int E_  = B_*EG_;     // 1048576
constexpr int NT_ = B_*N_;      // 65536

constexpr size_t OFF_MC  = (size_t)B_*32*128;                 // 524288
constexpr size_t OFF_O   = OFF_MC + 1;
constexpr size_t OFF_AGG = OFF_O + 1;                         // 524290
constexpr size_t OFF_ADJ = OFF_AGG + (size_t)B_*N_*32;        // 2621442

// ---------------------------------------------------------------------------
__global__ void q_init(float* den, float* losses){
  int i = threadIdx.x;
  if (i < B_) den[i] = 0.f;
  if (i < 2)  losses[i] = 0.f;
}
__global__ void q_sent(float* out, float v){
  if (threadIdx.x == 0) out[0] = v;
}

// ---------------------------------------------------------------------------
// deg/drow via LDS scatter: block per graph.
__global__ __launch_bounds__(256) void q_deg(const int* __restrict__ ei,
    const float* __restrict__ ea, float* __restrict__ dis, float* __restrict__ drow){
  __shared__ float degL[N_];
  __shared__ float drL[N_];
  int t = threadIdx.x, b = blockIdx.x, base = b*N_;
  for (int j=t; j<N_; j+=256){ degL[j] = 1.0f; drL[j] = 0.f; }  // 1.0 = self loop
  __syncthreads();
  int e0 = b*EG_;
  for (int j=t; j<EG_; j+=256){
    int e = e0 + j;
    int r = ei[e], c = ei[E_+e];
    atomicAdd(&degL[c-base], ea[e]);
    atomicAdd(&drL [r-base], 1.0f);
  }
  __syncthreads();
  for (int j=t; j<N_; j+=256){
    dis [base+j] = rsqrtf(degL[j]);
    drow[base+j] = drL[j];
  }
}

// ---------------------------------------------------------------------------
// ew[e] = dis[r]*ea[e]*dis[c]
__global__ __launch_bounds__(256) void q_prep(const int* __restrict__ ei,
    const float* __restrict__ ea, const float* __restrict__ dis,
    float* __restrict__ ew){
  int e = blockIdx.x*256 + threadIdx.x;
  ew[e] = dis[ei[e]] * ea[e] * dis[ei[E_+e]];
}

// ---------------------------------------------------------------------------
// xw[n,f] = sum_c pos[n,c] * W1[c,f]
__global__ __launch_bounds__(256) void q_xw(const float* __restrict__ pos,
    const float* __restrict__ W1, bf16* __restrict__ xw){
  int id = blockIdx.x*256 + threadIdx.x;        // NT*64
  int n = id >> 6, f = id & 63;
  float a = 0.f;
  for (int c = 0; c < 128; ++c) a += pos[(size_t)n*128 + c] * W1[c*64 + f];
  xw[id] = f2b(a);
}

// ---------------------------------------------------------------------------
// GCN conv, 4 blocks/graph (16-feature slice each). LDS h[512][17] f32.
__global__ __launch_bounds__(512) void q_gcn(const int* __restrict__ ei,
    const float* __restrict__ ew, const float* __restrict__ dis,
    const bf16* __restrict__ xw, const float* __restrict__ b1,
    bf16* __restrict__ x1){
  __shared__ float hacc[N_*17];    // 34816 B
  int t = threadIdx.x, blk = blockIdx.x;
  int b = blk >> 2, f0 = (blk & 3)*16;
  int base = b*N_;
  for (int j=t; j<N_*16; j+=512){
    int n = j>>4, f = j&15;
    float d = dis[base+n];
    hacc[n*17 + f] = d*d*b2f(xw[(size_t)(base+n)*64 + f0 + f]);
  }
  __syncthreads();
  int wv = t>>6, grp = (t>>4)&3, f = t&15;
  int ebase = b*EG_ + wv*1024 + grp;
  for (int j=0; j<1024; j+=16){
    int e = ebase + j;
    int r0 = ei[e],    c0 = ei[E_+e];
    int r1 = ei[e+4],  c1 = ei[E_+e+4];
    int r2 = ei[e+8],  c2 = ei[E_+e+8];
    int r3 = ei[e+12], c3 = ei[E_+e+12];
    float w0 = ew[e],  w1 = ew[e+4], w2 = ew[e+8], w3 = ew[e+12];
    float v0 = b2f(xw[(size_t)r0*64 + f0 + f]);
    float v1 = b2f(xw[(size_t)r1*64 + f0 + f]);
    float v2 = b2f(xw[(size_t)r2*64 + f0 + f]);
    float v3 = b2f(xw[(size_t)r3*64 + f0 + f]);
    atomicAdd(&hacc[(c0-base)*17 + f], w0*v0);
    atomicAdd(&hacc[(c1-base)*17 + f], w1*v1);
    atomicAdd(&hacc[(c2-base)*17 + f], w2*v2);
    atomicAdd(&hacc[(c3-base)*17 + f], w3*v3);
  }
  __syncthreads();
  for (int j=t; j<N_*16; j+=512){
    int n = j>>4, f = j&15;
    float v = hacc[n*17 + f] + b1[f0 + f];
    x1[(size_t)(base+n)*64 + f0 + f] = f2b(v > 0.f ? v : 0.f);
  }
}

// ---------------------------------------------------------------------------
// s1 softmax: Wp1 staged in LDS; x1 row held in-lane, broadcast via shuffle.
// Wave per 8 nodes; no global loads in the inner loop.
__global__ __launch_bounds__(256) void q_s1(const bf16* __restrict__ x1,
    const float* __restrict__ Wp1, const float* __restrict__ bp1,
    const float* __restrict__ drow, bf16* __restrict__ s1, float* __restrict__ den){
  __shared__ float wL[64][64];     // Wp1[f][k], 16 KB
  int t = threadIdx.x;
  for (int j=t; j<4096; j+=256) ((float*)wL)[j] = Wp1[j];
  __syncthreads();
  int wv = t>>6, k = t&63;
  int n0 = blockIdx.x*32 + wv*8;   // 4 waves x 8 nodes
  float bp = bp1[k];
  for (int i=0;i<8;++i){
    int n = n0 + i;
    float xv = b2f(x1[(size_t)n*64 + k]);   // lane k holds x1[n][k]
    float lg = bp;
    #pragma unroll
    for (int f=0; f<64; ++f)
      lg += __shfl(xv, f) * wL[f][k];
    float m = lg;
    #pragma unroll
    for (int o=32;o>=1;o>>=1) m = fmaxf(m, __shfl_xor(m, o));
    float p = expf(lg - m);
    float s = p;
    #pragma unroll
    for (int o=32;o>=1;o>>=1) s += __shfl_xor(s, o);
    float sv = p / s;
    s1[(size_t)n*64 + k] = f2b(sv);
    float q = sv*sv;
    #pragma unroll
    for (int o=32;o>=1;o>>=1) q += __shfl_xor(q, o);
    if (k == 0) atomicAdd(&den[n >> 9], q * drow[n]);
  }
}

// ---------------------------------------------------------------------------
// U = A @ s1, 4 blocks/graph (16-cluster slice). Per edge (r,c): U[r]+=s1[c].
__global__ __launch_bounds__(512) void q_u(const int* __restrict__ ei,
    const bf16* __restrict__ s1, bf16* __restrict__ U){
  __shared__ float uacc[N_*17];    // 34816 B
  int t = threadIdx.x, blk = blockIdx.x;
  int b = blk >> 2, f0 = (blk & 3)*16;
  int base = b*N_;
  for (int j=t; j<N_*17; j+=512) uacc[j] = 0.f;
  __syncthreads();
  int wv = t>>6, grp = (t>>4)&3, f = t&15;
  int ebase = b*EG_ + wv*1024 + grp;
  for (int j=0; j<1024; j+=16){
    int e = ebase + j;
    int r0 = ei[e],    c0 = ei[E_+e];
    int r1 = ei[e+4],  c1 = ei[E_+e+4];
    int r2 = ei[e+8],  c2 = ei[E_+e+8];
    int r3 = ei[e+12], c3 = ei[E_+e+12];
    float v0 = b2f(s1[(size_t)c0*64 + f0 + f]);
    float v1 = b2f(s1[(size_t)c1*64 + f0 + f]);
    float v2 = b2f(s1[(size_t)c2*64 + f0 + f]);
    float v3 = b2f(s1[(size_t)c3*64 + f0 + f]);
    atomicAdd(&uacc[(r0-base)*17 + f], v0);
    atomicAdd(&uacc[(r1-base)*17 + f], v1);
    atomicAdd(&uacc[(r2-base)*17 + f], v2);
    atomicAdd(&uacc[(r3-base)*17 + f], v3);
  }
  __syncthreads();
  for (int j=t; j<N_*16; j+=512){
    int n = j>>4, f = j&15;
    U[(size_t)(base+n)*64 + f0 + f] = f2b(uacc[n*17 + f]);
  }
}

// ---------------------------------------------------------------------------
// q_p3: fused adjP = s^T U, ssP = s^T s, X1p = s^T x1 (one graph per block).
// 64-node chunks staged in LDS; each thread owns 4x4 tiles of all 3 outputs.
__global__ __launch_bounds__(256) void q_p3(const bf16* __restrict__ s1,
    const bf16* __restrict__ U, const bf16* __restrict__ x1,
    float* __restrict__ adjP, float* __restrict__ ssP, float* __restrict__ X1p){
  __shared__ float sL[64][64];     // 16 KB each
  __shared__ float uL[64][64];
  __shared__ float xL[64][64];
  int t = threadIdx.x, b = blockIdx.x, base = b*N_;
  int ti = t>>4, tj = t&15;        // 16x16 grid, 4(k) x 4(l) per thread
  float accA[4][4], accS[4][4], accX[4][4];
  #pragma unroll
  for (int i=0;i<4;i++)
    #pragma unroll
    for (int j=0;j<4;j++){ accA[i][j]=0.f; accS[i][j]=0.f; accX[i][j]=0.f; }
  for (int c=0; c<8; ++c){
    __syncthreads();
    for (int j=t; j<4096; j+=256){
      int n = j>>6, q = j&63;
      size_t g = (size_t)(base + c*64 + n)*64 + q;
      sL[n][q] = b2f(s1[g]);
      uL[n][q] = b2f(U [g]);
      xL[n][q] = b2f(x1[g]);
    }
    __syncthreads();
    for (int n=0; n<64; ++n){
      float4 skv = *reinterpret_cast<const float4*>(&sL[n][ti*4]);
      float4 ulv = *reinterpret_cast<const float4*>(&uL[n][tj*4]);
      float4 xlv = *reinterpret_cast<const float4*>(&xL[n][tj*4]);
      float4 slv = *reinterpret_cast<const float4*>(&sL[n][tj*4]);
      float sk[4] = {skv.x, skv.y, skv.z, skv.w};
      float ul[4] = {ulv.x, ulv.y, ulv.z, ulv.w};
      float xl[4] = {xlv.x, xlv.y, xlv.z, xlv.w};
      float sl[4] = {slv.x, slv.y, slv.z, slv.w};
      #pragma unroll
      for (int i=0;i<4;i++)
        #pragma unroll
        for (int j=0;j<4;j++){
          accA[i][j] += sk[i]*ul[j];
          accS[i][j] += sk[i]*sl[j];
          accX[i][j] += sk[i]*xl[j];
        }
    }
  }
  #pragma unroll
  for (int i=0;i<4;i++)
    #pragma unroll
    for (int j=0;j<4;j++){
      size_t o = (size_t)b*4096 + (ti*4+i)*64 + tj*4+j;
      adjP[o] = accA[i][j];
      ssP [o] = accS[i][j];
      X1p [o] = accX[i][j];
    }
}

// ---------------------------------------------------------------------------
// norm1: losses (mincut1, ortho1); A2 = degnorm(diagzero(adjP)).
__global__ __launch_bounds__(256) void q_norm1(const float* __restrict__ adjP,
    const float* __restrict__ ssP, const float* __restrict__ den,
    float* __restrict__ A2, float* __restrict__ losses){
  __shared__ float aL[4096];
  __shared__ float rL[64];
  __shared__ float red[4];
  int b = blockIdx.x, t = threadIdx.x;
  for (int j = t; j < 4096; j += 256) aL[j] = adjP[(size_t)b*4096 + j];
  __syncthreads();
  if (t == 0){
    float tr = 0.f;
    for (int k = 0; k < 64; ++k) tr += aL[k*64 + k];
    atomicAdd(&losses[0], -(tr/den[b]) * (1.0f/B_));
  }
  if (t < 64){
    float rs = 0.f;
    for (int l = 0; l < 64; ++l) rs += aL[t*64 + l];
    rs -= aL[t*64 + t];                     // diag zeroed before rowsum
    rL[t] = 1.f/(sqrtf(rs) + 1e-15f);
  }
  float pp = 0.f;
  for (int j = t; j < 4096; j += 256){ float v = ssP[(size_t)b*4096 + j]; pp += v*v; }
  #pragma unroll
  for (int o = 32; o >= 1; o >>= 1) pp += __shfl_xor(pp, o);
  if ((t & 63) == 0) red[t >> 6] = pp;
  __syncthreads();                          // publishes red AND rL
  float fro = sqrtf(red[0]+red[1]+red[2]+red[3]);
  __syncthreads();
  float op = 0.f;
  for (int j = t; j < 4096; j += 256){
    int kk = j >> 6, ll = j & 63;
    float v = ssP[(size_t)b*4096 + j]/fro - ((kk==ll) ? 0.125f : 0.f);  // I/sqrt(64)
    op += v*v;
  }
  #pragma unroll
  for (int o = 32; o >= 1; o >>= 1) op += __shfl_xor(op, o);
  if ((t & 63) == 0) red[t >> 6] = op;
  __syncthreads();
  if (t == 0) atomicAdd(&losses[1], sqrtf(red[0]+red[1]+red[2]+red[3]) * (1.0f/B_));
  for (int j = t; j < 4096; j += 256){
    int kk = j >> 6, ll = j & 63;
    A2[(size_t)b*4096 + j] = (kk==ll) ? 0.f : aL[j]*rL[kk]*rL[ll];
  }
}

// ---------------------------------------------------------------------------
// AX[b,n,f] = sum_m A2[b,n,m]*X1p[b,m,f]
__global__ __launch_bounds__(256) void q_ax(const float* __restrict__ A2,
    const float* __restrict__ X1p, float* __restrict__ AX){
  int id = blockIdx.x*256 + threadIdx.x;        // B*4096
  int b = id >> 12, n = (id >> 6) & 63, f = id & 63;
  float a = 0.f;
  for (int m = 0; m < 64; ++m) a += A2[(size_t)b*4096 + n*64 + m]*X1p[(size_t)b*4096 + m*64 + f];
  AX[id] = a;
}
// x2 = relu(AX@W2r + X1p@W2s + b2)
__global__ __launch_bounds__(256) void q_x2(const float* __restrict__ AX,
    const float* __restrict__ X1p, const float* __restrict__ W2r,
    const float* __restrict__ W2s, const float* __restrict__ b2,
    float* __restrict__ x2){
  int id = blockIdx.x*256 + threadIdx.x;        // B*4096
  int b = id >> 12, n = (id >> 6) & 63, f = id & 63;
  float a = b2[f];
  for (int m = 0; m < 64; ++m) a += AX[(size_t)b*4096 + n*64 + m]*W2r[m*64 + f];
  for (int m = 0; m < 64; ++m) a += X1p[(size_t)b*4096 + n*64 + m]*W2s[m*64 + f];
  x2[id] = a > 0.f ? a : 0.f;
}

// ---------------------------------------------------------------------------
// s2 softmax over 32: one THREAD per (b,n).
__global__ __launch_bounds__(256) void q_s2(const float* __restrict__ x2,
    const float* __restrict__ Wp2, const float* __restrict__ bp2,
    float* __restrict__ s2){
  int id = blockIdx.x*256 + threadIdx.x;        // B*64
  if (id >= B_*64) return;
  float lg[32];
  float mx = -1e30f;
  #pragma unroll
  for (int k = 0; k < 32; ++k){
    float a = bp2[k];
    for (int f = 0; f < 64; ++f) a += x2[(size_t)id*64 + f]*Wp2[f*32 + k];
    lg[k] = a; mx = fmaxf(mx, a);
  }
  float ss = 0.f;
  #pragma unroll
  for (int k = 0; k < 32; ++k){ lg[k] = expf(lg[k]-mx); ss += lg[k]; }
  float inv = 1.f/ss;
  #pragma unroll
  for (int k = 0; k < 32; ++k) s2[(size_t)id*32 + k] = lg[k]*inv;
}

// ---------------------------------------------------------------------------
// V[b,n,l] = sum_m A2[b,n,m]*s2[b,m,l]
__global__ __launch_bounds__(256) void q_v(const float* __restrict__ A2,
    const float* __restrict__ s2, float* __restrict__ V){
  int id = blockIdx.x*256 + threadIdx.x;        // B*2048
  int b = id >> 11, n = (id >> 5) & 63, l = id & 31;
  float a = 0.f;
  for (int m = 0; m < 64; ++m) a += A2[(size_t)b*4096 + n*64 + m]*s2[(size_t)b*2048 + m*32 + l];
  V[id] = a;
}
// adj2[b,k,l] = sum_n s2[n,k]*V[n,l] ; ss2 = s2^T s2
__global__ __launch_bounds__(256) void q_adj2(const float* __restrict__ s2,
    const float* __restrict__ V, float* __restrict__ adj2, float* __restrict__ ss2){
  int id = blockIdx.x*256 + threadIdx.x;        // B*1024
  int b = id >> 10, k = (id >> 5) & 31, l = id & 31;
  float a = 0.f, c = 0.f;
  for (int n = 0; n < 64; ++n){
    float sk = s2[(size_t)b*2048 + n*32 + k];
    a += sk*V[(size_t)b*2048 + n*32 + l];
    c += sk*s2[(size_t)b*2048 + n*32 + l];
  }
  adj2[id] = a; ss2[id] = c;
}

// ---------------------------------------------------------------------------
// norm2: losses (mincut2, ortho2); A3 -> ws and out (f32).
__global__ __launch_bounds__(256) void q_norm2(const float* __restrict__ adj2,
    const float* __restrict__ ss2, const float* __restrict__ A2,
    const float* __restrict__ s2, float* __restrict__ A3,
    float* __restrict__ out, float* __restrict__ losses){
  __shared__ float aL[1024];
  __shared__ float sL[1024];
  __shared__ float r2[32];
  __shared__ float red[4];
  __shared__ float den2s;
  int b = blockIdx.x, t = threadIdx.x;
  for (int j = t; j < 1024; j += 256){
    aL[j] = adj2[(size_t)b*1024 + j];
    sL[j] = ss2[(size_t)b*1024 + j];
  }
  __syncthreads();
  if (t < 64){
    float rsA = 0.f;
    for (int m = 0; m < 64; ++m) rsA += A2[(size_t)b*4096 + t*64 + m];
    float q = 0.f;
    for (int k = 0; k < 32; ++k){ float s = s2[(size_t)b*2048 + t*32 + k]; q += s*s; }
    float part = rsA*q;
    #pragma unroll
    for (int o = 32; o >= 1; o >>= 1) part += __shfl_xor(part, o);
    if (t == 0) den2s = part;
  }
  if (t < 32){
    float rs = 0.f;
    for (int l = 0; l < 32; ++l) rs += aL[t*32 + l];
    rs -= aL[t*32 + t];
    r2[t] = 1.f/(sqrtf(rs) + 1e-15f);
  }
  __syncthreads();
  if (t == 0){
    float tr = 0.f;
    for (int k = 0; k < 32; ++k) tr += aL[k*32 + k];
    atomicAdd(&losses[0], -(tr/den2s) * (1.0f/B_));
  }
  float pp = 0.f;
  for (int j = t; j < 1024; j += 256){ float v = sL[j]; pp += v*v; }
  #pragma unroll
  for (int o = 32; o >= 1; o >>= 1) pp += __shfl_xor(pp, o);
  if ((t & 63) == 0) red[t >> 6] = pp;
  __syncthreads();
  float fro = sqrtf(red[0]+red[1]+red[2]+red[3]);
  __syncthreads();
  float op = 0.f;
  for (int j = t; j < 1024; j += 256){
    int kk = j >> 5, ll = j & 31;
    float v = sL[j]/fro - ((kk==ll) ? 0.1767766952966369f : 0.f);  // I/sqrt(32)
    op += v*v;
  }
  #pragma unroll
  for (int o = 32; o >= 1; o >>= 1) op += __shfl_xor(op, o);
  if ((t & 63) == 0) red[t >> 6] = op;
  __syncthreads();
  if (t == 0) atomicAdd(&losses[1], sqrtf(red[0]+red[1]+red[2]+red[3]) * (1.0f/B_));
  for (int j = t; j < 1024; j += 256){
    int kk = j >> 5, ll = j & 31;
    float v = (kk==ll) ? 0.f : aL[j]*r2[kk]*r2[ll];
    A3[(size_t)b*1024 + j] = v;
    out[OFF_ADJ + (size_t)b*1024 + j] = v;
  }
}

// ---------------------------------------------------------------------------
// o2[b,k,f] = sum_n s2[n,k]*x2[n,f]
__global__ __launch_bounds__(256) void q_o2(const float* __restrict__ s2,
    const float* __restrict__ x2, float* __restrict__ o2){
  int id = blockIdx.x*256 + threadIdx.x;        // B*2048
  int b = id >> 11, k = (id >> 6) & 31, f = id & 63;
  float a = 0.f;
  for (int n = 0; n < 64; ++n)
    a += s2[(size_t)b*2048 + n*32 + k]*x2[(size_t)b*4096 + n*64 + f];
  o2[id] = a;
}
// G[b,n,f] = sum_m A3[b,n,m]*o2[b,m,f]
__global__ __launch_bounds__(256) void q_g(const float* __restrict__ A3,
    const float* __restrict__ o2, float* __restrict__ G){
  int id = blockIdx.x*256 + threadIdx.x;        // B*2048
  int b = id >> 11, n = (id >> 6) & 31, f = id & 63;
  float a = 0.f;
  for (int m = 0; m < 32; ++m)
    a += A3[(size_t)b*1024 + n*32 + m]*o2[(size_t)b*2048 + m*64 + f];
  G[id] = a;
}
// x3[b,n,o] -> out (f32)
__global__ __launch_bounds__(256) void q_xout(const float* __restrict__ G,
    const float* __restrict__ o2, const float* __restrict__ W3r,
    const float* __restrict__ W3s, const float* __restrict__ b3,
    float* __restrict__ out){
  int id = blockIdx.x*256 + threadIdx.x;        // B*4096
  int b = id >> 12, n = (id >> 7) & 31, o = id & 127;
  float a = b3[o];
  for (int f = 0; f < 64; ++f) a += G[(size_t)b*2048 + n*64 + f]*W3r[f*128 + o];
  for (int f = 0; f < 64; ++f) a += o2[(size_t)b*2048 + n*64 + f]*W3s[f*128 + o];
  out[(size_t)b*4096 + n*128 + o] = a;
}

// ---------------------------------------------------------------------------
// agg[b,n,l] = sum_k s1[bN+n,k]*s2[b,k,l] -> out (f32)
__global__ __launch_bounds__(256) void q_agg(const bf16* __restrict__ s1,
    const float* __restrict__ s2, float* __restrict__ out){
  int id = blockIdx.x*256 + threadIdx.x;        // B*16384
  int b = id >> 14, n = (id >> 5) & 511, l = id & 31;
  float a = 0.f;
  for (int k = 0; k < 64; ++k)
    a += b2f(s1[((size_t)b*N_ + n)*64 + k]) * s2[(size_t)b*2048 + k*32 + l];
  out[OFF_AGG + ((size_t)b*N_ + n)*32 + l] = a;
}

// ---------------------------------------------------------------------------
__global__ void q_loss(const float* losses, float* out){
  if (threadIdx.x == 0){
    out[OFF_MC] = losses[0];
    out[OFF_O]  = losses[1];
  }
}

// ===========================================================================
extern "C" void kernel_launch(void* const* d_in, const int* in_sizes, int n_in,
                              void* d_out, int out_size, void* d_ws, size_t ws_size,
                              hipStream_t stream){
  (void)out_size;
  float* out = (float*)d_out;

  static const long long EXP_SIZES[16] = {
    8388608LL, 2097152LL, 1048576LL, 65536LL,
    8192LL, 64LL, 4096LL, 64LL,
    4096LL, 64LL, 4096LL, 2048LL, 32LL,
    8192LL, 128LL, 8192LL };
  if (n_in != 16){ q_sent<<<1,64,0,stream>>>(out, exp2f(36.f)); return; }
  for (int i = 0; i < 16; ++i){
    if ((long long)in_sizes[i] != EXP_SIZES[i]){
      q_sent<<<1,64,0,stream>>>(out, exp2f((float)(37+i))); return;
    }
  }

  const float* pos = (const float*)d_in[0];
  const int*   ei  = (const int*)  d_in[1];
  const float* ea  = (const float*)d_in[2];
  const float* W1  = (const float*)d_in[4];
  const float* b1  = (const float*)d_in[5];
  const float* Wp1 = (const float*)d_in[6];
  const float* bp1 = (const float*)d_in[7];
  const float* W2r = (const float*)d_in[8];
  const float* b2  = (const float*)d_in[9];
  const float* W2s = (const float*)d_in[10];
  const float* Wp2 = (const float*)d_in[11];
  const float* bp2 = (const float*)d_in[12];
  const float* W3r = (const float*)d_in[13];
  const float* b3  = (const float*)d_in[14];
  const float* W3s = (const float*)d_in[15];

  // ---- workspace (~43 MB); only aliasing: xw -> U (xw dead after q_gcn)
  char* w = (char*)d_ws;
  float* dis    = (float*)w; w += (size_t)NT_*4;        // 256 KB
  float* drow   = (float*)w; w += (size_t)NT_*4;        // 256 KB
  float* den    = (float*)w; w += (size_t)B_*4;
  float* losses = (float*)w; w += 64;
  float* ew     = (float*)w; w += (size_t)E_*4;         // 4 MB
  float* adjP   = (float*)w; w += (size_t)B_*4096*4;    // 2 MB
  float* ssP    = (float*)w; w += (size_t)B_*4096*4;    // 2 MB
  float* X1p    = (float*)w; w += (size_t)B_*4096*4;    // 2 MB
  float* A2     = (float*)w; w += (size_t)B_*4096*4;    // 2 MB
  float* AX     = (float*)w; w += (size_t)B_*4096*4;    // 2 MB
  float* x2     = (float*)w; w += (size_t)B_*4096*4;    // 2 MB
  float* s2     = (float*)w; w += (size_t)B_*2048*4;    // 1 MB
  float* V      = (float*)w; w += (size_t)B_*2048*4;    // 1 MB
  float* adj2   = (float*)w; w += (size_t)B_*1024*4;    // 0.5 MB
  float* ss2    = (float*)w; w += (size_t)B_*1024*4;    // 0.5 MB
  float* A3     = (float*)w; w += (size_t)B_*1024*4;    // 0.5 MB
  float* o2     = (float*)w; w += (size_t)B_*2048*4;    // 1 MB
  float* G      = (float*)w; w += (size_t)B_*2048*4;    // 1 MB
  bf16*  xwU    = (bf16*)w;  w += (size_t)NT_*64*2;     // 8 MB (xw, then U)
  bf16*  x1     = (bf16*)w;  w += (size_t)NT_*64*2;     // 8 MB
  bf16*  s1     = (bf16*)w;  w += (size_t)NT_*64*2;     // 8 MB
  size_t need = (size_t)(w - (char*)d_ws);
  if (ws_size < need){ q_sent<<<1,64,0,stream>>>(out, exp2f(20.f)); return; }

  q_init <<<1,    256, 0, stream>>>(den, losses);
  q_deg  <<<B_,   256, 0, stream>>>(ei, ea, dis, drow);
  q_prep <<<E_/256,256,0, stream>>>(ei, ea, dis, ew);
  q_xw   <<<16384,256, 0, stream>>>(pos, W1, xwU);
  q_gcn  <<<B_*4, 512, 0, stream>>>(ei, ew, dis, xwU, b1, x1);
  q_s1   <<<NT_/32,256, 0, stream>>>(x1, Wp1, bp1, drow, s1, den);
  q_u    <<<B_*4, 512, 0, stream>>>(ei, s1, xwU);            // xwU := U
  q_p3   <<<B_,   256, 0, stream>>>(s1, xwU, x1, adjP, ssP, X1p);
  q_norm1<<<B_,   256, 0, stream>>>(adjP, ssP, den, A2, losses);
  q_ax   <<<2048, 256, 0, stream>>>(A2, X1p, AX);
  q_x2   <<<2048, 256, 0, stream>>>(AX, X1p, W2r, W2s, b2, x2);
  q_s2   <<<32,   256, 0, stream>>>(x2, Wp2, bp2, s2);
  q_v    <<<1024, 256, 0, stream>>>(A2, s2, V);
  q_adj2 <<<512,  256, 0, stream>>>(s2, V, adj2, ss2);
  q_norm2<<<B_,   256, 0, stream>>>(adj2, ss2, A2, s2, A3, out, losses);
  q_o2   <<<1024, 256, 0, stream>>>(s2, x2, o2);
  q_g    <<<1024, 256, 0, stream>>>(A3, o2, G);
  q_xout <<<2048, 256, 0, stream>>>(G, o2, W3r, W3s, b3, out);
  q_agg  <<<8192, 256, 0, stream>>>(s1, s2, out);
  q_loss <<<1,     64, 0, stream>>>(losses, out);
}

// Round 14
// 916.819 us; speedup vs baseline: 18.4672x; 1.4963x over previous
//
#include <hip/hip_runtime.h>
#include <hip/hip_bf16.h>

// ============================================================================
// FrameAggregator — ROUND 14: CSR edge kernels.
//  * q_csr: per-graph CSR (by-col with fused weight, by-row) in one pass.
//  * q_gcn/q_u: one WAVE per destination node, register accumulator,
//    coalesced 128B row gathers, zero LDS/atomics, each edge visited once.
//  * ws unions CSR arrays with later-phase buffers -> 42.5 MB total.
// Everything else identical to the round-13 passing pipeline.
// ============================================================================

typedef __hip_bfloat16 bf16;
#define DEV static __device__ __forceinline__
DEV float b2f(bf16 x){ return __bfloat162float(x); }
DEV bf16  f2b(float x){ return __float2bfloat16(x); }

constexpr int B_  = 128;
constexpr int N_  = 512;
constexpr int EG_ = 8192;
constexpr int E_  = B_*EG_;     // 1048576
constexpr int NT_ = B_*N_;      // 65536

constexpr size_t OFF_MC  = (size_t)B_*32*128;                 // 524288
constexpr size_t OFF_O   = OFF_MC + 1;
constexpr size_t OFF_AGG = OFF_O + 1;                         // 524290
constexpr size_t OFF_ADJ = OFF_AGG + (size_t)B_*N_*32;        // 2621442

// ---------------------------------------------------------------------------
__global__ void q_init(float* den, float* losses){
  int i = threadIdx.x;
  if (i < B_) den[i] = 0.f;
  if (i < 2)  losses[i] = 0.f;
}
__global__ void q_sent(float* out, float v){
  if (threadIdx.x == 0) out[0] = v;
}

// ---------------------------------------------------------------------------
// deg/drow via LDS scatter: block per graph.
__global__ __launch_bounds__(256) void q_deg(const int* __restrict__ ei,
    const float* __restrict__ ea, float* __restrict__ dis, float* __restrict__ drow){
  __shared__ float degL[N_];
  __shared__ float drL[N_];
  int t = threadIdx.x, b = blockIdx.x, base = b*N_;
  for (int j=t; j<N_; j+=256){ degL[j] = 1.0f; drL[j] = 0.f; }  // 1.0 = self loop
  __syncthreads();
  int e0 = b*EG_;
  for (int j=t; j<EG_; j+=256){
    int e = e0 + j;
    int r = ei[e], c = ei[E_+e];
    atomicAdd(&degL[c-base], ea[e]);
    atomicAdd(&drL [r-base], 1.0f);
  }
  __syncthreads();
  for (int j=t; j<N_; j+=256){
    dis [base+j] = rsqrtf(degL[j]);
    drow[base+j] = drL[j];
  }
}

// ---------------------------------------------------------------------------
// q_csr: per-graph CSR build. by-col: (csrR, csrW=dis[r]*ea*dis[c]); by-row: csrC.
__global__ __launch_bounds__(256) void q_csr(const int* __restrict__ ei,
    const float* __restrict__ ea, const float* __restrict__ dis,
    int* __restrict__ offC, int* __restrict__ offR,
    int* __restrict__ csrR, float* __restrict__ csrW, int* __restrict__ csrC){
  __shared__ int cC[N_], cR[N_];
  int t = threadIdx.x, b = blockIdx.x, base = b*N_, e0 = b*EG_;
  for (int j=t; j<N_; j+=256){ cC[j]=0; cR[j]=0; }
  __syncthreads();
  for (int j=t; j<EG_; j+=256){
    int e = e0 + j;
    atomicAdd(&cC[ei[E_+e]-base], 1);
    atomicAdd(&cR[ei[e]   -base], 1);
  }
  __syncthreads();
  if (t == 0){                    // serial exclusive scan (512 elems, cheap)
    int aC = 0, aR = 0;
    for (int n=0; n<N_; ++n){
      int vc = cC[n], vr = cR[n];
      cC[n] = aC; cR[n] = aR;
      aC += vc; aR += vr;
    }
  }
  __syncthreads();
  for (int j=t; j<N_; j+=256){ offC[base+j] = e0 + cC[j]; offR[base+j] = e0 + cR[j]; }
  __syncthreads();
  for (int j=t; j<EG_; j+=256){
    int e = e0 + j;
    int r = ei[e], c = ei[E_+e];
    float w = dis[r]*ea[e]*dis[c];
    int p  = atomicAdd(&cC[c-base], 1);
    csrR[e0+p] = r;  csrW[e0+p] = w;
    int p2 = atomicAdd(&cR[r-base], 1);
    csrC[e0+p2] = c;
  }
}

// ---------------------------------------------------------------------------
// xw[n,f] = sum_c pos[n,c] * W1[c,f]
__global__ __launch_bounds__(256) void q_xw(const float* __restrict__ pos,
    const float* __restrict__ W1, bf16* __restrict__ xw){
  int id = blockIdx.x*256 + threadIdx.x;        // NT*64
  int n = id >> 6, f = id & 63;
  float a = 0.f;
  for (int c = 0; c < 128; ++c) a += pos[(size_t)n*128 + c] * W1[c*64 + f];
  xw[id] = f2b(a);
}

// ---------------------------------------------------------------------------
// GCN conv: one wave per destination node, CSR gather, register accumulator.
__global__ __launch_bounds__(256) void q_gcn(const int* __restrict__ offC,
    const int* __restrict__ csrR, const float* __restrict__ csrW,
    const float* __restrict__ dis, const bf16* __restrict__ xw,
    const float* __restrict__ b1, bf16* __restrict__ x1){
  int n = (blockIdx.x*256 + threadIdx.x) >> 6;  // node 0..NT-1
  int f = threadIdx.x & 63;
  float d = dis[n];
  float h = d*d*b2f(xw[(size_t)n*64 + f]);
  int s = offC[n];
  int e = ((n & 511) == 511) ? ((n >> 9) + 1)*EG_ : offC[n+1];
  for (int j = s; j < e; ++j){
    int r = csrR[j];
    float w = csrW[j];
    h += w * b2f(xw[(size_t)r*64 + f]);
  }
  h += b1[f];
  x1[(size_t)n*64 + f] = f2b(h > 0.f ? h : 0.f);
}

// ---------------------------------------------------------------------------
// s1 softmax: Wp1 staged in LDS; x1 row held in-lane, broadcast via shuffle.
__global__ __launch_bounds__(256) void q_s1(const bf16* __restrict__ x1,
    const float* __restrict__ Wp1, const float* __restrict__ bp1,
    const float* __restrict__ drow, bf16* __restrict__ s1, float* __restrict__ den){
  __shared__ float wL[64][64];     // Wp1[f][k], 16 KB
  int t = threadIdx.x;
  for (int j=t; j<4096; j+=256) ((float*)wL)[j] = Wp1[j];
  __syncthreads();
  int wv = t>>6, k = t&63;
  int n0 = blockIdx.x*32 + wv*8;   // 4 waves x 8 nodes
  float bp = bp1[k];
  for (int i=0;i<8;++i){
    int n = n0 + i;
    float xv = b2f(x1[(size_t)n*64 + k]);   // lane k holds x1[n][k]
    float lg = bp;
    #pragma unroll
    for (int f=0; f<64; ++f)
      lg += __shfl(xv, f) * wL[f][k];
    float m = lg;
    #pragma unroll
    for (int o=32;o>=1;o>>=1) m = fmaxf(m, __shfl_xor(m, o));
    float p = expf(lg - m);
    float s = p;
    #pragma unroll
    for (int o=32;o>=1;o>>=1) s += __shfl_xor(s, o);
    float sv = p / s;
    s1[(size_t)n*64 + k] = f2b(sv);
    float q = sv*sv;
    #pragma unroll
    for (int o=32;o>=1;o>>=1) q += __shfl_xor(q, o);
    if (k == 0) atomicAdd(&den[n >> 9], q * drow[n]);
  }
}

// ---------------------------------------------------------------------------
// U = A @ s1: one wave per row node, CSR(by-row) gather of s1[c].
__global__ __launch_bounds__(256) void q_u(const int* __restrict__ offR,
    const int* __restrict__ csrC, const bf16* __restrict__ s1,
    bf16* __restrict__ U){
  int n = (blockIdx.x*256 + threadIdx.x) >> 6;
  int l = threadIdx.x & 63;
  float u = 0.f;
  int s = offR[n];
  int e = ((n & 511) == 511) ? ((n >> 9) + 1)*EG_ : offR[n+1];
  for (int j = s; j < e; ++j){
    int c = csrC[j];
    u += b2f(s1[(size_t)c*64 + l]);
  }
  U[(size_t)n*64 + l] = f2b(u);
}

// ---------------------------------------------------------------------------
// q_p3: fused adjP = s^T U, ssP = s^T s, X1p = s^T x1 (one graph per block).
__global__ __launch_bounds__(256) void q_p3(const bf16* __restrict__ s1,
    const bf16* __restrict__ U, const bf16* __restrict__ x1,
    float* __restrict__ adjP, float* __restrict__ ssP, float* __restrict__ X1p){
  __shared__ float sL[64][64];     // 16 KB each
  __shared__ float uL[64][64];
  __shared__ float xL[64][64];
  int t = threadIdx.x, b = blockIdx.x, base = b*N_;
  int ti = t>>4, tj = t&15;        // 16x16 grid, 4(k) x 4(l) per thread
  float accA[4][4], accS[4][4], accX[4][4];
  #pragma unroll
  for (int i=0;i<4;i++)
    #pragma unroll
    for (int j=0;j<4;j++){ accA[i][j]=0.f; accS[i][j]=0.f; accX[i][j]=0.f; }
  for (int c=0; c<8; ++c){
    __syncthreads();
    for (int j=t; j<4096; j+=256){
      int n = j>>6, q = j&63;
      size_t g = (size_t)(base + c*64 + n)*64 + q;
      sL[n][q] = b2f(s1[g]);
      uL[n][q] = b2f(U [g]);
      xL[n][q] = b2f(x1[g]);
    }
    __syncthreads();
    for (int n=0; n<64; ++n){
      float4 skv = *reinterpret_cast<const float4*>(&sL[n][ti*4]);
      float4 ulv = *reinterpret_cast<const float4*>(&uL[n][tj*4]);
      float4 xlv = *reinterpret_cast<const float4*>(&xL[n][tj*4]);
      float4 slv = *reinterpret_cast<const float4*>(&sL[n][tj*4]);
      float sk[4] = {skv.x, skv.y, skv.z, skv.w};
      float ul[4] = {ulv.x, ulv.y, ulv.z, ulv.w};
      float xl[4] = {xlv.x, xlv.y, xlv.z, xlv.w};
      float sl[4] = {slv.x, slv.y, slv.z, slv.w};
      #pragma unroll
      for (int i=0;i<4;i++)
        #pragma unroll
        for (int j=0;j<4;j++){
          accA[i][j] += sk[i]*ul[j];
          accS[i][j] += sk[i]*sl[j];
          accX[i][j] += sk[i]*xl[j];
        }
    }
  }
  #pragma unroll
  for (int i=0;i<4;i++)
    #pragma unroll
    for (int j=0;j<4;j++){
      size_t o = (size_t)b*4096 + (ti*4+i)*64 + tj*4+j;
      adjP[o] = accA[i][j];
      ssP [o] = accS[i][j];
      X1p [o] = accX[i][j];
    }
}

// ---------------------------------------------------------------------------
// norm1: losses (mincut1, ortho1); A2 = degnorm(diagzero(adjP)).
__global__ __launch_bounds__(256) void q_norm1(const float* __restrict__ adjP,
    const float* __restrict__ ssP, const float* __restrict__ den,
    float* __restrict__ A2, float* __restrict__ losses){
  __shared__ float aL[4096];
  __shared__ float rL[64];
  __shared__ float red[4];
  int b = blockIdx.x, t = threadIdx.x;
  for (int j = t; j < 4096; j += 256) aL[j] = adjP[(size_t)b*4096 + j];
  __syncthreads();
  if (t == 0){
    float tr = 0.f;
    for (int k = 0; k < 64; ++k) tr += aL[k*64 + k];
    atomicAdd(&losses[0], -(tr/den[b]) * (1.0f/B_));
  }
  if (t < 64){
    float rs = 0.f;
    for (int l = 0; l < 64; ++l) rs += aL[t*64 + l];
    rs -= aL[t*64 + t];                     // diag zeroed before rowsum
    rL[t] = 1.f/(sqrtf(rs) + 1e-15f);
  }
  float pp = 0.f;
  for (int j = t; j < 4096; j += 256){ float v = ssP[(size_t)b*4096 + j]; pp += v*v; }
  #pragma unroll
  for (int o = 32; o >= 1; o >>= 1) pp += __shfl_xor(pp, o);
  if ((t & 63) == 0) red[t >> 6] = pp;
  __syncthreads();                          // publishes red AND rL
  float fro = sqrtf(red[0]+red[1]+red[2]+red[3]);
  __syncthreads();
  float op = 0.f;
  for (int j = t; j < 4096; j += 256){
    int kk = j >> 6, ll = j & 63;
    float v = ssP[(size_t)b*4096 + j]/fro - ((kk==ll) ? 0.125f : 0.f);  // I/sqrt(64)
    op += v*v;
  }
  #pragma unroll
  for (int o = 32; o >= 1; o >>= 1) op += __shfl_xor(op, o);
  if ((t & 63) == 0) red[t >> 6] = op;
  __syncthreads();
  if (t == 0) atomicAdd(&losses[1], sqrtf(red[0]+red[1]+red[2]+red[3]) * (1.0f/B_));
  for (int j = t; j < 4096; j += 256){
    int kk = j >> 6, ll = j & 63;
    A2[(size_t)b*4096 + j] = (kk==ll) ? 0.f : aL[j]*rL[kk]*rL[ll];
  }
}

// ---------------------------------------------------------------------------
// AX[b,n,f] = sum_m A2[b,n,m]*X1p[b,m,f]
__global__ __launch_bounds__(256) void q_ax(const float* __restrict__ A2,
    const float* __restrict__ X1p, float* __restrict__ AX){
  int id = blockIdx.x*256 + threadIdx.x;        // B*4096
  int b = id >> 12, n = (id >> 6) & 63, f = id & 63;
  float a = 0.f;
  for (int m = 0; m < 64; ++m) a += A2[(size_t)b*4096 + n*64 + m]*X1p[(size_t)b*4096 + m*64 + f];
  AX[id] = a;
}
// x2 = relu(AX@W2r + X1p@W2s + b2)
__global__ __launch_bounds__(256) void q_x2(const float* __restrict__ AX,
    const float* __restrict__ X1p, const float* __restrict__ W2r,
    const float* __restrict__ W2s, const float* __restrict__ b2,
    float* __restrict__ x2){
  int id = blockIdx.x*256 + threadIdx.x;        // B*4096
  int b = id >> 12, n = (id >> 6) & 63, f = id & 63;
  float a = b2[f];
  for (int m = 0; m < 64; ++m) a += AX[(size_t)b*4096 + n*64 + m]*W2r[m*64 + f];
  for (int m = 0; m < 64; ++m) a += X1p[(size_t)b*4096 + n*64 + m]*W2s[m*64 + f];
  x2[id] = a > 0.f ? a : 0.f;
}

// ---------------------------------------------------------------------------
// s2 softmax over 32: one THREAD per (b,n).
__global__ __launch_bounds__(256) void q_s2(const float* __restrict__ x2,
    const float* __restrict__ Wp2, const float* __restrict__ bp2,
    float* __restrict__ s2){
  int id = blockIdx.x*256 + threadIdx.x;        // B*64
  if (id >= B_*64) return;
  float lg[32];
  float mx = -1e30f;
  #pragma unroll
  for (int k = 0; k < 32; ++k){
    float a = bp2[k];
    for (int f = 0; f < 64; ++f) a += x2[(size_t)id*64 + f]*Wp2[f*32 + k];
    lg[k] = a; mx = fmaxf(mx, a);
  }
  float ss = 0.f;
  #pragma unroll
  for (int k = 0; k < 32; ++k){ lg[k] = expf(lg[k]-mx); ss += lg[k]; }
  float inv = 1.f/ss;
  #pragma unroll
  for (int k = 0; k < 32; ++k) s2[(size_t)id*32 + k] = lg[k]*inv;
}

// ---------------------------------------------------------------------------
// V[b,n,l] = sum_m A2[b,n,m]*s2[b,m,l]
__global__ __launch_bounds__(256) void q_v(const float* __restrict__ A2,
    const float* __restrict__ s2, float* __restrict__ V){
  int id = blockIdx.x*256 + threadIdx.x;        // B*2048
  int b = id >> 11, n = (id >> 5) & 63, l = id & 31;
  float a = 0.f;
  for (int m = 0; m < 64; ++m) a += A2[(size_t)b*4096 + n*64 + m]*s2[(size_t)b*2048 + m*32 + l];
  V[id] = a;
}
// adj2[b,k,l] = sum_n s2[n,k]*V[n,l] ; ss2 = s2^T s2
__global__ __launch_bounds__(256) void q_adj2(const float* __restrict__ s2,
    const float* __restrict__ V, float* __restrict__ adj2, float* __restrict__ ss2){
  int id = blockIdx.x*256 + threadIdx.x;        // B*1024
  int b = id >> 10, k = (id >> 5) & 31, l = id & 31;
  float a = 0.f, c = 0.f;
  for (int n = 0; n < 64; ++n){
    float sk = s2[(size_t)b*2048 + n*32 + k];
    a += sk*V[(size_t)b*2048 + n*32 + l];
    c += sk*s2[(size_t)b*2048 + n*32 + l];
  }
  adj2[id] = a; ss2[id] = c;
}

// ---------------------------------------------------------------------------
// norm2: losses (mincut2, ortho2); A3 -> ws and out (f32).
__global__ __launch_bounds__(256) void q_norm2(const float* __restrict__ adj2,
    const float* __restrict__ ss2, const float* __restrict__ A2,
    const float* __restrict__ s2, float* __restrict__ A3,
    float* __restrict__ out, float* __restrict__ losses){
  __shared__ float aL[1024];
  __shared__ float sL[1024];
  __shared__ float r2[32];
  __shared__ float red[4];
  __shared__ float den2s;
  int b = blockIdx.x, t = threadIdx.x;
  for (int j = t; j < 1024; j += 256){
    aL[j] = adj2[(size_t)b*1024 + j];
    sL[j] = ss2[(size_t)b*1024 + j];
  }
  __syncthreads();
  if (t < 64){
    float rsA = 0.f;
    for (int m = 0; m < 64; ++m) rsA += A2[(size_t)b*4096 + t*64 + m];
    float q = 0.f;
    for (int k = 0; k < 32; ++k){ float s = s2[(size_t)b*2048 + t*32 + k]; q += s*s; }
    float part = rsA*q;
    #pragma unroll
    for (int o = 32; o >= 1; o >>= 1) part += __shfl_xor(part, o);
    if (t == 0) den2s = part;
  }
  if (t < 32){
    float rs = 0.f;
    for (int l = 0; l < 32; ++l) rs += aL[t*32 + l];
    rs -= aL[t*32 + t];
    r2[t] = 1.f/(sqrtf(rs) + 1e-15f);
  }
  __syncthreads();
  if (t == 0){
    float tr = 0.f;
    for (int k = 0; k < 32; ++k) tr += aL[k*32 + k];
    atomicAdd(&losses[0], -(tr/den2s) * (1.0f/B_));
  }
  float pp = 0.f;
  for (int j = t; j < 1024; j += 256){ float v = sL[j]; pp += v*v; }
  #pragma unroll
  for (int o = 32; o >= 1; o >>= 1) pp += __shfl_xor(pp, o);
  if ((t & 63) == 0) red[t >> 6] = pp;
  __syncthreads();
  float fro = sqrtf(red[0]+red[1]+red[2]+red[3]);
  __syncthreads();
  float op = 0.f;
  for (int j = t; j < 1024; j += 256){
    int kk = j >> 5, ll = j & 31;
    float v = sL[j]/fro - ((kk==ll) ? 0.1767766952966369f : 0.f);  // I/sqrt(32)
    op += v*v;
  }
  #pragma unroll
  for (int o = 32; o >= 1; o >>= 1) op += __shfl_xor(op, o);
  if ((t & 63) == 0) red[t >> 6] = op;
  __syncthreads();
  if (t == 0) atomicAdd(&losses[1], sqrtf(red[0]+red[1]+red[2]+red[3]) * (1.0f/B_));
  for (int j = t; j < 1024; j += 256){
    int kk = j >> 5, ll = j & 31;
    float v = (kk==ll) ? 0.f : aL[j]*r2[kk]*r2[ll];
    A3[(size_t)b*1024 + j] = v;
    out[OFF_ADJ + (size_t)b*1024 + j] = v;
  }
}

// ---------------------------------------------------------------------------
// o2[b,k,f] = sum_n s2[n,k]*x2[n,f]
__global__ __launch_bounds__(256) void q_o2(const float* __restrict__ s2,
    const float* __restrict__ x2, float* __restrict__ o2){
  int id = blockIdx.x*256 + threadIdx.x;        // B*2048
  int b = id >> 11, k = (id >> 6) & 31, f = id & 63;
  float a = 0.f;
  for (int n = 0; n < 64; ++n)
    a += s2[(size_t)b*2048 + n*32 + k]*x2[(size_t)b*4096 + n*64 + f];
  o2[id] = a;
}
// G[b,n,f] = sum_m A3[b,n,m]*o2[b,m,f]
__global__ __launch_bounds__(256) void q_g(const float* __restrict__ A3,
    const float* __restrict__ o2, float* __restrict__ G){
  int id = blockIdx.x*256 + threadIdx.x;        // B*2048
  int b = id >> 11, n = (id >> 6) & 31, f = id & 63;
  float a = 0.f;
  for (int m = 0; m < 32; ++m)
    a += A3[(size_t)b*1024 + n*32 + m]*o2[(size_t)b*2048 + m*64 + f];
  G[id] = a;
}
// x3[b,n,o] -> out (f32)
__global__ __launch_bounds__(256) void q_xout(const float* __restrict__ G,
    const float* __restrict__ o2, const float* __restrict__ W3r,
    const float* __restrict__ W3s, const float* __restrict__ b3,
    float* __restrict__ out){
  int id = blockIdx.x*256 + threadIdx.x;        // B*4096
  int b = id >> 12, n = (id >> 7) & 31, o = id & 127;
  float a = b3[o];
  for (int f = 0; f < 64; ++f) a += G[(size_t)b*2048 + n*64 + f]*W3r[f*128 + o];
  for (int f = 0; f < 64; ++f) a += o2[(size_t)b*2048 + n*64 + f]*W3s[f*128 + o];
  out[(size_t)b*4096 + n*128 + o] = a;
}

// ---------------------------------------------------------------------------
// agg[b,n,l] = sum_k s1[bN+n,k]*s2[b,k,l] -> out (f32)
__global__ __launch_bounds__(256) void q_agg(const bf16* __restrict__ s1,
    const float* __restrict__ s2, float* __restrict__ out){
  int id = blockIdx.x*256 + threadIdx.x;        // B*16384
  int b = id >> 14, n = (id >> 5) & 511, l = id & 31;
  float a = 0.f;
  for (int k = 0; k < 64; ++k)
    a += b2f(s1[((size_t)b*N_ + n)*64 + k]) * s2[(size_t)b*2048 + k*32 + l];
  out[OFF_AGG + ((size_t)b*N_ + n)*32 + l] = a;
}

// ---------------------------------------------------------------------------
__global__ void q_loss(const float* losses, float* out){
  if (threadIdx.x == 0){
    out[OFF_MC] = losses[0];
    out[OFF_O]  = losses[1];
  }
}

// ===========================================================================
extern "C" void kernel_launch(void* const* d_in, const int* in_sizes, int n_in,
                              void* d_out, int out_size, void* d_ws, size_t ws_size,
                              hipStream_t stream){
  (void)out_size;
  float* out = (float*)d_out;

  static const long long EXP_SIZES[16] = {
    8388608LL, 2097152LL, 1048576LL, 65536LL,
    8192LL, 64LL, 4096LL, 64LL,
    4096LL, 64LL, 4096LL, 2048LL, 32LL,
    8192LL, 128LL, 8192LL };
  if (n_in != 16){ q_sent<<<1,64,0,stream>>>(out, exp2f(36.f)); return; }
  for (int i = 0; i < 16; ++i){
    if ((long long)in_sizes[i] != EXP_SIZES[i]){
      q_sent<<<1,64,0,stream>>>(out, exp2f((float)(37+i))); return;
    }
  }

  const float* pos = (const float*)d_in[0];
  const int*   ei  = (const int*)  d_in[1];
  const float* ea  = (const float*)d_in[2];
  const float* W1  = (const float*)d_in[4];
  const float* b1  = (const float*)d_in[5];
  const float* Wp1 = (const float*)d_in[6];
  const float* bp1 = (const float*)d_in[7];
  const float* W2r = (const float*)d_in[8];
  const float* b2  = (const float*)d_in[9];
  const float* W2s = (const float*)d_in[10];
  const float* Wp2 = (const float*)d_in[11];
  const float* bp2 = (const float*)d_in[12];
  const float* W3r = (const float*)d_in[13];
  const float* b3  = (const float*)d_in[14];
  const float* W3s = (const float*)d_in[15];

  // ---- workspace (~42.5 MB) with lifetime-safe unions:
  //  R1: csrR (q_csr..q_gcn)  -> adjP+ssP (q_p3..)
  //  R2: csrW (q_csr..q_gcn)  -> AX+x2    (q_ax..)
  //  R3: csrC (q_csr..q_u)    -> X1p+A2   (q_p3..)
  constexpr size_t MB2 = (size_t)B_*4096*4;     // 2 MB
  char* w = (char*)d_ws;
  float* dis    = (float*)w; w += (size_t)NT_*4;
  float* drow   = (float*)w; w += (size_t)NT_*4;
  float* den    = (float*)w; w += (size_t)B_*4;
  float* losses = (float*)w; w += 64;
  int*   offC   = (int*)  w; w += (size_t)NT_*4;
  int*   offR   = (int*)  w; w += (size_t)NT_*4;
  char*  R1     = w;         w += 2*MB2;        // 4 MB
  char*  R2     = w;         w += 2*MB2;        // 4 MB
  char*  R3     = w;         w += 2*MB2;        // 4 MB
  float* s2     = (float*)w; w += (size_t)B_*2048*4;
  float* V      = (float*)w; w += (size_t)B_*2048*4;
  float* adj2   = (float*)w; w += (size_t)B_*1024*4;
  float* ss2    = (float*)w; w += (size_t)B_*1024*4;
  float* A3     = (float*)w; w += (size_t)B_*1024*4;
  float* o2     = (float*)w; w += (size_t)B_*2048*4;
  float* G      = (float*)w; w += (size_t)B_*2048*4;
  bf16*  xwU    = (bf16*)w;  w += (size_t)NT_*64*2;    // xw, then U
  bf16*  x1     = (bf16*)w;  w += (size_t)NT_*64*2;
  bf16*  s1     = (bf16*)w;  w += (size_t)NT_*64*2;
  size_t need = (size_t)(w - (char*)d_ws);
  if (ws_size < need){ q_sent<<<1,64,0,stream>>>(out, exp2f(20.f)); return; }

  int*   csrR = (int*)  R1;
  float* csrW = (float*)R2;
  int*   csrC = (int*)  R3;
  float* adjP = (float*)R1;
  float* ssP  = (float*)(R1 + MB2);
  float* AX   = (float*)R2;
  float* x2   = (float*)(R2 + MB2);
  float* X1p  = (float*)R3;
  float* A2   = (float*)(R3 + MB2);

  q_init <<<1,    256, 0, stream>>>(den, losses);
  q_deg  <<<B_,   256, 0, stream>>>(ei, ea, dis, drow);
  q_csr  <<<B_,   256, 0, stream>>>(ei, ea, dis, offC, offR, csrR, csrW, csrC);
  q_xw   <<<16384,256, 0, stream>>>(pos, W1, xwU);
  q_gcn  <<<16384,256, 0, stream>>>(offC, csrR, csrW, dis, xwU, b1, x1);
  q_s1   <<<NT_/32,256, 0, stream>>>(x1, Wp1, bp1, drow, s1, den);
  q_u    <<<16384,256, 0, stream>>>(offR, csrC, s1, xwU);     // xwU := U
  q_p3   <<<B_,   256, 0, stream>>>(s1, xwU, x1, adjP, ssP, X1p);
  q_norm1<<<B_,   256, 0, stream>>>(adjP, ssP, den, A2, losses);
  q_ax   <<<2048, 256, 0, stream>>>(A2, X1p, AX);
  q_x2   <<<2048, 256, 0, stream>>>(AX, X1p, W2r, W2s, b2, x2);
  q_s2   <<<32,   256, 0, stream>>>(x2, Wp2, bp2, s2);
  q_v    <<<1024, 256, 0, stream>>>(A2, s2, V);
  q_adj2 <<<512,  256, 0, stream>>>(s2, V, adj2, ss2);
  q_norm2<<<B_,   256, 0, stream>>>(adj2, ss2, A2, s2, A3, out, losses);
  q_o2   <<<1024, 256, 0, stream>>>(s2, x2, o2);
  q_g    <<<1024, 256, 0, stream>>>(A3, o2, G);
  q_xout <<<2048, 256, 0, stream>>>(G, o2, W3r, W3s, b3, out);
  q_agg  <<<8192, 256, 0, stream>>>(s1, s2, out);
  q_loss <<<1,     64, 0, stream>>>(losses, out);
}

// Round 15
// 558.578 us; speedup vs baseline: 30.3110x; 1.6413x over previous
//
#include <hip/hip_runtime.h>
#include <hip/hip_bf16.h>

// ============================================================================
// FrameAggregator — ROUND 15:
//  * q_s1: blocked register-tile GEMM (x1@Wp1) + in-register 16-lane softmax
//  * q_s2: 8 nodes/block, LDS-staged Wp2/x2, 32-lane parallel softmax
// Everything else identical to the round-14 passing pipeline (CSR edges).
// ============================================================================

typedef __hip_bfloat16 bf16;
#define DEV static __device__ __forceinline__
DEV float b2f(bf16 x){ return __bfloat162float(x); }
DEV bf16  f2b(float x){ return __float2bfloat16(x); }

constexpr int B_  = 128;
constexpr int N_  = 512;
constexpr int EG_ = 8192;
constexpr int E_  = B_*EG_;     // 1048576
constexpr int NT_ = B_*N_;      // 65536

constexpr size_t OFF_MC  = (size_t)B_*32*128;                 // 524288
constexpr size_t OFF_O   = OFF_MC + 1;
constexpr size_t OFF_AGG = OFF_O + 1;                         // 524290
constexpr size_t OFF_ADJ = OFF_AGG + (size_t)B_*N_*32;        // 2621442

// ---------------------------------------------------------------------------
__global__ void q_init(float* den, float* losses){
  int i = threadIdx.x;
  if (i < B_) den[i] = 0.f;
  if (i < 2)  losses[i] = 0.f;
}
__global__ void q_sent(float* out, float v){
  if (threadIdx.x == 0) out[0] = v;
}

// ---------------------------------------------------------------------------
// deg/drow via LDS scatter: block per graph.
__global__ __launch_bounds__(256) void q_deg(const int* __restrict__ ei,
    const float* __restrict__ ea, float* __restrict__ dis, float* __restrict__ drow){
  __shared__ float degL[N_];
  __shared__ float drL[N_];
  int t = threadIdx.x, b = blockIdx.x, base = b*N_;
  for (int j=t; j<N_; j+=256){ degL[j] = 1.0f; drL[j] = 0.f; }  // 1.0 = self loop
  __syncthreads();
  int e0 = b*EG_;
  for (int j=t; j<EG_; j+=256){
    int e = e0 + j;
    int r = ei[e], c = ei[E_+e];
    atomicAdd(&degL[c-base], ea[e]);
    atomicAdd(&drL [r-base], 1.0f);
  }
  __syncthreads();
  for (int j=t; j<N_; j+=256){
    dis [base+j] = rsqrtf(degL[j]);
    drow[base+j] = drL[j];
  }
}

// ---------------------------------------------------------------------------
// q_csr: per-graph CSR build. by-col: (csrR, csrW=dis[r]*ea*dis[c]); by-row: csrC.
__global__ __launch_bounds__(256) void q_csr(const int* __restrict__ ei,
    const float* __restrict__ ea, const float* __restrict__ dis,
    int* __restrict__ offC, int* __restrict__ offR,
    int* __restrict__ csrR, float* __restrict__ csrW, int* __restrict__ csrC){
  __shared__ int cC[N_], cR[N_];
  int t = threadIdx.x, b = blockIdx.x, base = b*N_, e0 = b*EG_;
  for (int j=t; j<N_; j+=256){ cC[j]=0; cR[j]=0; }
  __syncthreads();
  for (int j=t; j<EG_; j+=256){
    int e = e0 + j;
    atomicAdd(&cC[ei[E_+e]-base], 1);
    atomicAdd(&cR[ei[e]   -base], 1);
  }
  __syncthreads();
  if (t == 0){                    // serial exclusive scan (512 elems, cheap)
    int aC = 0, aR = 0;
    for (int n=0; n<N_; ++n){
      int vc = cC[n], vr = cR[n];
      cC[n] = aC; cR[n] = aR;
      aC += vc; aR += vr;
    }
  }
  __syncthreads();
  for (int j=t; j<N_; j+=256){ offC[base+j] = e0 + cC[j]; offR[base+j] = e0 + cR[j]; }
  __syncthreads();
  for (int j=t; j<EG_; j+=256){
    int e = e0 + j;
    int r = ei[e], c = ei[E_+e];
    float w = dis[r]*ea[e]*dis[c];
    int p  = atomicAdd(&cC[c-base], 1);
    csrR[e0+p] = r;  csrW[e0+p] = w;
    int p2 = atomicAdd(&cR[r-base], 1);
    csrC[e0+p2] = c;
  }
}

// ---------------------------------------------------------------------------
// xw[n,f] = sum_c pos[n,c] * W1[c,f]
__global__ __launch_bounds__(256) void q_xw(const float* __restrict__ pos,
    const float* __restrict__ W1, bf16* __restrict__ xw){
  int id = blockIdx.x*256 + threadIdx.x;        // NT*64
  int n = id >> 6, f = id & 63;
  float a = 0.f;
  for (int c = 0; c < 128; ++c) a += pos[(size_t)n*128 + c] * W1[c*64 + f];
  xw[id] = f2b(a);
}

// ---------------------------------------------------------------------------
// GCN conv: one wave per destination node, CSR gather, register accumulator.
__global__ __launch_bounds__(256) void q_gcn(const int* __restrict__ offC,
    const int* __restrict__ csrR, const float* __restrict__ csrW,
    const float* __restrict__ dis, const bf16* __restrict__ xw,
    const float* __restrict__ b1, bf16* __restrict__ x1){
  int n = (blockIdx.x*256 + threadIdx.x) >> 6;  // node 0..NT-1
  int f = threadIdx.x & 63;
  float d = dis[n];
  float h = d*d*b2f(xw[(size_t)n*64 + f]);
  int s = offC[n];
  int e = ((n & 511) == 511) ? ((n >> 9) + 1)*EG_ : offC[n+1];
  for (int j = s; j < e; ++j){
    int r = csrR[j];
    float w = csrW[j];
    h += w * b2f(xw[(size_t)r*64 + f]);
  }
  h += b1[f];
  x1[(size_t)n*64 + f] = f2b(h > 0.f ? h : 0.f);
}

// ---------------------------------------------------------------------------
// s1 = softmax(x1 @ Wp1 + bp1): 64 nodes/block, register-tile GEMM,
// in-register softmax with 16-lane shfl reductions; den via block accumulator.
__global__ __launch_bounds__(256) void q_s1(const bf16* __restrict__ x1,
    const float* __restrict__ Wp1, const float* __restrict__ bp1,
    const float* __restrict__ drow, bf16* __restrict__ s1, float* __restrict__ den){
  __shared__ float xT[64][65];     // x1 tile [node][f], padded
  __shared__ float wT[64][64];     // Wp1[f][k]
  __shared__ float denL;
  int t = threadIdx.x;
  int n0 = blockIdx.x*64;          // 64 nodes, all in graph n0>>9
  if (t == 0) denL = 0.f;
  for (int j=t; j<4096; j+=256){
    wT[j>>6][j&63] = Wp1[j];
    xT[j>>6][j&63] = b2f(x1[(size_t)n0*64 + j]);
  }
  __syncthreads();
  int ti = t>>4, tj = t&15;        // node group ti (4 nodes), k group tj (4 ks)
  float acc[4][4];
  #pragma unroll
  for (int i=0;i<4;i++)
    #pragma unroll
    for (int j=0;j<4;j++) acc[i][j] = 0.f;
  for (int f=0; f<64; ++f){
    float xs[4], ws[4];
    #pragma unroll
    for (int i=0;i<4;i++) xs[i] = xT[ti*4+i][f];
    #pragma unroll
    for (int j=0;j<4;j++) ws[j] = wT[f][tj*4+j];
    #pragma unroll
    for (int i=0;i<4;i++)
      #pragma unroll
      for (int j=0;j<4;j++) acc[i][j] += xs[i]*ws[j];
  }
  {
    float bp[4];
    #pragma unroll
    for (int j=0;j<4;j++) bp[j] = bp1[tj*4+j];
    #pragma unroll
    for (int i=0;i<4;i++)
      #pragma unroll
      for (int j=0;j<4;j++) acc[i][j] += bp[j];
  }
  // per-row softmax: reduction across the 16 tj-lanes (xor masks 1,2,4,8)
  #pragma unroll
  for (int i=0;i<4;i++){
    float m = fmaxf(fmaxf(acc[i][0],acc[i][1]), fmaxf(acc[i][2],acc[i][3]));
    #pragma unroll
    for (int o=8;o>=1;o>>=1) m = fmaxf(m, __shfl_xor(m, o));
    float e[4]; float ssum = 0.f;
    #pragma unroll
    for (int j=0;j<4;j++){ e[j] = expf(acc[i][j]-m); ssum += e[j]; }
    #pragma unroll
    for (int o=8;o>=1;o>>=1) ssum += __shfl_xor(ssum, o);
    float inv = 1.f/ssum, q = 0.f;
    int n = n0 + ti*4 + i;
    #pragma unroll
    for (int j=0;j<4;j++){
      float sv = e[j]*inv;
      s1[(size_t)n*64 + tj*4 + j] = f2b(sv);
      q += sv*sv;
    }
    #pragma unroll
    for (int o=8;o>=1;o>>=1) q += __shfl_xor(q, o);
    if (tj == 0) atomicAdd(&denL, q * drow[n]);
  }
  __syncthreads();
  if (t == 0) atomicAdd(&den[n0 >> 9], denL);
}

// ---------------------------------------------------------------------------
// U = A @ s1: one wave per row node, CSR(by-row) gather of s1[c].
__global__ __launch_bounds__(256) void q_u(const int* __restrict__ offR,
    const int* __restrict__ csrC, const bf16* __restrict__ s1,
    bf16* __restrict__ U){
  int n = (blockIdx.x*256 + threadIdx.x) >> 6;
  int l = threadIdx.x & 63;
  float u = 0.f;
  int s = offR[n];
  int e = ((n & 511) == 511) ? ((n >> 9) + 1)*EG_ : offR[n+1];
  for (int j = s; j < e; ++j){
    int c = csrC[j];
    u += b2f(s1[(size_t)c*64 + l]);
  }
  U[(size_t)n*64 + l] = f2b(u);
}

// ---------------------------------------------------------------------------
// q_p3: fused adjP = s^T U, ssP = s^T s, X1p = s^T x1 (one graph per block).
__global__ __launch_bounds__(256) void q_p3(const bf16* __restrict__ s1,
    const bf16* __restrict__ U, const bf16* __restrict__ x1,
    float* __restrict__ adjP, float* __restrict__ ssP, float* __restrict__ X1p){
  __shared__ float sL[64][64];     // 16 KB each
  __shared__ float uL[64][64];
  __shared__ float xL[64][64];
  int t = threadIdx.x, b = blockIdx.x, base = b*N_;
  int ti = t>>4, tj = t&15;        // 16x16 grid, 4(k) x 4(l) per thread
  float accA[4][4], accS[4][4], accX[4][4];
  #pragma unroll
  for (int i=0;i<4;i++)
    #pragma unroll
    for (int j=0;j<4;j++){ accA[i][j]=0.f; accS[i][j]=0.f; accX[i][j]=0.f; }
  for (int c=0; c<8; ++c){
    __syncthreads();
    for (int j=t; j<4096; j+=256){
      int n = j>>6, q = j&63;
      size_t g = (size_t)(base + c*64 + n)*64 + q;
      sL[n][q] = b2f(s1[g]);
      uL[n][q] = b2f(U [g]);
      xL[n][q] = b2f(x1[g]);
    }
    __syncthreads();
    for (int n=0; n<64; ++n){
      float4 skv = *reinterpret_cast<const float4*>(&sL[n][ti*4]);
      float4 ulv = *reinterpret_cast<const float4*>(&uL[n][tj*4]);
      float4 xlv = *reinterpret_cast<const float4*>(&xL[n][tj*4]);
      float4 slv = *reinterpret_cast<const float4*>(&sL[n][tj*4]);
      float sk[4] = {skv.x, skv.y, skv.z, skv.w};
      float ul[4] = {ulv.x, ulv.y, ulv.z, ulv.w};
      float xl[4] = {xlv.x, xlv.y, xlv.z, xlv.w};
      float sl[4] = {slv.x, slv.y, slv.z, slv.w};
      #pragma unroll
      for (int i=0;i<4;i++)
        #pragma unroll
        for (int j=0;j<4;j++){
          accA[i][j] += sk[i]*ul[j];
          accS[i][j] += sk[i]*sl[j];
          accX[i][j] += sk[i]*xl[j];
        }
    }
  }
  #pragma unroll
  for (int i=0;i<4;i++)
    #pragma unroll
    for (int j=0;j<4;j++){
      size_t o = (size_t)b*4096 + (ti*4+i)*64 + tj*4+j;
      adjP[o] = accA[i][j];
      ssP [o] = accS[i][j];
      X1p [o] = accX[i][j];
    }
}

// ---------------------------------------------------------------------------
// norm1: losses (mincut1, ortho1); A2 = degnorm(diagzero(adjP)).
__global__ __launch_bounds__(256) void q_norm1(const float* __restrict__ adjP,
    const float* __restrict__ ssP, const float* __restrict__ den,
    float* __restrict__ A2, float* __restrict__ losses){
  __shared__ float aL[4096];
  __shared__ float rL[64];
  __shared__ float red[4];
  int b = blockIdx.x, t = threadIdx.x;
  for (int j = t; j < 4096; j += 256) aL[j] = adjP[(size_t)b*4096 + j];
  __syncthreads();
  if (t == 0){
    float tr = 0.f;
    for (int k = 0; k < 64; ++k) tr += aL[k*64 + k];
    atomicAdd(&losses[0], -(tr/den[b]) * (1.0f/B_));
  }
  if (t < 64){
    float rs = 0.f;
    for (int l = 0; l < 64; ++l) rs += aL[t*64 + l];
    rs -= aL[t*64 + t];                     // diag zeroed before rowsum
    rL[t] = 1.f/(sqrtf(rs) + 1e-15f);
  }
  float pp = 0.f;
  for (int j = t; j < 4096; j += 256){ float v = ssP[(size_t)b*4096 + j]; pp += v*v; }
  #pragma unroll
  for (int o = 32; o >= 1; o >>= 1) pp += __shfl_xor(pp, o);
  if ((t & 63) == 0) red[t >> 6] = pp;
  __syncthreads();                          // publishes red AND rL
  float fro = sqrtf(red[0]+red[1]+red[2]+red[3]);
  __syncthreads();
  float op = 0.f;
  for (int j = t; j < 4096; j += 256){
    int kk = j >> 6, ll = j & 63;
    float v = ssP[(size_t)b*4096 + j]/fro - ((kk==ll) ? 0.125f : 0.f);  // I/sqrt(64)
    op += v*v;
  }
  #pragma unroll
  for (int o = 32; o >= 1; o >>= 1) op += __shfl_xor(op, o);
  if ((t & 63) == 0) red[t >> 6] = op;
  __syncthreads();
  if (t == 0) atomicAdd(&losses[1], sqrtf(red[0]+red[1]+red[2]+red[3]) * (1.0f/B_));
  for (int j = t; j < 4096; j += 256){
    int kk = j >> 6, ll = j & 63;
    A2[(size_t)b*4096 + j] = (kk==ll) ? 0.f : aL[j]*rL[kk]*rL[ll];
  }
}

// ---------------------------------------------------------------------------
// AX[b,n,f] = sum_m A2[b,n,m]*X1p[b,m,f]
__global__ __launch_bounds__(256) void q_ax(const float* __restrict__ A2,
    const float* __restrict__ X1p, float* __restrict__ AX){
  int id = blockIdx.x*256 + threadIdx.x;        // B*4096
  int b = id >> 12, n = (id >> 6) & 63, f = id & 63;
  float a = 0.f;
  for (int m = 0; m < 64; ++m) a += A2[(size_t)b*4096 + n*64 + m]*X1p[(size_t)b*4096 + m*64 + f];
  AX[id] = a;
}
// x2 = relu(AX@W2r + X1p@W2s + b2)
__global__ __launch_bounds__(256) void q_x2(const float* __restrict__ AX,
    const float* __restrict__ X1p, const float* __restrict__ W2r,
    const float* __restrict__ W2s, const float* __restrict__ b2,
    float* __restrict__ x2){
  int id = blockIdx.x*256 + threadIdx.x;        // B*4096
  int b = id >> 12, n = (id >> 6) & 63, f = id & 63;
  float a = b2[f];
  for (int m = 0; m < 64; ++m) a += AX[(size_t)b*4096 + n*64 + m]*W2r[m*64 + f];
  for (int m = 0; m < 64; ++m) a += X1p[(size_t)b*4096 + n*64 + m]*W2s[m*64 + f];
  x2[id] = a > 0.f ? a : 0.f;
}

// ---------------------------------------------------------------------------
// s2 = softmax(x2@Wp2+bp2) over 32: 8 nodes/block, LDS staging, 32-lane softmax.
__global__ __launch_bounds__(256) void q_s2(const float* __restrict__ x2,
    const float* __restrict__ Wp2, const float* __restrict__ bp2,
    float* __restrict__ s2){
  __shared__ float wL[64][32];     // 8 KB
  __shared__ float xR[8][64];      // 2 KB
  int t = threadIdx.x, blk = blockIdx.x;
  int b = blk >> 3, n0 = (blk & 7)*8;
  for (int j=t; j<2048; j+=256) ((float*)wL)[j] = Wp2[j];
  for (int j=t; j<512; j+=256) ((float*)xR)[j] = x2[(size_t)b*4096 + n0*64 + j];
  __syncthreads();
  int g = t>>5, k = t&31;          // node group g (8 nodes), cluster k
  float lg = bp2[k];
  #pragma unroll
  for (int f=0; f<64; ++f) lg += xR[g][f]*wL[f][k];
  float m = lg;
  #pragma unroll
  for (int o=16;o>=1;o>>=1) m = fmaxf(m, __shfl_xor(m, o));
  float p = expf(lg - m);
  float ssum = p;
  #pragma unroll
  for (int o=16;o>=1;o>>=1) ssum += __shfl_xor(ssum, o);
  s2[(size_t)b*2048 + (n0+g)*32 + k] = p/ssum;
}

// ---------------------------------------------------------------------------
// V[b,n,l] = sum_m A2[b,n,m]*s2[b,m,l]
__global__ __launch_bounds__(256) void q_v(const float* __restrict__ A2,
    const float* __restrict__ s2, float* __restrict__ V){
  int id = blockIdx.x*256 + threadIdx.x;        // B*2048
  int b = id >> 11, n = (id >> 5) & 63, l = id & 31;
  float a = 0.f;
  for (int m = 0; m < 64; ++m) a += A2[(size_t)b*4096 + n*64 + m]*s2[(size_t)b*2048 + m*32 + l];
  V[id] = a;
}
// adj2[b,k,l] = sum_n s2[n,k]*V[n,l] ; ss2 = s2^T s2
__global__ __launch_bounds__(256) void q_adj2(const float* __restrict__ s2,
    const float* __restrict__ V, float* __restrict__ adj2, float* __restrict__ ss2){
  int id = blockIdx.x*256 + threadIdx.x;        // B*1024
  int b = id >> 10, k = (id >> 5) & 31, l = id & 31;
  float a = 0.f, c = 0.f;
  for (int n = 0; n < 64; ++n){
    float sk = s2[(size_t)b*2048 + n*32 + k];
    a += sk*V[(size_t)b*2048 + n*32 + l];
    c += sk*s2[(size_t)b*2048 + n*32 + l];
  }
  adj2[id] = a; ss2[id] = c;
}

// ---------------------------------------------------------------------------
// norm2: losses (mincut2, ortho2); A3 -> ws and out (f32).
__global__ __launch_bounds__(256) void q_norm2(const float* __restrict__ adj2,
    const float* __restrict__ ss2, const float* __restrict__ A2,
    const float* __restrict__ s2, float* __restrict__ A3,
    float* __restrict__ out, float* __restrict__ losses){
  __shared__ float aL[1024];
  __shared__ float sL[1024];
  __shared__ float r2[32];
  __shared__ float red[4];
  __shared__ float den2s;
  int b = blockIdx.x, t = threadIdx.x;
  for (int j = t; j < 1024; j += 256){
    aL[j] = adj2[(size_t)b*1024 + j];
    sL[j] = ss2[(size_t)b*1024 + j];
  }
  __syncthreads();
  if (t < 64){
    float rsA = 0.f;
    for (int m = 0; m < 64; ++m) rsA += A2[(size_t)b*4096 + t*64 + m];
    float q = 0.f;
    for (int k = 0; k < 32; ++k){ float s = s2[(size_t)b*2048 + t*32 + k]; q += s*s; }
    float part = rsA*q;
    #pragma unroll
    for (int o = 32; o >= 1; o >>= 1) part += __shfl_xor(part, o);
    if (t == 0) den2s = part;
  }
  if (t < 32){
    float rs = 0.f;
    for (int l = 0; l < 32; ++l) rs += aL[t*32 + l];
    rs -= aL[t*32 + t];
    r2[t] = 1.f/(sqrtf(rs) + 1e-15f);
  }
  __syncthreads();
  if (t == 0){
    float tr = 0.f;
    for (int k = 0; k < 32; ++k) tr += aL[k*32 + k];
    atomicAdd(&losses[0], -(tr/den2s) * (1.0f/B_));
  }
  float pp = 0.f;
  for (int j = t; j < 1024; j += 256){ float v = sL[j]; pp += v*v; }
  #pragma unroll
  for (int o = 32; o >= 1; o >>= 1) pp += __shfl_xor(pp, o);
  if ((t & 63) == 0) red[t >> 6] = pp;
  __syncthreads();
  float fro = sqrtf(red[0]+red[1]+red[2]+red[3]);
  __syncthreads();
  float op = 0.f;
  for (int j = t; j < 1024; j += 256){
    int kk = j >> 5, ll = j & 31;
    float v = sL[j]/fro - ((kk==ll) ? 0.1767766952966369f : 0.f);  // I/sqrt(32)
    op += v*v;
  }
  #pragma unroll
  for (int o = 32; o >= 1; o >>= 1) op += __shfl_xor(op, o);
  if ((t & 63) == 0) red[t >> 6] = op;
  __syncthreads();
  if (t == 0) atomicAdd(&losses[1], sqrtf(red[0]+red[1]+red[2]+red[3]) * (1.0f/B_));
  for (int j = t; j < 1024; j += 256){
    int kk = j >> 5, ll = j & 31;
    float v = (kk==ll) ? 0.f : aL[j]*r2[kk]*r2[ll];
    A3[(size_t)b*1024 + j] = v;
    out[OFF_ADJ + (size_t)b*1024 + j] = v;
  }
}

// ---------------------------------------------------------------------------
// o2[b,k,f] = sum_n s2[n,k]*x2[n,f]
__global__ __launch_bounds__(256) void q_o2(const float* __restrict__ s2,
    const float* __restrict__ x2, float* __restrict__ o2){
  int id = blockIdx.x*256 + threadIdx.x;        // B*2048
  int b = id >> 11, k = (id >> 6) & 31, f = id & 63;
  float a = 0.f;
  for (int n = 0; n < 64; ++n)
    a += s2[(size_t)b*2048 + n*32 + k]*x2[(size_t)b*4096 + n*64 + f];
  o2[id] = a;
}
// G[b,n,f] = sum_m A3[b,n,m]*o2[b,m,f]
__global__ __launch_bounds__(256) void q_g(const float* __restrict__ A3,
    const float* __restrict__ o2, float* __restrict__ G){
  int id = blockIdx.x*256 + threadIdx.x;        // B*2048
  int b = id >> 11, n = (id >> 6) & 31, f = id & 63;
  float a = 0.f;
  for (int m = 0; m < 32; ++m)
    a += A3[(size_t)b*1024 + n*32 + m]*o2[(size_t)b*2048 + m*64 + f];
  G[id] = a;
}
// x3[b,n,o] -> out (f32)
__global__ __launch_bounds__(256) void q_xout(const float* __restrict__ G,
    const float* __restrict__ o2, const float* __restrict__ W3r,
    const float* __restrict__ W3s, const float* __restrict__ b3,
    float* __restrict__ out){
  int id = blockIdx.x*256 + threadIdx.x;        // B*4096
  int b = id >> 12, n = (id >> 7) & 31, o = id & 127;
  float a = b3[o];
  for (int f = 0; f < 64; ++f) a += G[(size_t)b*2048 + n*64 + f]*W3r[f*128 + o];
  for (int f = 0; f < 64; ++f) a += o2[(size_t)b*2048 + n*64 + f]*W3s[f*128 + o];
  out[(size_t)b*4096 + n*128 + o] = a;
}

// ---------------------------------------------------------------------------
// agg[b,n,l] = sum_k s1[bN+n,k]*s2[b,k,l] -> out (f32)
__global__ __launch_bounds__(256) void q_agg(const bf16* __restrict__ s1,
    const float* __restrict__ s2, float* __restrict__ out){
  int id = blockIdx.x*256 + threadIdx.x;        // B*16384
  int b = id >> 14, n = (id >> 5) & 511, l = id & 31;
  float a = 0.f;
  for (int k = 0; k < 64; ++k)
    a += b2f(s1[((size_t)b*N_ + n)*64 + k]) * s2[(size_t)b*2048 + k*32 + l];
  out[OFF_AGG + ((size_t)b*N_ + n)*32 + l] = a;
}

// ---------------------------------------------------------------------------
__global__ void q_loss(const float* losses, float* out){
  if (threadIdx.x == 0){
    out[OFF_MC] = losses[0];
    out[OFF_O]  = losses[1];
  }
}

// ===========================================================================
extern "C" void kernel_launch(void* const* d_in, const int* in_sizes, int n_in,
                              void* d_out, int out_size, void* d_ws, size_t ws_size,
                              hipStream_t stream){
  (void)out_size;
  float* out = (float*)d_out;

  static const long long EXP_SIZES[16] = {
    8388608LL, 2097152LL, 1048576LL, 65536LL,
    8192LL, 64LL, 4096LL, 64LL,
    4096LL, 64LL, 4096LL, 2048LL, 32LL,
    8192LL, 128LL, 8192LL };
  if (n_in != 16){ q_sent<<<1,64,0,stream>>>(out, exp2f(36.f)); return; }
  for (int i = 0; i < 16; ++i){
    if ((long long)in_sizes[i] != EXP_SIZES[i]){
      q_sent<<<1,64,0,stream>>>(out, exp2f((float)(37+i))); return;
    }
  }

  const float* pos = (const float*)d_in[0];
  const int*   ei  = (const int*)  d_in[1];
  const float* ea  = (const float*)d_in[2];
  const float* W1  = (const float*)d_in[4];
  const float* b1  = (const float*)d_in[5];
  const float* Wp1 = (const float*)d_in[6];
  const float* bp1 = (const float*)d_in[7];
  const float* W2r = (const float*)d_in[8];
  const float* b2  = (const float*)d_in[9];
  const float* W2s = (const float*)d_in[10];
  const float* Wp2 = (const float*)d_in[11];
  const float* bp2 = (const float*)d_in[12];
  const float* W3r = (const float*)d_in[13];
  const float* b3  = (const float*)d_in[14];
  const float* W3s = (const float*)d_in[15];

  // ---- workspace (~42.5 MB) with lifetime-safe unions:
  //  R1: csrR (q_csr..q_gcn)  -> adjP+ssP (q_p3..)
  //  R2: csrW (q_csr..q_gcn)  -> AX+x2    (q_ax..)
  //  R3: csrC (q_csr..q_u)    -> X1p+A2   (q_p3..)
  constexpr size_t MB2 = (size_t)B_*4096*4;     // 2 MB
  char* w = (char*)d_ws;
  float* dis    = (float*)w; w += (size_t)NT_*4;
  float* drow   = (float*)w; w += (size_t)NT_*4;
  float* den    = (float*)w; w += (size_t)B_*4;
  float* losses = (float*)w; w += 64;
  int*   offC   = (int*)  w; w += (size_t)NT_*4;
  int*   offR   = (int*)  w; w += (size_t)NT_*4;
  char*  R1     = w;         w += 2*MB2;        // 4 MB
  char*  R2     = w;         w += 2*MB2;        // 4 MB
  char*  R3     = w;         w += 2*MB2;        // 4 MB
  float* s2     = (float*)w; w += (size_t)B_*2048*4;
  float* V      = (float*)w; w += (size_t)B_*2048*4;
  float* adj2   = (float*)w; w += (size_t)B_*1024*4;
  float* ss2    = (float*)w; w += (size_t)B_*1024*4;
  float* A3     = (float*)w; w += (size_t)B_*1024*4;
  float* o2     = (float*)w; w += (size_t)B_*2048*4;
  float* G      = (float*)w; w += (size_t)B_*2048*4;
  bf16*  xwU    = (bf16*)w;  w += (size_t)NT_*64*2;    // xw, then U
  bf16*  x1     = (bf16*)w;  w += (size_t)NT_*64*2;
  bf16*  s1     = (bf16*)w;  w += (size_t)NT_*64*2;
  size_t need = (size_t)(w - (char*)d_ws);
  if (ws_size < need){ q_sent<<<1,64,0,stream>>>(out, exp2f(20.f)); return; }

  int*   csrR = (int*)  R1;
  float* csrW = (float*)R2;
  int*   csrC = (int*)  R3;
  float* adjP = (float*)R1;
  float* ssP  = (float*)(R1 + MB2);
  float* AX   = (float*)R2;
  float* x2   = (float*)(R2 + MB2);
  float* X1p  = (float*)R3;
  float* A2   = (float*)(R3 + MB2);

  q_init <<<1,    256, 0, stream>>>(den, losses);
  q_deg  <<<B_,   256, 0, stream>>>(ei, ea, dis, drow);
  q_csr  <<<B_,   256, 0, stream>>>(ei, ea, dis, offC, offR, csrR, csrW, csrC);
  q_xw   <<<16384,256, 0, stream>>>(pos, W1, xwU);
  q_gcn  <<<16384,256, 0, stream>>>(offC, csrR, csrW, dis, xwU, b1, x1);
  q_s1   <<<NT_/64,256, 0, stream>>>(x1, Wp1, bp1, drow, s1, den);
  q_u    <<<16384,256, 0, stream>>>(offR, csrC, s1, xwU);     // xwU := U
  q_p3   <<<B_,   256, 0, stream>>>(s1, xwU, x1, adjP, ssP, X1p);
  q_norm1<<<B_,   256, 0, stream>>>(adjP, ssP, den, A2, losses);
  q_ax   <<<2048, 256, 0, stream>>>(A2, X1p, AX);
  q_x2   <<<2048, 256, 0, stream>>>(AX, X1p, W2r, W2s, b2, x2);
  q_s2   <<<1024, 256, 0, stream>>>(x2, Wp2, bp2, s2);
  q_v    <<<1024, 256, 0, stream>>>(A2, s2, V);
  q_adj2 <<<512,  256, 0, stream>>>(s2, V, adj2, ss2);
  q_norm2<<<B_,   256, 0, stream>>>(adj2, ss2, A2, s2, A3, out, losses);
  q_o2   <<<1024, 256, 0, stream>>>(s2, x2, o2);
  q_g    <<<1024, 256, 0, stream>>>(A3, o2, G);
  q_xout <<<2048, 256, 0, stream>>>(G, o2, W3r, W3s, b3, out);
  q_agg  <<<8192, 256, 0, stream>>>(s1, s2, out);
  q_loss <<<1,     64, 0, stream>>>(losses, out);
}

// Round 16
// 447.754 us; speedup vs baseline: 37.8134x; 1.2475x over previous
//
#include <hip/hip_runtime.h>
#include <hip/hip_bf16.h>

// ============================================================================
// FrameAggregator — ROUND 16:
//  * q_xw: register-tile GEMM (pos@W1), pos+W1 staged in LDS, 4x4/thread
//  * q_agg: register-tile GEMM (s1@s2), LDS-staged, 4x2/thread
// Everything else identical to the round-15 passing pipeline.
// ============================================================================

typedef __hip_bfloat16 bf16;
#define DEV static __device__ __forceinline__
DEV float b2f(bf16 x){ return __bfloat162float(x); }
DEV bf16  f2b(float x){ return __float2bfloat16(x); }

constexpr int B_  = 128;
constexpr int N_  = 512;
constexpr int EG_ = 8192;
constexpr int E_  = B_*EG_;     // 1048576
constexpr int NT_ = B_*N_;      // 65536

constexpr size_t OFF_MC  = (size_t)B_*32*128;                 // 524288
constexpr size_t OFF_O   = OFF_MC + 1;
constexpr size_t OFF_AGG = OFF_O + 1;                         // 524290
constexpr size_t OFF_ADJ = OFF_AGG + (size_t)B_*N_*32;        // 2621442

// ---------------------------------------------------------------------------
__global__ void q_init(float* den, float* losses){
  int i = threadIdx.x;
  if (i < B_) den[i] = 0.f;
  if (i < 2)  losses[i] = 0.f;
}
__global__ void q_sent(float* out, float v){
  if (threadIdx.x == 0) out[0] = v;
}

// ---------------------------------------------------------------------------
// deg/drow via LDS scatter: block per graph.
__global__ __launch_bounds__(256) void q_deg(const int* __restrict__ ei,
    const float* __restrict__ ea, float* __restrict__ dis, float* __restrict__ drow){
  __shared__ float degL[N_];
  __shared__ float drL[N_];
  int t = threadIdx.x, b = blockIdx.x, base = b*N_;
  for (int j=t; j<N_; j+=256){ degL[j] = 1.0f; drL[j] = 0.f; }  // 1.0 = self loop
  __syncthreads();
  int e0 = b*EG_;
  for (int j=t; j<EG_; j+=256){
    int e = e0 + j;
    int r = ei[e], c = ei[E_+e];
    atomicAdd(&degL[c-base], ea[e]);
    atomicAdd(&drL [r-base], 1.0f);
  }
  __syncthreads();
  for (int j=t; j<N_; j+=256){
    dis [base+j] = rsqrtf(degL[j]);
    drow[base+j] = drL[j];
  }
}

// ---------------------------------------------------------------------------
// q_csr: per-graph CSR build. by-col: (csrR, csrW=dis[r]*ea*dis[c]); by-row: csrC.
__global__ __launch_bounds__(256) void q_csr(const int* __restrict__ ei,
    const float* __restrict__ ea, const float* __restrict__ dis,
    int* __restrict__ offC, int* __restrict__ offR,
    int* __restrict__ csrR, float* __restrict__ csrW, int* __restrict__ csrC){
  __shared__ int cC[N_], cR[N_];
  int t = threadIdx.x, b = blockIdx.x, base = b*N_, e0 = b*EG_;
  for (int j=t; j<N_; j+=256){ cC[j]=0; cR[j]=0; }
  __syncthreads();
  for (int j=t; j<EG_; j+=256){
    int e = e0 + j;
    atomicAdd(&cC[ei[E_+e]-base], 1);
    atomicAdd(&cR[ei[e]   -base], 1);
  }
  __syncthreads();
  if (t == 0){                    // serial exclusive scan (512 elems, cheap)
    int aC = 0, aR = 0;
    for (int n=0; n<N_; ++n){
      int vc = cC[n], vr = cR[n];
      cC[n] = aC; cR[n] = aR;
      aC += vc; aR += vr;
    }
  }
  __syncthreads();
  for (int j=t; j<N_; j+=256){ offC[base+j] = e0 + cC[j]; offR[base+j] = e0 + cR[j]; }
  __syncthreads();
  for (int j=t; j<EG_; j+=256){
    int e = e0 + j;
    int r = ei[e], c = ei[E_+e];
    float w = dis[r]*ea[e]*dis[c];
    int p  = atomicAdd(&cC[c-base], 1);
    csrR[e0+p] = r;  csrW[e0+p] = w;
    int p2 = atomicAdd(&cR[r-base], 1);
    csrC[e0+p2] = c;
  }
}

// ---------------------------------------------------------------------------
// xw = pos @ W1: 64-node tiles, LDS-staged pos+W1, 4x4 register tiles.
__global__ __launch_bounds__(256) void q_xw(const float* __restrict__ pos,
    const float* __restrict__ W1, bf16* __restrict__ xw){
  __shared__ float pL[64][129];    // 33 KB, padded
  __shared__ float wT[128][64];    // 32 KB (= W1 layout)
  int t = threadIdx.x;
  int n0 = blockIdx.x*64;
  for (int j=t; j<2048; j+=256){   // 64 rows x 32 float4
    int n = j >> 5, c4 = j & 31;
    float4 v = *reinterpret_cast<const float4*>(pos + (size_t)(n0+n)*128 + c4*4);
    pL[n][c4*4+0]=v.x; pL[n][c4*4+1]=v.y; pL[n][c4*4+2]=v.z; pL[n][c4*4+3]=v.w;
  }
  for (int j=t; j<8192; j+=256) ((float*)wT)[j] = W1[j];
  __syncthreads();
  int ti = t>>4, tj = t&15;
  float acc[4][4];
  #pragma unroll
  for (int i=0;i<4;i++)
    #pragma unroll
    for (int j=0;j<4;j++) acc[i][j] = 0.f;
  for (int k=0; k<128; ++k){
    float xs[4], ws[4];
    #pragma unroll
    for (int i=0;i<4;i++) xs[i] = pL[ti*4+i][k];
    #pragma unroll
    for (int j=0;j<4;j++) ws[j] = wT[k][tj*4+j];
    #pragma unroll
    for (int i=0;i<4;i++)
      #pragma unroll
      for (int j=0;j<4;j++) acc[i][j] += xs[i]*ws[j];
  }
  #pragma unroll
  for (int i=0;i<4;i++)
    #pragma unroll
    for (int j=0;j<4;j++)
      xw[(size_t)(n0+ti*4+i)*64 + tj*4+j] = f2b(acc[i][j]);
}

// ---------------------------------------------------------------------------
// GCN conv: one wave per destination node, CSR gather, register accumulator.
__global__ __launch_bounds__(256) void q_gcn(const int* __restrict__ offC,
    const int* __restrict__ csrR, const float* __restrict__ csrW,
    const float* __restrict__ dis, const bf16* __restrict__ xw,
    const float* __restrict__ b1, bf16* __restrict__ x1){
  int n = (blockIdx.x*256 + threadIdx.x) >> 6;  // node 0..NT-1
  int f = threadIdx.x & 63;
  float d = dis[n];
  float h = d*d*b2f(xw[(size_t)n*64 + f]);
  int s = offC[n];
  int e = ((n & 511) == 511) ? ((n >> 9) + 1)*EG_ : offC[n+1];
  for (int j = s; j < e; ++j){
    int r = csrR[j];
    float w = csrW[j];
    h += w * b2f(xw[(size_t)r*64 + f]);
  }
  h += b1[f];
  x1[(size_t)n*64 + f] = f2b(h > 0.f ? h : 0.f);
}

// ---------------------------------------------------------------------------
// s1 = softmax(x1 @ Wp1 + bp1): 64 nodes/block, register-tile GEMM,
// in-register softmax with 16-lane shfl reductions; den via block accumulator.
__global__ __launch_bounds__(256) void q_s1(const bf16* __restrict__ x1,
    const float* __restrict__ Wp1, const float* __restrict__ bp1,
    const float* __restrict__ drow, bf16* __restrict__ s1, float* __restrict__ den){
  __shared__ float xT[64][65];     // x1 tile [node][f], padded
  __shared__ float wT[64][64];     // Wp1[f][k]
  __shared__ float denL;
  int t = threadIdx.x;
  int n0 = blockIdx.x*64;          // 64 nodes, all in graph n0>>9
  if (t == 0) denL = 0.f;
  for (int j=t; j<4096; j+=256){
    wT[j>>6][j&63] = Wp1[j];
    xT[j>>6][j&63] = b2f(x1[(size_t)n0*64 + j]);
  }
  __syncthreads();
  int ti = t>>4, tj = t&15;        // node group ti (4 nodes), k group tj (4 ks)
  float acc[4][4];
  #pragma unroll
  for (int i=0;i<4;i++)
    #pragma unroll
    for (int j=0;j<4;j++) acc[i][j] = 0.f;
  for (int f=0; f<64; ++f){
    float xs[4], ws[4];
    #pragma unroll
    for (int i=0;i<4;i++) xs[i] = xT[ti*4+i][f];
    #pragma unroll
    for (int j=0;j<4;j++) ws[j] = wT[f][tj*4+j];
    #pragma unroll
    for (int i=0;i<4;i++)
      #pragma unroll
      for (int j=0;j<4;j++) acc[i][j] += xs[i]*ws[j];
  }
  {
    float bp[4];
    #pragma unroll
    for (int j=0;j<4;j++) bp[j] = bp1[tj*4+j];
    #pragma unroll
    for (int i=0;i<4;i++)
      #pragma unroll
      for (int j=0;j<4;j++) acc[i][j] += bp[j];
  }
  // per-row softmax: reduction across the 16 tj-lanes (xor masks 1,2,4,8)
  #pragma unroll
  for (int i=0;i<4;i++){
    float m = fmaxf(fmaxf(acc[i][0],acc[i][1]), fmaxf(acc[i][2],acc[i][3]));
    #pragma unroll
    for (int o=8;o>=1;o>>=1) m = fmaxf(m, __shfl_xor(m, o));
    float e[4]; float ssum = 0.f;
    #pragma unroll
    for (int j=0;j<4;j++){ e[j] = expf(acc[i][j]-m); ssum += e[j]; }
    #pragma unroll
    for (int o=8;o>=1;o>>=1) ssum += __shfl_xor(ssum, o);
    float inv = 1.f/ssum, q = 0.f;
    int n = n0 + ti*4 + i;
    #pragma unroll
    for (int j=0;j<4;j++){
      float sv = e[j]*inv;
      s1[(size_t)n*64 + tj*4 + j] = f2b(sv);
      q += sv*sv;
    }
    #pragma unroll
    for (int o=8;o>=1;o>>=1) q += __shfl_xor(q, o);
    if (tj == 0) atomicAdd(&denL, q * drow[n]);
  }
  __syncthreads();
  if (t == 0) atomicAdd(&den[n0 >> 9], denL);
}

// ---------------------------------------------------------------------------
// U = A @ s1: one wave per row node, CSR(by-row) gather of s1[c].
__global__ __launch_bounds__(256) void q_u(const int* __restrict__ offR,
    const int* __restrict__ csrC, const bf16* __restrict__ s1,
    bf16* __restrict__ U){
  int n = (blockIdx.x*256 + threadIdx.x) >> 6;
  int l = threadIdx.x & 63;
  float u = 0.f;
  int s = offR[n];
  int e = ((n & 511) == 511) ? ((n >> 9) + 1)*EG_ : offR[n+1];
  for (int j = s; j < e; ++j){
    int c = csrC[j];
    u += b2f(s1[(size_t)c*64 + l]);
  }
  U[(size_t)n*64 + l] = f2b(u);
}

// ---------------------------------------------------------------------------
// q_p3: fused adjP = s^T U, ssP = s^T s, X1p = s^T x1 (one graph per block).
__global__ __launch_bounds__(256) void q_p3(const bf16* __restrict__ s1,
    const bf16* __restrict__ U, const bf16* __restrict__ x1,
    float* __restrict__ adjP, float* __restrict__ ssP, float* __restrict__ X1p){
  __shared__ float sL[64][64];     // 16 KB each
  __shared__ float uL[64][64];
  __shared__ float xL[64][64];
  int t = threadIdx.x, b = blockIdx.x, base = b*N_;
  int ti = t>>4, tj = t&15;        // 16x16 grid, 4(k) x 4(l) per thread
  float accA[4][4], accS[4][4], accX[4][4];
  #pragma unroll
  for (int i=0;i<4;i++)
    #pragma unroll
    for (int j=0;j<4;j++){ accA[i][j]=0.f; accS[i][j]=0.f; accX[i][j]=0.f; }
  for (int c=0; c<8; ++c){
    __syncthreads();
    for (int j=t; j<4096; j+=256){
      int n = j>>6, q = j&63;
      size_t g = (size_t)(base + c*64 + n)*64 + q;
      sL[n][q] = b2f(s1[g]);
      uL[n][q] = b2f(U [g]);
      xL[n][q] = b2f(x1[g]);
    }
    __syncthreads();
    for (int n=0; n<64; ++n){
      float4 skv = *reinterpret_cast<const float4*>(&sL[n][ti*4]);
      float4 ulv = *reinterpret_cast<const float4*>(&uL[n][tj*4]);
      float4 xlv = *reinterpret_cast<const float4*>(&xL[n][tj*4]);
      float4 slv = *reinterpret_cast<const float4*>(&sL[n][tj*4]);
      float sk[4] = {skv.x, skv.y, skv.z, skv.w};
      float ul[4] = {ulv.x, ulv.y, ulv.z, ulv.w};
      float xl[4] = {xlv.x, xlv.y, xlv.z, xlv.w};
      float sl[4] = {slv.x, slv.y, slv.z, slv.w};
      #pragma unroll
      for (int i=0;i<4;i++)
        #pragma unroll
        for (int j=0;j<4;j++){
          accA[i][j] += sk[i]*ul[j];
          accS[i][j] += sk[i]*sl[j];
          accX[i][j] += sk[i]*xl[j];
        }
    }
  }
  #pragma unroll
  for (int i=0;i<4;i++)
    #pragma unroll
    for (int j=0;j<4;j++){
      size_t o = (size_t)b*4096 + (ti*4+i)*64 + tj*4+j;
      adjP[o] = accA[i][j];
      ssP [o] = accS[i][j];
      X1p [o] = accX[i][j];
    }
}

// ---------------------------------------------------------------------------
// norm1: losses (mincut1, ortho1); A2 = degnorm(diagzero(adjP)).
__global__ __launch_bounds__(256) void q_norm1(const float* __restrict__ adjP,
    const float* __restrict__ ssP, const float* __restrict__ den,
    float* __restrict__ A2, float* __restrict__ losses){
  __shared__ float aL[4096];
  __shared__ float rL[64];
  __shared__ float red[4];
  int b = blockIdx.x, t = threadIdx.x;
  for (int j = t; j < 4096; j += 256) aL[j] = adjP[(size_t)b*4096 + j];
  __syncthreads();
  if (t == 0){
    float tr = 0.f;
    for (int k = 0; k < 64; ++k) tr += aL[k*64 + k];
    atomicAdd(&losses[0], -(tr/den[b]) * (1.0f/B_));
  }
  if (t < 64){
    float rs = 0.f;
    for (int l = 0; l < 64; ++l) rs += aL[t*64 + l];
    rs -= aL[t*64 + t];                     // diag zeroed before rowsum
    rL[t] = 1.f/(sqrtf(rs) + 1e-15f);
  }
  float pp = 0.f;
  for (int j = t; j < 4096; j += 256){ float v = ssP[(size_t)b*4096 + j]; pp += v*v; }
  #pragma unroll
  for (int o = 32; o >= 1; o >>= 1) pp += __shfl_xor(pp, o);
  if ((t & 63) == 0) red[t >> 6] = pp;
  __syncthreads();                          // publishes red AND rL
  float fro = sqrtf(red[0]+red[1]+red[2]+red[3]);
  __syncthreads();
  float op = 0.f;
  for (int j = t; j < 4096; j += 256){
    int kk = j >> 6, ll = j & 63;
    float v = ssP[(size_t)b*4096 + j]/fro - ((kk==ll) ? 0.125f : 0.f);  // I/sqrt(64)
    op += v*v;
  }
  #pragma unroll
  for (int o = 32; o >= 1; o >>= 1) op += __shfl_xor(op, o);
  if ((t & 63) == 0) red[t >> 6] = op;
  __syncthreads();
  if (t == 0) atomicAdd(&losses[1], sqrtf(red[0]+red[1]+red[2]+red[3]) * (1.0f/B_));
  for (int j = t; j < 4096; j += 256){
    int kk = j >> 6, ll = j & 63;
    A2[(size_t)b*4096 + j] = (kk==ll) ? 0.f : aL[j]*rL[kk]*rL[ll];
  }
}

// ---------------------------------------------------------------------------
// AX[b,n,f] = sum_m A2[b,n,m]*X1p[b,m,f]
__global__ __launch_bounds__(256) void q_ax(const float* __restrict__ A2,
    const float* __restrict__ X1p, float* __restrict__ AX){
  int id = blockIdx.x*256 + threadIdx.x;        // B*4096
  int b = id >> 12, n = (id >> 6) & 63, f = id & 63;
  float a = 0.f;
  for (int m = 0; m < 64; ++m) a += A2[(size_t)b*4096 + n*64 + m]*X1p[(size_t)b*4096 + m*64 + f];
  AX[id] = a;
}
// x2 = relu(AX@W2r + X1p@W2s + b2)
__global__ __launch_bounds__(256) void q_x2(const float* __restrict__ AX,
    const float* __restrict__ X1p, const float* __restrict__ W2r,
    const float* __restrict__ W2s, const float* __restrict__ b2,
    float* __restrict__ x2){
  int id = blockIdx.x*256 + threadIdx.x;        // B*4096
  int b = id >> 12, n = (id >> 6) & 63, f = id & 63;
  float a = b2[f];
  for (int m = 0; m < 64; ++m) a += AX[(size_t)b*4096 + n*64 + m]*W2r[m*64 + f];
  for (int m = 0; m < 64; ++m) a += X1p[(size_t)b*4096 + n*64 + m]*W2s[m*64 + f];
  x2[id] = a > 0.f ? a : 0.f;
}

// ---------------------------------------------------------------------------
// s2 = softmax(x2@Wp2+bp2) over 32: 8 nodes/block, LDS staging, 32-lane softmax.
__global__ __launch_bounds__(256) void q_s2(const float* __restrict__ x2,
    const float* __restrict__ Wp2, const float* __restrict__ bp2,
    float* __restrict__ s2){
  __shared__ float wL[64][32];     // 8 KB
  __shared__ float xR[8][64];      // 2 KB
  int t = threadIdx.x, blk = blockIdx.x;
  int b = blk >> 3, n0 = (blk & 7)*8;
  for (int j=t; j<2048; j+=256) ((float*)wL)[j] = Wp2[j];
  for (int j=t; j<512; j+=256) ((float*)xR)[j] = x2[(size_t)b*4096 + n0*64 + j];
  __syncthreads();
  int g = t>>5, k = t&31;          // node group g (8 nodes), cluster k
  float lg = bp2[k];
  #pragma unroll
  for (int f=0; f<64; ++f) lg += xR[g][f]*wL[f][k];
  float m = lg;
  #pragma unroll
  for (int o=16;o>=1;o>>=1) m = fmaxf(m, __shfl_xor(m, o));
  float p = expf(lg - m);
  float ssum = p;
  #pragma unroll
  for (int o=16;o>=1;o>>=1) ssum += __shfl_xor(ssum, o);
  s2[(size_t)b*2048 + (n0+g)*32 + k] = p/ssum;
}

// ---------------------------------------------------------------------------
// V[b,n,l] = sum_m A2[b,n,m]*s2[b,m,l]
__global__ __launch_bounds__(256) void q_v(const float* __restrict__ A2,
    const float* __restrict__ s2, float* __restrict__ V){
  int id = blockIdx.x*256 + threadIdx.x;        // B*2048
  int b = id >> 11, n = (id >> 5) & 63, l = id & 31;
  float a = 0.f;
  for (int m = 0; m < 64; ++m) a += A2[(size_t)b*4096 + n*64 + m]*s2[(size_t)b*2048 + m*32 + l];
  V[id] = a;
}
// adj2[b,k,l] = sum_n s2[n,k]*V[n,l] ; ss2 = s2^T s2
__global__ __launch_bounds__(256) void q_adj2(const float* __restrict__ s2,
    const float* __restrict__ V, float* __restrict__ adj2, float* __restrict__ ss2){
  int id = blockIdx.x*256 + threadIdx.x;        // B*1024
  int b = id >> 10, k = (id >> 5) & 31, l = id & 31;
  float a = 0.f, c = 0.f;
  for (int n = 0; n < 64; ++n){
    float sk = s2[(size_t)b*2048 + n*32 + k];
    a += sk*V[(size_t)b*2048 + n*32 + l];
    c += sk*s2[(size_t)b*2048 + n*32 + l];
  }
  adj2[id] = a; ss2[id] = c;
}

// ---------------------------------------------------------------------------
// norm2: losses (mincut2, ortho2); A3 -> ws and out (f32).
__global__ __launch_bounds__(256) void q_norm2(const float* __restrict__ adj2,
    const float* __restrict__ ss2, const float* __restrict__ A2,
    const float* __restrict__ s2, float* __restrict__ A3,
    float* __restrict__ out, float* __restrict__ losses){
  __shared__ float aL[1024];
  __shared__ float sL[1024];
  __shared__ float r2[32];
  __shared__ float red[4];
  __shared__ float den2s;
  int b = blockIdx.x, t = threadIdx.x;
  for (int j = t; j < 1024; j += 256){
    aL[j] = adj2[(size_t)b*1024 + j];
    sL[j] = ss2[(size_t)b*1024 + j];
  }
  __syncthreads();
  if (t < 64){
    float rsA = 0.f;
    for (int m = 0; m < 64; ++m) rsA += A2[(size_t)b*4096 + t*64 + m];
    float q = 0.f;
    for (int k = 0; k < 32; ++k){ float s = s2[(size_t)b*2048 + t*32 + k]; q += s*s; }
    float part = rsA*q;
    #pragma unroll
    for (int o = 32; o >= 1; o >>= 1) part += __shfl_xor(part, o);
    if (t == 0) den2s = part;
  }
  if (t < 32){
    float rs = 0.f;
    for (int l = 0; l < 32; ++l) rs += aL[t*32 + l];
    rs -= aL[t*32 + t];
    r2[t] = 1.f/(sqrtf(rs) + 1e-15f);
  }
  __syncthreads();
  if (t == 0){
    float tr = 0.f;
    for (int k = 0; k < 32; ++k) tr += aL[k*32 + k];
    atomicAdd(&losses[0], -(tr/den2s) * (1.0f/B_));
  }
  float pp = 0.f;
  for (int j = t; j < 1024; j += 256){ float v = sL[j]; pp += v*v; }
  #pragma unroll
  for (int o = 32; o >= 1; o >>= 1) pp += __shfl_xor(pp, o);
  if ((t & 63) == 0) red[t >> 6] = pp;
  __syncthreads();
  float fro = sqrtf(red[0]+red[1]+red[2]+red[3]);
  __syncthreads();
  float op = 0.f;
  for (int j = t; j < 1024; j += 256){
    int kk = j >> 5, ll = j & 31;
    float v = sL[j]/fro - ((kk==ll) ? 0.1767766952966369f : 0.f);  // I/sqrt(32)
    op += v*v;
  }
  #pragma unroll
  for (int o = 32; o >= 1; o >>= 1) op += __shfl_xor(op, o);
  if ((t & 63) == 0) red[t >> 6] = op;
  __syncthreads();
  if (t == 0) atomicAdd(&losses[1], sqrtf(red[0]+red[1]+red[2]+red[3]) * (1.0f/B_));
  for (int j = t; j < 1024; j += 256){
    int kk = j >> 5, ll = j & 31;
    float v = (kk==ll) ? 0.f : aL[j]*r2[kk]*r2[ll];
    A3[(size_t)b*1024 + j] = v;
    out[OFF_ADJ + (size_t)b*1024 + j] = v;
  }
}

// ---------------------------------------------------------------------------
// o2[b,k,f] = sum_n s2[n,k]*x2[n,f]
__global__ __launch_bounds__(256) void q_o2(const float* __restrict__ s2,
    const float* __restrict__ x2, float* __restrict__ o2){
  int id = blockIdx.x*256 + threadIdx.x;        // B*2048
  int b = id >> 11, k = (id >> 6) & 31, f = id & 63;
  float a = 0.f;
  for (int n = 0; n < 64; ++n)
    a += s2[(size_t)b*2048 + n*32 + k]*x2[(size_t)b*4096 + n*64 + f];
  o2[id] = a;
}
// G[b,n,f] = sum_m A3[b,n,m]*o2[b,m,f]
__global__ __launch_bounds__(256) void q_g(const float* __restrict__ A3,
    const float* __restrict__ o2, float* __restrict__ G){
  int id = blockIdx.x*256 + threadIdx.x;        // B*2048
  int b = id >> 11, n = (id >> 6) & 31, f = id & 63;
  float a = 0.f;
  for (int m = 0; m < 32; ++m)
    a += A3[(size_t)b*1024 + n*32 + m]*o2[(size_t)b*2048 + m*64 + f];
  G[id] = a;
}
// x3[b,n,o] -> out (f32)
__global__ __launch_bounds__(256) void q_xout(const float* __restrict__ G,
    const float* __restrict__ o2, const float* __restrict__ W3r,
    const float* __restrict__ W3s, const float* __restrict__ b3,
    float* __restrict__ out){
  int id = blockIdx.x*256 + threadIdx.x;        // B*4096
  int b = id >> 12, n = (id >> 7) & 31, o = id & 127;
  float a = b3[o];
  for (int f = 0; f < 64; ++f) a += G[(size_t)b*2048 + n*64 + f]*W3r[f*128 + o];
  for (int f = 0; f < 64; ++f) a += o2[(size_t)b*2048 + n*64 + f]*W3s[f*128 + o];
  out[(size_t)b*4096 + n*128 + o] = a;
}

// ---------------------------------------------------------------------------
// agg = s1 @ s2: 8 blocks/graph (64 nodes each), LDS-staged, 4x2 register tile.
__global__ __launch_bounds__(256) void q_agg(const bf16* __restrict__ s1,
    const float* __restrict__ s2, float* __restrict__ out){
  __shared__ float s1L[64][65];    // 16.6 KB
  __shared__ float s2L[64][33];    //  8.4 KB
  int t = threadIdx.x, blk = blockIdx.x;
  int b = blk >> 3, n0 = (blk & 7)*64;
  for (int j=t; j<4096; j+=256){
    int n = j>>6, k = j&63;
    s1L[n][k] = b2f(s1[((size_t)b*N_ + n0 + n)*64 + k]);
  }
  for (int j=t; j<2048; j+=256){
    int k = j>>5, l = j&31;
    s2L[k][l] = s2[(size_t)b*2048 + j];
  }
  __syncthreads();
  int ti = t>>4, tj = t&15;        // 4 nodes x 2 cols per thread
  float acc[4][2];
  #pragma unroll
  for (int i=0;i<4;i++){ acc[i][0]=0.f; acc[i][1]=0.f; }
  for (int k=0; k<64; ++k){
    float xs[4];
    #pragma unroll
    for (int i=0;i<4;i++) xs[i] = s1L[ti*4+i][k];
    float w0 = s2L[k][tj*2], w1 = s2L[k][tj*2+1];
    #pragma unroll
    for (int i=0;i<4;i++){ acc[i][0] += xs[i]*w0; acc[i][1] += xs[i]*w1; }
  }
  #pragma unroll
  for (int i=0;i<4;i++){
    size_t o = OFF_AGG + ((size_t)b*N_ + n0 + ti*4+i)*32 + tj*2;
    out[o]   = acc[i][0];
    out[o+1] = acc[i][1];
  }
}

// ---------------------------------------------------------------------------
__global__ void q_loss(const float* losses, float* out){
  if (threadIdx.x == 0){
    out[OFF_MC] = losses[0];
    out[OFF_O]  = losses[1];
  }
}

// ===========================================================================
extern "C" void kernel_launch(void* const* d_in, const int* in_sizes, int n_in,
                              void* d_out, int out_size, void* d_ws, size_t ws_size,
                              hipStream_t stream){
  (void)out_size;
  float* out = (float*)d_out;

  static const long long EXP_SIZES[16] = {
    8388608LL, 2097152LL, 1048576LL, 65536LL,
    8192LL, 64LL, 4096LL, 64LL,
    4096LL, 64LL, 4096LL, 2048LL, 32LL,
    8192LL, 128LL, 8192LL };
  if (n_in != 16){ q_sent<<<1,64,0,stream>>>(out, exp2f(36.f)); return; }
  for (int i = 0; i < 16; ++i){
    if ((long long)in_sizes[i] != EXP_SIZES[i]){
      q_sent<<<1,64,0,stream>>>(out, exp2f((float)(37+i))); return;
    }
  }

  const float* pos = (const float*)d_in[0];
  const int*   ei  = (const int*)  d_in[1];
  const float* ea  = (const float*)d_in[2];
  const float* W1  = (const float*)d_in[4];
  const float* b1  = (const float*)d_in[5];
  const float* Wp1 = (const float*)d_in[6];
  const float* bp1 = (const float*)d_in[7];
  const float* W2r = (const float*)d_in[8];
  const float* b2  = (const float*)d_in[9];
  const float* W2s = (const float*)d_in[10];
  const float* Wp2 = (const float*)d_in[11];
  const float* bp2 = (const float*)d_in[12];
  const float* W3r = (const float*)d_in[13];
  const float* b3  = (const float*)d_in[14];
  const float* W3s = (const float*)d_in[15];

  // ---- workspace (~42.5 MB) with lifetime-safe unions:
  //  R1: csrR (q_csr..q_gcn)  -> adjP+ssP (q_p3..)
  //  R2: csrW (q_csr..q_gcn)  -> AX+x2    (q_ax..)
  //  R3: csrC (q_csr..q_u)    -> X1p+A2   (q_p3..)
  constexpr size_t MB2 = (size_t)B_*4096*4;     // 2 MB
  char* w = (char*)d_ws;
  float* dis    = (float*)w; w += (size_t)NT_*4;
  float* drow   = (float*)w; w += (size_t)NT_*4;
  float* den    = (float*)w; w += (size_t)B_*4;
  float* losses = (float*)w; w += 64;
  int*   offC   = (int*)  w; w += (size_t)NT_*4;
  int*   offR   = (int*)  w; w += (size_t)NT_*4;
  char*  R1     = w;         w += 2*MB2;        // 4 MB
  char*  R2     = w;         w += 2*MB2;        // 4 MB
  char*  R3     = w;         w += 2*MB2;        // 4 MB
  float* s2     = (float*)w; w += (size_t)B_*2048*4;
  float* V      = (float*)w; w += (size_t)B_*2048*4;
  float* adj2   = (float*)w; w += (size_t)B_*1024*4;
  float* ss2    = (float*)w; w += (size_t)B_*1024*4;
  float* A3     = (float*)w; w += (size_t)B_*1024*4;
  float* o2     = (float*)w; w += (size_t)B_*2048*4;
  float* G      = (float*)w; w += (size_t)B_*2048*4;
  bf16*  xwU    = (bf16*)w;  w += (size_t)NT_*64*2;    // xw, then U
  bf16*  x1     = (bf16*)w;  w += (size_t)NT_*64*2;
  bf16*  s1     = (bf16*)w;  w += (size_t)NT_*64*2;
  size_t need = (size_t)(w - (char*)d_ws);
  if (ws_size < need){ q_sent<<<1,64,0,stream>>>(out, exp2f(20.f)); return; }

  int*   csrR = (int*)  R1;
  float* csrW = (float*)R2;
  int*   csrC = (int*)  R3;
  float* adjP = (float*)R1;
  float* ssP  = (float*)(R1 + MB2);
  float* AX   = (float*)R2;
  float* x2   = (float*)(R2 + MB2);
  float* X1p  = (float*)R3;
  float* A2   = (float*)(R3 + MB2);

  q_init <<<1,    256, 0, stream>>>(den, losses);
  q_deg  <<<B_,   256, 0, stream>>>(ei, ea, dis, drow);
  q_csr  <<<B_,   256, 0, stream>>>(ei, ea, dis, offC, offR, csrR, csrW, csrC);
  q_xw   <<<NT_/64,256, 0, stream>>>(pos, W1, xwU);
  q_gcn  <<<16384,256, 0, stream>>>(offC, csrR, csrW, dis, xwU, b1, x1);
  q_s1   <<<NT_/64,256, 0, stream>>>(x1, Wp1, bp1, drow, s1, den);
  q_u    <<<16384,256, 0, stream>>>(offR, csrC, s1, xwU);     // xwU := U
  q_p3   <<<B_,   256, 0, stream>>>(s1, xwU, x1, adjP, ssP, X1p);
  q_norm1<<<B_,   256, 0, stream>>>(adjP, ssP, den, A2, losses);
  q_ax   <<<2048, 256, 0, stream>>>(A2, X1p, AX);
  q_x2   <<<2048, 256, 0, stream>>>(AX, X1p, W2r, W2s, b2, x2);
  q_s2   <<<1024, 256, 0, stream>>>(x2, Wp2, bp2, s2);
  q_v    <<<1024, 256, 0, stream>>>(A2, s2, V);
  q_adj2 <<<512,  256, 0, stream>>>(s2, V, adj2, ss2);
  q_norm2<<<B_,   256, 0, stream>>>(adj2, ss2, A2, s2, A3, out, losses);
  q_o2   <<<1024, 256, 0, stream>>>(s2, x2, o2);
  q_g    <<<1024, 256, 0, stream>>>(A3, o2, G);
  q_xout <<<2048, 256, 0, stream>>>(G, o2, W3r, W3s, b3, out);
  q_agg  <<<1024, 256, 0, stream>>>(s1, s2, out);
  q_loss <<<1,     64, 0, stream>>>(losses, out);
}

// Round 17
// 353.669 us; speedup vs baseline: 47.8727x; 1.2660x over previous
//
#include <hip/hip_runtime.h>
#include <hip/hip_bf16.h>

// ============================================================================
// FrameAggregator — ROUND 17:
//  * q_gcn/q_u: 4x-unrolled CSR gather loops (4 misses in flight)
//  * q_lvl2: fused AX/x2/s2/V/adj2/norm2/o2/G/xout (9 kernels -> 1, all
//    intermediates LDS-resident; s2 spilled to ws for q_agg)
// Everything else identical to the round-16 passing pipeline.
// ============================================================================

typedef __hip_bfloat16 bf16;
#define DEV static __device__ __forceinline__
DEV float b2f(bf16 x){ return __bfloat162float(x); }
DEV bf16  f2b(float x){ return __float2bfloat16(x); }

constexpr int B_  = 128;
constexpr int N_  = 512;
constexpr int EG_ = 8192;
constexpr int E_  = B_*EG_;     // 1048576
constexpr int NT_ = B_*N_;      // 65536

constexpr size_t OFF_MC  = (size_t)B_*32*128;                 // 524288
constexpr size_t OFF_O   = OFF_MC + 1;
constexpr size_t OFF_AGG = OFF_O + 1;                         // 524290
constexpr size_t OFF_ADJ = OFF_AGG + (size_t)B_*N_*32;        // 2621442

// ---------------------------------------------------------------------------
__global__ void q_init(float* den, float* losses){
  int i = threadIdx.x;
  if (i < B_) den[i] = 0.f;
  if (i < 2)  losses[i] = 0.f;
}
__global__ void q_sent(float* out, float v){
  if (threadIdx.x == 0) out[0] = v;
}

// ---------------------------------------------------------------------------
// deg/drow via LDS scatter: block per graph.
__global__ __launch_bounds__(256) void q_deg(const int* __restrict__ ei,
    const float* __restrict__ ea, float* __restrict__ dis, float* __restrict__ drow){
  __shared__ float degL[N_];
  __shared__ float drL[N_];
  int t = threadIdx.x, b = blockIdx.x, base = b*N_;
  for (int j=t; j<N_; j+=256){ degL[j] = 1.0f; drL[j] = 0.f; }  // 1.0 = self loop
  __syncthreads();
  int e0 = b*EG_;
  for (int j=t; j<EG_; j+=256){
    int e = e0 + j;
    int r = ei[e], c = ei[E_+e];
    atomicAdd(&degL[c-base], ea[e]);
    atomicAdd(&drL [r-base], 1.0f);
  }
  __syncthreads();
  for (int j=t; j<N_; j+=256){
    dis [base+j] = rsqrtf(degL[j]);
    drow[base+j] = drL[j];
  }
}

// ---------------------------------------------------------------------------
// q_csr: per-graph CSR build. by-col: (csrR, csrW=dis[r]*ea*dis[c]); by-row: csrC.
__global__ __launch_bounds__(256) void q_csr(const int* __restrict__ ei,
    const float* __restrict__ ea, const float* __restrict__ dis,
    int* __restrict__ offC, int* __restrict__ offR,
    int* __restrict__ csrR, float* __restrict__ csrW, int* __restrict__ csrC){
  __shared__ int cC[N_], cR[N_];
  int t = threadIdx.x, b = blockIdx.x, base = b*N_, e0 = b*EG_;
  for (int j=t; j<N_; j+=256){ cC[j]=0; cR[j]=0; }
  __syncthreads();
  for (int j=t; j<EG_; j+=256){
    int e = e0 + j;
    atomicAdd(&cC[ei[E_+e]-base], 1);
    atomicAdd(&cR[ei[e]   -base], 1);
  }
  __syncthreads();
  if (t == 0){                    // serial exclusive scan (512 elems, cheap)
    int aC = 0, aR = 0;
    for (int n=0; n<N_; ++n){
      int vc = cC[n], vr = cR[n];
      cC[n] = aC; cR[n] = aR;
      aC += vc; aR += vr;
    }
  }
  __syncthreads();
  for (int j=t; j<N_; j+=256){ offC[base+j] = e0 + cC[j]; offR[base+j] = e0 + cR[j]; }
  __syncthreads();
  for (int j=t; j<EG_; j+=256){
    int e = e0 + j;
    int r = ei[e], c = ei[E_+e];
    float w = dis[r]*ea[e]*dis[c];
    int p  = atomicAdd(&cC[c-base], 1);
    csrR[e0+p] = r;  csrW[e0+p] = w;
    int p2 = atomicAdd(&cR[r-base], 1);
    csrC[e0+p2] = c;
  }
}

// ---------------------------------------------------------------------------
// xw = pos @ W1: 64-node tiles, LDS-staged pos+W1, 4x4 register tiles.
__global__ __launch_bounds__(256) void q_xw(const float* __restrict__ pos,
    const float* __restrict__ W1, bf16* __restrict__ xw){
  __shared__ float pL[64][129];    // 33 KB, padded
  __shared__ float wT[128][64];    // 32 KB (= W1 layout)
  int t = threadIdx.x;
  int n0 = blockIdx.x*64;
  for (int j=t; j<2048; j+=256){   // 64 rows x 32 float4
    int n = j >> 5, c4 = j & 31;
    float4 v = *reinterpret_cast<const float4*>(pos + (size_t)(n0+n)*128 + c4*4);
    pL[n][c4*4+0]=v.x; pL[n][c4*4+1]=v.y; pL[n][c4*4+2]=v.z; pL[n][c4*4+3]=v.w;
  }
  for (int j=t; j<8192; j+=256) ((float*)wT)[j] = W1[j];
  __syncthreads();
  int ti = t>>4, tj = t&15;
  float acc[4][4];
  #pragma unroll
  for (int i=0;i<4;i++)
    #pragma unroll
    for (int j=0;j<4;j++) acc[i][j] = 0.f;
  for (int k=0; k<128; ++k){
    float xs[4], ws[4];
    #pragma unroll
    for (int i=0;i<4;i++) xs[i] = pL[ti*4+i][k];
    #pragma unroll
    for (int j=0;j<4;j++) ws[j] = wT[k][tj*4+j];
    #pragma unroll
    for (int i=0;i<4;i++)
      #pragma unroll
      for (int j=0;j<4;j++) acc[i][j] += xs[i]*ws[j];
  }
  #pragma unroll
  for (int i=0;i<4;i++)
    #pragma unroll
    for (int j=0;j<4;j++)
      xw[(size_t)(n0+ti*4+i)*64 + tj*4+j] = f2b(acc[i][j]);
}

// ---------------------------------------------------------------------------
// GCN conv: one wave per destination node, CSR gather, 4x unrolled.
__global__ __launch_bounds__(256) void q_gcn(const int* __restrict__ offC,
    const int* __restrict__ csrR, const float* __restrict__ csrW,
    const float* __restrict__ dis, const bf16* __restrict__ xw,
    const float* __restrict__ b1, bf16* __restrict__ x1){
  int n = (blockIdx.x*256 + threadIdx.x) >> 6;  // node 0..NT-1
  int f = threadIdx.x & 63;
  float d = dis[n];
  float h = d*d*b2f(xw[(size_t)n*64 + f]);
  int s = offC[n];
  int e = ((n & 511) == 511) ? ((n >> 9) + 1)*EG_ : offC[n+1];
  int j = s;
  for (; j + 3 < e; j += 4){
    int r0 = csrR[j],   r1 = csrR[j+1], r2 = csrR[j+2], r3 = csrR[j+3];
    float w0 = csrW[j], w1 = csrW[j+1], w2 = csrW[j+2], w3 = csrW[j+3];
    float v0 = b2f(xw[(size_t)r0*64 + f]);
    float v1 = b2f(xw[(size_t)r1*64 + f]);
    float v2 = b2f(xw[(size_t)r2*64 + f]);
    float v3 = b2f(xw[(size_t)r3*64 + f]);
    h += w0*v0 + w1*v1 + w2*v2 + w3*v3;
  }
  for (; j < e; ++j) h += csrW[j] * b2f(xw[(size_t)csrR[j]*64 + f]);
  h += b1[f];
  x1[(size_t)n*64 + f] = f2b(h > 0.f ? h : 0.f);
}

// ---------------------------------------------------------------------------
// s1 = softmax(x1 @ Wp1 + bp1): 64 nodes/block, register-tile GEMM,
// in-register softmax with 16-lane shfl reductions.
__global__ __launch_bounds__(256) void q_s1(const bf16* __restrict__ x1,
    const float* __restrict__ Wp1, const float* __restrict__ bp1,
    const float* __restrict__ drow, bf16* __restrict__ s1, float* __restrict__ den){
  __shared__ float xT[64][65];
  __shared__ float wT[64][64];
  __shared__ float denL;
  int t = threadIdx.x;
  int n0 = blockIdx.x*64;
  if (t == 0) denL = 0.f;
  for (int j=t; j<4096; j+=256){
    wT[j>>6][j&63] = Wp1[j];
    xT[j>>6][j&63] = b2f(x1[(size_t)n0*64 + j]);
  }
  __syncthreads();
  int ti = t>>4, tj = t&15;
  float acc[4][4];
  #pragma unroll
  for (int i=0;i<4;i++)
    #pragma unroll
    for (int j=0;j<4;j++) acc[i][j] = 0.f;
  for (int f=0; f<64; ++f){
    float xs[4], ws[4];
    #pragma unroll
    for (int i=0;i<4;i++) xs[i] = xT[ti*4+i][f];
    #pragma unroll
    for (int j=0;j<4;j++) ws[j] = wT[f][tj*4+j];
    #pragma unroll
    for (int i=0;i<4;i++)
      #pragma unroll
      for (int j=0;j<4;j++) acc[i][j] += xs[i]*ws[j];
  }
  {
    float bp[4];
    #pragma unroll
    for (int j=0;j<4;j++) bp[j] = bp1[tj*4+j];
    #pragma unroll
    for (int i=0;i<4;i++)
      #pragma unroll
      for (int j=0;j<4;j++) acc[i][j] += bp[j];
  }
  #pragma unroll
  for (int i=0;i<4;i++){
    float m = fmaxf(fmaxf(acc[i][0],acc[i][1]), fmaxf(acc[i][2],acc[i][3]));
    #pragma unroll
    for (int o=8;o>=1;o>>=1) m = fmaxf(m, __shfl_xor(m, o));
    float e[4]; float ssum = 0.f;
    #pragma unroll
    for (int j=0;j<4;j++){ e[j] = expf(acc[i][j]-m); ssum += e[j]; }
    #pragma unroll
    for (int o=8;o>=1;o>>=1) ssum += __shfl_xor(ssum, o);
    float inv = 1.f/ssum, q = 0.f;
    int n = n0 + ti*4 + i;
    #pragma unroll
    for (int j=0;j<4;j++){
      float sv = e[j]*inv;
      s1[(size_t)n*64 + tj*4 + j] = f2b(sv);
      q += sv*sv;
    }
    #pragma unroll
    for (int o=8;o>=1;o>>=1) q += __shfl_xor(q, o);
    if (tj == 0) atomicAdd(&denL, q * drow[n]);
  }
  __syncthreads();
  if (t == 0) atomicAdd(&den[n0 >> 9], denL);
}

// ---------------------------------------------------------------------------
// U = A @ s1: one wave per row node, CSR(by-row) gather, 4x unrolled.
__global__ __launch_bounds__(256) void q_u(const int* __restrict__ offR,
    const int* __restrict__ csrC, const bf16* __restrict__ s1,
    bf16* __restrict__ U){
  int n = (blockIdx.x*256 + threadIdx.x) >> 6;
  int l = threadIdx.x & 63;
  float u = 0.f;
  int s = offR[n];
  int e = ((n & 511) == 511) ? ((n >> 9) + 1)*EG_ : offR[n+1];
  int j = s;
  for (; j + 3 < e; j += 4){
    int c0 = csrC[j], c1 = csrC[j+1], c2 = csrC[j+2], c3 = csrC[j+3];
    float v0 = b2f(s1[(size_t)c0*64 + l]);
    float v1 = b2f(s1[(size_t)c1*64 + l]);
    float v2 = b2f(s1[(size_t)c2*64 + l]);
    float v3 = b2f(s1[(size_t)c3*64 + l]);
    u += v0 + v1 + v2 + v3;
  }
  for (; j < e; ++j) u += b2f(s1[(size_t)csrC[j]*64 + l]);
  U[(size_t)n*64 + l] = f2b(u);
}

// ---------------------------------------------------------------------------
// q_p3: fused adjP = s^T U, ssP = s^T s, X1p = s^T x1 (one graph per block).
__global__ __launch_bounds__(256) void q_p3(const bf16* __restrict__ s1,
    const bf16* __restrict__ U, const bf16* __restrict__ x1,
    float* __restrict__ adjP, float* __restrict__ ssP, float* __restrict__ X1p){
  __shared__ float sL[64][64];
  __shared__ float uL[64][64];
  __shared__ float xL[64][64];
  int t = threadIdx.x, b = blockIdx.x, base = b*N_;
  int ti = t>>4, tj = t&15;
  float accA[4][4], accS[4][4], accX[4][4];
  #pragma unroll
  for (int i=0;i<4;i++)
    #pragma unroll
    for (int j=0;j<4;j++){ accA[i][j]=0.f; accS[i][j]=0.f; accX[i][j]=0.f; }
  for (int c=0; c<8; ++c){
    __syncthreads();
    for (int j=t; j<4096; j+=256){
      int n = j>>6, q = j&63;
      size_t g = (size_t)(base + c*64 + n)*64 + q;
      sL[n][q] = b2f(s1[g]);
      uL[n][q] = b2f(U [g]);
      xL[n][q] = b2f(x1[g]);
    }
    __syncthreads();
    for (int n=0; n<64; ++n){
      float4 skv = *reinterpret_cast<const float4*>(&sL[n][ti*4]);
      float4 ulv = *reinterpret_cast<const float4*>(&uL[n][tj*4]);
      float4 xlv = *reinterpret_cast<const float4*>(&xL[n][tj*4]);
      float4 slv = *reinterpret_cast<const float4*>(&sL[n][tj*4]);
      float sk[4] = {skv.x, skv.y, skv.z, skv.w};
      float ul[4] = {ulv.x, ulv.y, ulv.z, ulv.w};
      float xl[4] = {xlv.x, xlv.y, xlv.z, xlv.w};
      float sl[4] = {slv.x, slv.y, slv.z, slv.w};
      #pragma unroll
      for (int i=0;i<4;i++)
        #pragma unroll
        for (int j=0;j<4;j++){
          accA[i][j] += sk[i]*ul[j];
          accS[i][j] += sk[i]*sl[j];
          accX[i][j] += sk[i]*xl[j];
        }
    }
  }
  #pragma unroll
  for (int i=0;i<4;i++)
    #pragma unroll
    for (int j=0;j<4;j++){
      size_t o = (size_t)b*4096 + (ti*4+i)*64 + tj*4+j;
      adjP[o] = accA[i][j];
      ssP [o] = accS[i][j];
      X1p [o] = accX[i][j];
    }
}

// ---------------------------------------------------------------------------
// norm1: losses (mincut1, ortho1); A2 = degnorm(diagzero(adjP)).
__global__ __launch_bounds__(256) void q_norm1(const float* __restrict__ adjP,
    const float* __restrict__ ssP, const float* __restrict__ den,
    float* __restrict__ A2, float* __restrict__ losses){
  __shared__ float aL[4096];
  __shared__ float rL[64];
  __shared__ float red[4];
  int b = blockIdx.x, t = threadIdx.x;
  for (int j = t; j < 4096; j += 256) aL[j] = adjP[(size_t)b*4096 + j];
  __syncthreads();
  if (t == 0){
    float tr = 0.f;
    for (int k = 0; k < 64; ++k) tr += aL[k*64 + k];
    atomicAdd(&losses[0], -(tr/den[b]) * (1.0f/B_));
  }
  if (t < 64){
    float rs = 0.f;
    for (int l = 0; l < 64; ++l) rs += aL[t*64 + l];
    rs -= aL[t*64 + t];
    rL[t] = 1.f/(sqrtf(rs) + 1e-15f);
  }
  float pp = 0.f;
  for (int j = t; j < 4096; j += 256){ float v = ssP[(size_t)b*4096 + j]; pp += v*v; }
  #pragma unroll
  for (int o = 32; o >= 1; o >>= 1) pp += __shfl_xor(pp, o);
  if ((t & 63) == 0) red[t >> 6] = pp;
  __syncthreads();
  float fro = sqrtf(red[0]+red[1]+red[2]+red[3]);
  __syncthreads();
  float op = 0.f;
  for (int j = t; j < 4096; j += 256){
    int kk = j >> 6, ll = j & 63;
    float v = ssP[(size_t)b*4096 + j]/fro - ((kk==ll) ? 0.125f : 0.f);
    op += v*v;
  }
  #pragma unroll
  for (int o = 32; o >= 1; o >>= 1) op += __shfl_xor(op, o);
  if ((t & 63) == 0) red[t >> 6] = op;
  __syncthreads();
  if (t == 0) atomicAdd(&losses[1], sqrtf(red[0]+red[1]+red[2]+red[3]) * (1.0f/B_));
  for (int j = t; j < 4096; j += 256){
    int kk = j >> 6, ll = j & 63;
    A2[(size_t)b*4096 + j] = (kk==ll) ? 0.f : aL[j]*rL[kk]*rL[ll];
  }
}

// ---------------------------------------------------------------------------
// q_lvl2: FUSED level-2 GCN + pool2 + level-3 GCN per graph. All intermediates
// in LDS. Reads X1p/A2 (+weights); writes s2 (ws), losses, out-x, out-adj.
__global__ __launch_bounds__(256) void q_lvl2(const float* __restrict__ X1p,
    const float* __restrict__ A2g,
    const float* __restrict__ W2r, const float* __restrict__ b2,
    const float* __restrict__ W2s, const float* __restrict__ Wp2,
    const float* __restrict__ bp2, const float* __restrict__ W3r,
    const float* __restrict__ b3, const float* __restrict__ W3s,
    float* __restrict__ s2f, float* __restrict__ out, float* __restrict__ losses){
  __shared__ float XL[64][64], AL[64][64], AXL[64][64], x2L[64][64];   // 64 KB
  __shared__ float s2L[64][32], VL[64][32];                            // 16 KB
  __shared__ float adj2L[32][32], ss2L[32][32], A3L[32][32];           // 12 KB
  __shared__ float o2L[32][64], GL[32][64];                            // 16 KB
  __shared__ float wp2L[64][32];                                       //  8 KB
  __shared__ float r2L[32], red[4];
  __shared__ float den2s;
  int t = threadIdx.x, b = blockIdx.x;
  int wv = t>>6, lane = t&63;
  for (int j=t; j<4096; j+=256){
    ((float*)XL)[j] = X1p[(size_t)b*4096 + j];
    ((float*)AL)[j] = A2g[(size_t)b*4096 + j];
  }
  for (int j=t; j<2048; j+=256) ((float*)wp2L)[j] = Wp2[j];
  __syncthreads();
  // AX = A2 @ X1p
  for (int i=0;i<16;i++){
    int n = wv*16+i; float a = 0.f;
    for (int m=0;m<64;m++) a += AL[n][m]*XL[m][lane];
    AXL[n][lane] = a;
  }
  __syncthreads();
  // x2 = relu(AX@W2r + X1p@W2s + b2)
  {
    float bb = b2[lane];
    for (int i=0;i<16;i++){
      int n = wv*16+i; float a = bb;
      for (int m=0;m<64;m++) a += AXL[n][m]*W2r[m*64+lane];
      for (int m=0;m<64;m++) a += XL[n][m]*W2s[m*64+lane];
      x2L[n][lane] = a > 0.f ? a : 0.f;
    }
  }
  __syncthreads();
  // s2 = softmax(x2@Wp2 + bp2) over 32 (duplicated 32-lane halves)
  {
    int k = lane & 31;
    for (int i=0;i<16;i++){
      int n = wv*16+i;
      float lgv = bp2[k];
      for (int f=0; f<64; f++) lgv += x2L[n][f]*wp2L[f][k];
      float m = lgv;
      #pragma unroll
      for (int o=16;o>=1;o>>=1) m = fmaxf(m, __shfl_xor(m, o));
      float p = expf(lgv - m), ssum = p;
      #pragma unroll
      for (int o=16;o>=1;o>>=1) ssum += __shfl_xor(ssum, o);
      float sv = p/ssum;
      s2L[n][k] = sv;
      s2f[(size_t)b*2048 + n*32 + k] = sv;
    }
  }
  __syncthreads();
  // den2 = sum_n ||s2_n||^2 * rowsum(A2[n])
  {
    float part = 0.f;
    if (t < 64){
      float rs = 0.f; for (int m=0;m<64;m++) rs += AL[t][m];
      float q  = 0.f; for (int k2=0;k2<32;k2++){ float s = s2L[t][k2]; q += s*s; }
      part = q*rs;
    }
    #pragma unroll
    for (int o=32;o>=1;o>>=1) part += __shfl_xor(part, o);
    if (t == 0) den2s = part;
  }
  __syncthreads();
  // V = A2 @ s2
  for (int j=0;j<8;j++){
    int idx = t + 256*j; int n = idx>>5, l = idx&31;
    float a = 0.f;
    for (int m=0;m<64;m++) a += AL[n][m]*s2L[m][l];
    VL[n][l] = a;
  }
  __syncthreads();
  // adj2 = s2^T V ; ss2 = s2^T s2
  for (int j=0;j<4;j++){
    int idx = t + 256*j; int k2 = idx>>5, l = idx&31;
    float a = 0.f, c2 = 0.f;
    for (int n=0;n<64;n++){ float s = s2L[n][k2]; a += s*VL[n][l]; c2 += s*s2L[n][l]; }
    adj2L[k2][l] = a; ss2L[k2][l] = c2;
  }
  __syncthreads();
  if (t == 0){
    float tr = 0.f; for (int k2=0;k2<32;k2++) tr += adj2L[k2][k2];
    atomicAdd(&losses[0], -(tr/den2s) * (1.0f/B_));
  }
  if (t < 32){
    float rs = 0.f; for (int l=0;l<32;l++) rs += adj2L[t][l];
    rs -= adj2L[t][t];
    r2L[t] = 1.f/(sqrtf(rs) + 1e-15f);
  }
  // fro2 / ortho2
  {
    float pp = 0.f;
    for (int j=t; j<1024; j+=256){ float v = ((float*)ss2L)[j]; pp += v*v; }
    #pragma unroll
    for (int o=32;o>=1;o>>=1) pp += __shfl_xor(pp, o);
    if ((t & 63) == 0) red[t >> 6] = pp;
    __syncthreads();
    float fro = sqrtf(red[0]+red[1]+red[2]+red[3]);
    __syncthreads();
    float op = 0.f;
    for (int j=t; j<1024; j+=256){
      int k2 = j>>5, l = j&31;
      float v = ((float*)ss2L)[j]/fro - ((k2==l) ? 0.1767766952966369f : 0.f);
      op += v*v;
    }
    #pragma unroll
    for (int o=32;o>=1;o>>=1) op += __shfl_xor(op, o);
    if ((t & 63) == 0) red[t >> 6] = op;
    __syncthreads();
    if (t == 0) atomicAdd(&losses[1], sqrtf(red[0]+red[1]+red[2]+red[3]) * (1.0f/B_));
  }
  __syncthreads();
  // A3 -> out adj
  for (int j=0;j<4;j++){
    int idx = t + 256*j; int k2 = idx>>5, l = idx&31;
    float v = (k2==l) ? 0.f : adj2L[k2][l]*r2L[k2]*r2L[l];
    A3L[k2][l] = v;
    out[OFF_ADJ + (size_t)b*1024 + idx] = v;
  }
  __syncthreads();
  // o2 = s2^T x2
  for (int j=0;j<8;j++){
    int idx = t + 256*j; int k2 = idx>>6, f = idx&63;
    float a = 0.f;
    for (int n=0;n<64;n++) a += s2L[n][k2]*x2L[n][f];
    o2L[k2][f] = a;
  }
  __syncthreads();
  // G = A3 @ o2
  for (int j=0;j<8;j++){
    int idx = t + 256*j; int n = idx>>6, f = idx&63;
    float a = 0.f;
    for (int m=0;m<32;m++) a += A3L[n][m]*o2L[m][f];
    GL[n][f] = a;
  }
  __syncthreads();
  // x3 = G@W3r + o2@W3s + b3 -> out x
  for (int j=0;j<16;j++){
    int idx = t + 256*j; int n = idx>>7, o = idx&127;
    float a = b3[o];
    for (int f=0;f<64;f++) a += GL[n][f]*W3r[f*128+o];
    for (int f=0;f<64;f++) a += o2L[n][f]*W3s[f*128+o];
    out[(size_t)b*4096 + idx] = a;
  }
}

// ---------------------------------------------------------------------------
// agg = s1 @ s2: 8 blocks/graph (64 nodes each), LDS-staged, 4x2 register tile.
__global__ __launch_bounds__(256) void q_agg(const bf16* __restrict__ s1,
    const float* __restrict__ s2, float* __restrict__ out){
  __shared__ float s1L[64][65];
  __shared__ float s2L[64][33];
  int t = threadIdx.x, blk = blockIdx.x;
  int b = blk >> 3, n0 = (blk & 7)*64;
  for (int j=t; j<4096; j+=256){
    int n = j>>6, k = j&63;
    s1L[n][k] = b2f(s1[((size_t)b*N_ + n0 + n)*64 + k]);
  }
  for (int j=t; j<2048; j+=256){
    int k = j>>5, l = j&31;
    s2L[k][l] = s2[(size_t)b*2048 + j];
  }
  __syncthreads();
  int ti = t>>4, tj = t&15;
  float acc[4][2];
  #pragma unroll
  for (int i=0;i<4;i++){ acc[i][0]=0.f; acc[i][1]=0.f; }
  for (int k=0; k<64; ++k){
    float xs[4];
    #pragma unroll
    for (int i=0;i<4;i++) xs[i] = s1L[ti*4+i][k];
    float w0 = s2L[k][tj*2], w1 = s2L[k][tj*2+1];
    #pragma unroll
    for (int i=0;i<4;i++){ acc[i][0] += xs[i]*w0; acc[i][1] += xs[i]*w1; }
  }
  #pragma unroll
  for (int i=0;i<4;i++){
    size_t o = OFF_AGG + ((size_t)b*N_ + n0 + ti*4+i)*32 + tj*2;
    out[o]   = acc[i][0];
    out[o+1] = acc[i][1];
  }
}

// ---------------------------------------------------------------------------
__global__ void q_loss(const float* losses, float* out){
  if (threadIdx.x == 0){
    out[OFF_MC] = losses[0];
    out[OFF_O]  = losses[1];
  }
}

// ===========================================================================
extern "C" void kernel_launch(void* const* d_in, const int* in_sizes, int n_in,
                              void* d_out, int out_size, void* d_ws, size_t ws_size,
                              hipStream_t stream){
  (void)out_size;
  float* out = (float*)d_out;

  static const long long EXP_SIZES[16] = {
    8388608LL, 2097152LL, 1048576LL, 65536LL,
    8192LL, 64LL, 4096LL, 64LL,
    4096LL, 64LL, 4096LL, 2048LL, 32LL,
    8192LL, 128LL, 8192LL };
  if (n_in != 16){ q_sent<<<1,64,0,stream>>>(out, exp2f(36.f)); return; }
  for (int i = 0; i < 16; ++i){
    if ((long long)in_sizes[i] != EXP_SIZES[i]){
      q_sent<<<1,64,0,stream>>>(out, exp2f((float)(37+i))); return;
    }
  }

  const float* pos = (const float*)d_in[0];
  const int*   ei  = (const int*)  d_in[1];
  const float* ea  = (const float*)d_in[2];
  const float* W1  = (const float*)d_in[4];
  const float* b1  = (const float*)d_in[5];
  const float* Wp1 = (const float*)d_in[6];
  const float* bp1 = (const float*)d_in[7];
  const float* W2r = (const float*)d_in[8];
  const float* b2  = (const float*)d_in[9];
  const float* W2s = (const float*)d_in[10];
  const float* Wp2 = (const float*)d_in[11];
  const float* bp2 = (const float*)d_in[12];
  const float* W3r = (const float*)d_in[13];
  const float* b3  = (const float*)d_in[14];
  const float* W3s = (const float*)d_in[15];

  // ---- workspace with lifetime-safe unions (as round 16)
  constexpr size_t MB2 = (size_t)B_*4096*4;     // 2 MB
  char* w = (char*)d_ws;
  float* dis    = (float*)w; w += (size_t)NT_*4;
  float* drow   = (float*)w; w += (size_t)NT_*4;
  float* den    = (float*)w; w += (size_t)B_*4;
  float* losses = (float*)w; w += 64;
  int*   offC   = (int*)  w; w += (size_t)NT_*4;
  int*   offR   = (int*)  w; w += (size_t)NT_*4;
  char*  R1     = w;         w += 2*MB2;        // csrR -> adjP+ssP
  char*  R2     = w;         w += 2*MB2;        // csrW -> (unused after q_gcn)
  char*  R3     = w;         w += 2*MB2;        // csrC -> X1p+A2
  float* s2     = (float*)w; w += (size_t)B_*2048*4;
  bf16*  xwU    = (bf16*)w;  w += (size_t)NT_*64*2;    // xw, then U
  bf16*  x1     = (bf16*)w;  w += (size_t)NT_*64*2;
  bf16*  s1     = (bf16*)w;  w += (size_t)NT_*64*2;
  size_t need = (size_t)(w - (char*)d_ws);
  if (ws_size < need){ q_sent<<<1,64,0,stream>>>(out, exp2f(20.f)); return; }

  int*   csrR = (int*)  R1;
  float* csrW = (float*)R2;
  int*   csrC = (int*)  R3;
  float* adjP = (float*)R1;
  float* ssP  = (float*)(R1 + MB2);
  float* X1p  = (float*)R3;
  float* A2   = (float*)(R3 + MB2);

  q_init <<<1,    256, 0, stream>>>(den, losses);
  q_deg  <<<B_,   256, 0, stream>>>(ei, ea, dis, drow);
  q_csr  <<<B_,   256, 0, stream>>>(ei, ea, dis, offC, offR, csrR, csrW, csrC);
  q_xw   <<<NT_/64,256, 0, stream>>>(pos, W1, xwU);
  q_gcn  <<<16384,256, 0, stream>>>(offC, csrR, csrW, dis, xwU, b1, x1);
  q_s1   <<<NT_/64,256, 0, stream>>>(x1, Wp1, bp1, drow, s1, den);
  q_u    <<<16384,256, 0, stream>>>(offR, csrC, s1, xwU);     // xwU := U
  q_p3   <<<B_,   256, 0, stream>>>(s1, xwU, x1, adjP, ssP, X1p);
  q_norm1<<<B_,   256, 0, stream>>>(adjP, ssP, den, A2, losses);
  q_lvl2 <<<B_,   256, 0, stream>>>(X1p, A2, W2r, b2, W2s, Wp2, bp2,
                                    W3r, b3, W3s, s2, out, losses);
  q_agg  <<<1024, 256, 0, stream>>>(s1, s2, out);
  q_loss <<<1,     64, 0, stream>>>(losses, out);
}